// Round 1
// baseline (764.863 us; speedup 1.0000x reference)
//
#include <hip/hip_runtime.h>

#define N1 32768
#define EE 524288
#define NB 16
#define NPG1 2048
#define KK1 1024
#define N2 16384
#define NPG2 1024
#define KK2 512
#define N3 8192

static __device__ __forceinline__ float leaky(float x){ return x > 0.f ? x : 0.2f*x; }

// ---------------- utility kernels ----------------
__global__ void fill_i32(int* p, int v, int n){
    int i = blockIdx.x*blockDim.x + threadIdx.x;
    if (i < n) p[i] = v;
}

__global__ void count_dst(const int* __restrict__ dst, int* __restrict__ cnt, int E){
    int i = blockIdx.x*blockDim.x + threadIdx.x;
    if (i < E) atomicAdd(&cnt[dst[i]], 1);
}

__global__ void count_dst_valid(const int* __restrict__ s, const int* __restrict__ d,
                                int* __restrict__ cnt, int E){
    int i = blockIdx.x*blockDim.x + threadIdx.x;
    if (i < E){ int ss = s[i], dd = d[i]; if (ss >= 0 && dd >= 0) atomicAdd(&cnt[dd], 1); }
}

// single-block exclusive scan; cnt and cur may alias
__global__ void exscan_k(const int* cnt, int* rowptr, int* cur, int n){
    __shared__ int part[1024];
    int tid = threadIdx.x;
    int per = (n + 1023) >> 10;
    int base = tid * per;
    int s = 0;
    for (int i = 0; i < per; i++){ int idx = base + i; if (idx < n) s += cnt[idx]; }
    part[tid] = s;
    __syncthreads();
    for (int off = 1; off < 1024; off <<= 1){
        int v = (tid >= off) ? part[tid - off] : 0;
        __syncthreads();
        if (tid >= off) part[tid] += v;
        __syncthreads();
    }
    int run = (tid == 0) ? 0 : part[tid - 1];
    for (int i = 0; i < per; i++){
        int idx = base + i;
        if (idx < n){ int c = cnt[idx]; rowptr[idx] = run; cur[idx] = run; run += c; }
    }
    if (tid == 1023) rowptr[n] = part[1023];
}

__global__ void scatter1(const int* __restrict__ dst, int* __restrict__ cur,
                         int* __restrict__ eids, int E){
    int i = blockIdx.x*blockDim.x + threadIdx.x;
    if (i < E){ int p = atomicAdd(&cur[dst[i]], 1); eids[p] = i; }
}

__global__ void scatter2(const int* __restrict__ s, const int* __restrict__ d,
                         int* __restrict__ cur, int* __restrict__ eids, int E){
    int i = blockIdx.x*blockDim.x + threadIdx.x;
    if (i < E){
        int ss = s[i], dd = d[i];
        if (ss >= 0 && dd >= 0){ int p = atomicAdd(&cur[dd], 1); eids[p] = i; }
    }
}

__global__ void dinv_k(const int* __restrict__ rowptr, float* __restrict__ dinv, int n){
    int i = blockIdx.x*blockDim.x + threadIdx.x;
    if (i < n) dinv[i] = 1.0f / sqrtf((float)(rowptr[i+1] - rowptr[i]) + 1.0f);
}

// ---------------- fp32 tiled GEMM: C[n,M] = A[n,K] @ W[M,K]^T ----------------
// n,M multiples of 64; K multiple of 64
__global__ __launch_bounds__(256) void gemm_nt(const float* __restrict__ A,
                                               const float* __restrict__ W,
                                               float* __restrict__ C,
                                               int n, int K, int M){
    __shared__ float As[64][68];   // [k][row], float4-aligned stride (68*4=272=16*17)
    __shared__ float Ws[64][68];   // [k][col]
    int t = threadIdx.x;
    int tx = t & 15, ty = t >> 4;
    int row0 = blockIdx.x * 64, col0 = blockIdx.y * 64;
    float acc[4][4] = {};
    for (int kk = 0; kk < K; kk += 64){
        #pragma unroll
        for (int it = 0; it < 4; ++it){
            int r = ty + it*16;
            float4 av = *(const float4*)(A + (size_t)(row0 + r)*K + kk + tx*4);
            As[tx*4+0][r] = av.x; As[tx*4+1][r] = av.y; As[tx*4+2][r] = av.z; As[tx*4+3][r] = av.w;
            float4 wv = *(const float4*)(W + (size_t)(col0 + r)*K + kk + tx*4);
            Ws[tx*4+0][r] = wv.x; Ws[tx*4+1][r] = wv.y; Ws[tx*4+2][r] = wv.z; Ws[tx*4+3][r] = wv.w;
        }
        __syncthreads();
        #pragma unroll
        for (int k = 0; k < 64; k++){
            float4 a  = *(const float4*)&As[k][ty*4];
            float4 bv = *(const float4*)&Ws[k][tx*4];
            float ar[4] = {a.x, a.y, a.z, a.w};
            float br[4] = {bv.x, bv.y, bv.z, bv.w};
            #pragma unroll
            for (int i = 0; i < 4; i++)
                #pragma unroll
                for (int j = 0; j < 4; j++) acc[i][j] += ar[i]*br[j];
        }
        __syncthreads();
    }
    #pragma unroll
    for (int i = 0; i < 4; i++){
        float4 o; o.x = acc[i][0]; o.y = acc[i][1]; o.z = acc[i][2]; o.w = acc[i][3];
        *(float4*)(C + (size_t)(row0 + ty*4 + i)*M + col0 + tx*4) = o;
    }
}

// ---------------- GAT attention coefficients: asrc/adst per node,head -------
// h: [n,256]; ws/wd: [4,64] flattened = [256]; block 256 = 4 waves, 1 node/wave
__global__ void attn_pre(const float* __restrict__ h, const float* __restrict__ wsrc,
                         const float* __restrict__ wdst, float* __restrict__ as_,
                         float* __restrict__ ad_){
    int lane = threadIdx.x & 63;
    int w = threadIdx.x >> 6;
    int d = blockIdx.x*4 + w;
    float4 hv = *(const float4*)(h + (size_t)d*256 + lane*4);
    float4 ws = *(const float4*)(wsrc + lane*4);
    float4 wd = *(const float4*)(wdst + lane*4);
    float ps = hv.x*ws.x + hv.y*ws.y + hv.z*ws.z + hv.w*ws.w;
    float pd = hv.x*wd.x + hv.y*wd.y + hv.z*wd.z + hv.w*wd.w;
    #pragma unroll
    for (int m = 8; m; m >>= 1){ ps += __shfl_xor(ps, m); pd += __shfl_xor(pd, m); }
    if ((lane & 15) == 0){
        as_[d*4 + (lane >> 4)] = ps;
        ad_[d*4 + (lane >> 4)] = pd;
    }
}

// ---------------- GAT aggregation (softmax over in-edges + self loop) -------
// 1 wave per dst node, 4 waves/block; XCD-swizzled node order
template<int RELU>
__global__ void gat_agg(const float* __restrict__ h, const float* __restrict__ as_,
                        const float* __restrict__ ad_, const float* __restrict__ bias,
                        const int* __restrict__ rowptr, const int* __restrict__ eids,
                        const int* __restrict__ src, float* __restrict__ out){
    int lane = threadIdx.x & 63;
    int w = threadIdx.x >> 6;
    int nb = gridDim.x;
    int b = blockIdx.x;
    int sb = (b & 7)*(nb >> 3) + (b >> 3);   // bijective XCD swizzle (nb % 8 == 0)
    int d = sb*4 + w;
    int beg = rowptr[d], end = rowptr[d+1];

    float ad4[4], m[4], es[4];
    #pragma unroll
    for (int hh = 0; hh < 4; hh++) ad4[hh] = ad_[d*4 + hh];
    #pragma unroll
    for (int hh = 0; hh < 4; hh++){ es[hh] = leaky(as_[d*4 + hh] + ad4[hh]); m[hh] = es[hh]; }

    // pass 1: per-head max over in-edges
    for (int i = beg + lane; i < end; i += 64){
        int s = src[eids[i]];
        #pragma unroll
        for (int hh = 0; hh < 4; hh++) m[hh] = fmaxf(m[hh], leaky(as_[s*4 + hh] + ad4[hh]));
    }
    #pragma unroll
    for (int off = 32; off; off >>= 1)
        #pragma unroll
        for (int hh = 0; hh < 4; hh++) m[hh] = fmaxf(m[hh], __shfl_xor(m[hh], off));

    // pass 2: denominators
    float den[4] = {0.f, 0.f, 0.f, 0.f};
    for (int i = beg + lane; i < end; i += 64){
        int s = src[eids[i]];
        #pragma unroll
        for (int hh = 0; hh < 4; hh++) den[hh] += expf(leaky(as_[s*4 + hh] + ad4[hh]) - m[hh]);
    }
    #pragma unroll
    for (int off = 32; off; off >>= 1)
        #pragma unroll
        for (int hh = 0; hh < 4; hh++) den[hh] += __shfl_xor(den[hh], off);
    #pragma unroll
    for (int hh = 0; hh < 4; hh++) den[hh] += expf(es[hh] - m[hh]) + 1e-16f;

    // pass 3: weighted feature gather; lane owns channels c0..c0+3 (head = lane>>4)
    int hh = lane >> 4;
    int c0 = lane*4;
    float rden = 1.0f / den[hh];
    float mh = m[hh];
    float aself = expf(es[hh] - mh) * rden;
    float4 hd = *(const float4*)(h + (size_t)d*256 + c0);
    float4 acc;
    acc.x = aself*hd.x; acc.y = aself*hd.y; acc.z = aself*hd.z; acc.w = aself*hd.w;
    for (int i = beg; i < end; i++){
        int s = src[eids[i]];
        float al = expf(leaky(as_[s*4 + hh] + ad4[hh]) - mh) * rden;
        float4 hv = *(const float4*)(h + (size_t)s*256 + c0);
        acc.x += al*hv.x; acc.y += al*hv.y; acc.z += al*hv.z; acc.w += al*hv.w;
    }
    float4 bv = *(const float4*)(bias + c0);
    acc.x += bv.x; acc.y += bv.y; acc.z += bv.z; acc.w += bv.w;
    if (RELU){
        acc.x = fmaxf(acc.x, 0.f); acc.y = fmaxf(acc.y, 0.f);
        acc.z = fmaxf(acc.z, 0.f); acc.w = fmaxf(acc.w, 0.f);
    }
    *(float4*)(out + (size_t)d*256 + c0) = acc;
}

// ---------------- GCN aggregation (sym-norm, self loop, +bias, relu) --------
// 128 channels, 1 wave/node (2 ch/lane), 4 waves/block
__global__ void gcn_agg(const float* __restrict__ h, const float* __restrict__ dinv,
                        const float* __restrict__ bias, const int* __restrict__ rowptr,
                        const int* __restrict__ eids, const int* __restrict__ src,
                        float* __restrict__ out){
    int lane = threadIdx.x & 63;
    int w = threadIdx.x >> 6;
    int nb = gridDim.x;
    int b = blockIdx.x;
    int sb = (b & 7)*(nb >> 3) + (b >> 3);
    int d = sb*4 + w;
    int beg = rowptr[d], end = rowptr[d+1];
    float dv = dinv[d];
    int c0 = lane*2;
    float2 hd = *(const float2*)(h + (size_t)d*128 + c0);
    float self = dv*dv;
    float ax = self*hd.x, ay = self*hd.y;
    for (int i = beg; i < end; i++){
        int s = src[eids[i]];
        float coef = dinv[s]*dv;
        float2 hv = *(const float2*)(h + (size_t)s*128 + c0);
        ax += coef*hv.x; ay += coef*hv.y;
    }
    ax = fmaxf(ax + bias[c0], 0.f);
    ay = fmaxf(ay + bias[c0+1], 0.f);
    float2 o; o.x = ax; o.y = ay;
    *(float2*)(out + (size_t)d*128 + c0) = o;
}

// ---------------- SAGPool score: GraphConv(1) ---------------------------
__global__ void sag_score(const float* __restrict__ x, const float* __restrict__ wrel,
                          const float* __restrict__ brel, const float* __restrict__ wroot,
                          const int* __restrict__ rowptr, const int* __restrict__ eids,
                          const int* __restrict__ src, float* __restrict__ score){
    int lane = threadIdx.x & 63;
    int w = threadIdx.x >> 6;
    int nb = gridDim.x;
    int b = blockIdx.x;
    int sb = (b & 7)*(nb >> 3) + (b >> 3);
    int d = sb*4 + w;
    int beg = rowptr[d], end = rowptr[d+1];
    int c0 = lane*2;
    float aggx = 0.f, aggy = 0.f;
    for (int i = beg; i < end; i++){
        int s = src[eids[i]];
        float2 xv = *(const float2*)(x + (size_t)s*128 + c0);
        aggx += xv.x; aggy += xv.y;
    }
    float2 xd = *(const float2*)(x + (size_t)d*128 + c0);
    float part = aggx*wrel[c0] + aggy*wrel[c0+1] + xd.x*wroot[c0] + xd.y*wroot[c0+1];
    #pragma unroll
    for (int off = 32; off; off >>= 1) part += __shfl_xor(part, off);
    if (lane == 0) score[d] = part + brel[0];
}

// ---------------- per-graph top-k via in-LDS bitonic sort -------------------
__global__ void topk_k(const float* __restrict__ score, int npg, int k,
                       int* __restrict__ perm, float* __restrict__ ssort,
                       int* __restrict__ nid, int writeNid){
    __shared__ float ls[2048];
    __shared__ int   li[2048];
    int g = blockIdx.x, tid = threadIdx.x;
    for (int i = tid; i < npg; i += 256){ ls[i] = score[g*npg + i]; li[i] = i; }
    __syncthreads();
    for (int size = 2; size <= npg; size <<= 1){
        for (int stride = size >> 1; stride > 0; stride >>= 1){
            for (int i = tid; i < npg; i += 256){
                int j = i ^ stride;
                if (j > i){
                    bool desc = ((i & size) == 0);
                    float si = ls[i], sj = ls[j];
                    int   ii = li[i], ij = li[j];
                    bool i_after_j = (si < sj) || (si == sj && ii > ij);
                    bool sw = desc ? i_after_j : !i_after_j;
                    if (sw){ ls[i] = sj; ls[j] = si; li[i] = ij; li[j] = ii; }
                }
            }
            __syncthreads();
        }
    }
    for (int r = tid; r < k; r += 256){
        int idx = li[r];
        perm[g*k + r]  = g*npg + idx;
        ssort[g*k + r] = ls[r];
        if (writeNid) nid[g*npg + idx] = g*k + r;
    }
}

__global__ void edge_remap(const int* __restrict__ s, const int* __restrict__ d,
                           const int* __restrict__ nid, int* __restrict__ ns,
                           int* __restrict__ nd, int E){
    int i = blockIdx.x*blockDim.x + threadIdx.x;
    if (i < E){ ns[i] = nid[s[i]]; nd[i] = nid[d[i]]; }
}

__global__ void pool_gather(const float* __restrict__ x, const int* __restrict__ perm,
                            const float* __restrict__ ssort, float* __restrict__ xn){
    int j = blockIdx.x; int c = threadIdx.x;   // 128 threads
    int o = perm[j];
    float t = tanhf(ssort[j]);
    xn[(size_t)j*128 + c] = x[(size_t)o*128 + c] * t;
}

__global__ void pool_mean(const float* __restrict__ x, float* __restrict__ g){
    int b = blockIdx.x, c = threadIdx.x;       // 128 threads
    float s = 0.f;
    for (int i = 0; i < KK2; i++) s += x[((size_t)b*KK2 + i)*128 + c];
    g[b*128 + c] = s * (1.0f/KK2);
}

__global__ void mlp_k(const float* __restrict__ g,
                      const float* __restrict__ fc1w, const float* __restrict__ fc1b,
                      const float* __restrict__ fc2w, const float* __restrict__ fc2b,
                      const float* __restrict__ ow,  const float* __restrict__ ob,
                      float* __restrict__ out){
    __shared__ float gv[128], t1[256], t2[128];
    int b = blockIdx.x, t = threadIdx.x;       // 256 threads
    if (t < 128) gv[t] = g[b*128 + t];
    __syncthreads();
    {
        float s = fc1b[t];
        for (int c = 0; c < 128; c++) s += gv[c]*fc1w[t*128 + c];
        t1[t] = fmaxf(s, 0.f);
    }
    __syncthreads();
    if (t < 128){
        float s = fc2b[t];
        for (int c = 0; c < 256; c++) s += t1[c]*fc2w[t*256 + c];
        t2[t] = fmaxf(s, 0.f);
    }
    __syncthreads();
    if (t < 10){
        float s = ob[t];
        for (int c = 0; c < 128; c++) s += t2[c]*ow[t*128 + c];
        out[b*10 + t] = s;
    }
}

// ---------------- launch ----------------
extern "C" void kernel_launch(void* const* d_in, const int* in_sizes, int n_in,
                              void* d_out, int out_size, void* d_ws, size_t ws_size,
                              hipStream_t stream){
    (void)in_sizes; (void)n_in; (void)out_size; (void)ws_size;
    const float* x    = (const float*)d_in[0];
    const int*   eidx = (const int*)d_in[1];
    const int*   src  = eidx;
    const int*   dst  = eidx + EE;
    const float* g1w  = (const float*)d_in[3];
    const float* g1as = (const float*)d_in[4];
    const float* g1ad = (const float*)d_in[5];
    const float* g1b  = (const float*)d_in[6];
    const float* g2w  = (const float*)d_in[7];
    const float* g2as = (const float*)d_in[8];
    const float* g2ad = (const float*)d_in[9];
    const float* g2b  = (const float*)d_in[10];
    const float* c1w  = (const float*)d_in[11];
    const float* c1b  = (const float*)d_in[12];
    const float* s1wrel  = (const float*)d_in[13];
    const float* s1brel  = (const float*)d_in[14];
    const float* s1wroot = (const float*)d_in[15];
    const float* c2w  = (const float*)d_in[16];
    const float* c2b  = (const float*)d_in[17];
    const float* s2wrel  = (const float*)d_in[18];
    const float* s2brel  = (const float*)d_in[19];
    const float* s2wroot = (const float*)d_in[20];
    const float* f1w  = (const float*)d_in[21];
    const float* f1b  = (const float*)d_in[22];
    const float* f2w  = (const float*)d_in[23];
    const float* f2b  = (const float*)d_in[24];
    const float* ow   = (const float*)d_in[25];
    const float* ob   = (const float*)d_in[26];
    float* out = (float*)d_out;

    char* ws = (char*)d_ws;
    size_t off = 0;
    auto alloc = [&](size_t bytes)->char*{
        char* p = ws + off;
        off += (bytes + 255) & ~(size_t)255;
        return p;
    };
    float* F0     = (float*)alloc((size_t)N1*256*4);
    float* F1     = (float*)alloc((size_t)N1*256*4);
    float* F2     = (float*)alloc((size_t)N2*128*4);
    float* AS     = (float*)alloc((size_t)N1*4*4);
    float* AD     = (float*)alloc((size_t)N1*4*4);
    int*   RP     = (int*)  alloc((size_t)(N1+1)*4);
    int*   CUR    = (int*)  alloc((size_t)N1*4);
    int*   EL     = (int*)  alloc((size_t)EE*4);
    float* DINV   = (float*)alloc((size_t)N1*4);
    float* SCORE  = (float*)alloc((size_t)N1*4);
    int*   PERM1  = (int*)  alloc((size_t)N2*4);
    float* SSORT1 = (float*)alloc((size_t)N2*4);
    int*   NID    = (int*)  alloc((size_t)N1*4);
    int*   E1S    = (int*)  alloc((size_t)EE*4);
    int*   E1D    = (int*)  alloc((size_t)EE*4);
    int*   RP2    = (int*)  alloc((size_t)(N2+1)*4);
    int*   CUR2   = (int*)  alloc((size_t)N2*4);
    int*   EL2    = (int*)  alloc((size_t)EE*4);
    float* DINV2  = (float*)alloc((size_t)N2*4);
    int*   PERM2  = (int*)  alloc((size_t)N3*4);
    float* SSORT2 = (float*)alloc((size_t)N3*4);
    float* GBUF   = (float*)alloc((size_t)NB*128*4);

    // ---- level-1 CSR (by dst) ----
    fill_i32<<<N1/256, 256, 0, stream>>>(CUR, 0, N1);
    count_dst<<<EE/256, 256, 0, stream>>>(dst, CUR, EE);
    exscan_k<<<1, 1024, 0, stream>>>(CUR, RP, CUR, N1);
    scatter1<<<EE/256, 256, 0, stream>>>(dst, CUR, EL, EE);

    // ---- GAT layer 1 (64 -> 4x64, relu) ----
    gemm_nt<<<dim3(N1/64, 4), 256, 0, stream>>>(x, g1w, F0, N1, 64, 256);
    attn_pre<<<N1/4, 256, 0, stream>>>(F0, g1as, g1ad, AS, AD);
    gat_agg<1><<<N1/4, 256, 0, stream>>>(F0, AS, AD, g1b, RP, EL, src, F1);

    // ---- GAT layer 2 (256 -> 4x64) ----
    gemm_nt<<<dim3(N1/64, 4), 256, 0, stream>>>(F1, g2w, F0, N1, 256, 256);
    attn_pre<<<N1/4, 256, 0, stream>>>(F0, g2as, g2ad, AS, AD);
    gat_agg<0><<<N1/4, 256, 0, stream>>>(F0, AS, AD, g2b, RP, EL, src, F1);

    // ---- GCN1 (256 -> 128, relu) ----
    gemm_nt<<<dim3(N1/64, 2), 256, 0, stream>>>(F1, c1w, F0, N1, 256, 128);
    dinv_k<<<N1/256, 256, 0, stream>>>(RP, DINV, N1);
    gcn_agg<<<N1/4, 256, 0, stream>>>(F0, DINV, c1b, RP, EL, src, F1);

    // ---- SAGPool1 ----
    sag_score<<<N1/4, 256, 0, stream>>>(F1, s1wrel, s1brel, s1wroot, RP, EL, src, SCORE);
    fill_i32<<<N1/256, 256, 0, stream>>>(NID, -1, N1);
    topk_k<<<NB, 256, 0, stream>>>(SCORE, NPG1, KK1, PERM1, SSORT1, NID, 1);
    pool_gather<<<N2, 128, 0, stream>>>(F1, PERM1, SSORT1, F0);          // x2 -> F0
    edge_remap<<<EE/256, 256, 0, stream>>>(src, dst, NID, E1S, E1D, EE);

    // ---- level-2 CSR (valid edges only) ----
    fill_i32<<<N2/256, 256, 0, stream>>>(CUR2, 0, N2);
    count_dst_valid<<<EE/256, 256, 0, stream>>>(E1S, E1D, CUR2, EE);
    exscan_k<<<1, 1024, 0, stream>>>(CUR2, RP2, CUR2, N2);
    scatter2<<<EE/256, 256, 0, stream>>>(E1S, E1D, CUR2, EL2, EE);

    // ---- GCN2 (128 -> 128, relu) ----
    gemm_nt<<<dim3(N2/64, 2), 256, 0, stream>>>(F0, c2w, F1, N2, 128, 128);
    dinv_k<<<N2/256, 256, 0, stream>>>(RP2, DINV2, N2);
    gcn_agg<<<N2/4, 256, 0, stream>>>(F1, DINV2, c2b, RP2, EL2, E1S, F2);

    // ---- SAGPool2 ----
    sag_score<<<N2/4, 256, 0, stream>>>(F2, s2wrel, s2brel, s2wroot, RP2, EL2, E1S, SCORE);
    topk_k<<<NB, 256, 0, stream>>>(SCORE, NPG2, KK2, PERM2, SSORT2, nullptr, 0);
    pool_gather<<<N3, 128, 0, stream>>>(F2, PERM2, SSORT2, F0);          // x3 -> F0

    // ---- mean pool + MLP ----
    pool_mean<<<NB, 128, 0, stream>>>(F0, GBUF);
    mlp_k<<<NB, 256, 0, stream>>>(GBUF, f1w, f1b, f2w, f2b, ow, ob, out);
}

// Round 2
// 585.483 us; speedup vs baseline: 1.3064x; 1.3064x over previous
//
#include <hip/hip_runtime.h>

#define N1 32768
#define EE 524288
#define NB 16
#define NPG1 2048
#define KK1 1024
#define N2 16384
#define NPG2 1024
#define KK2 512
#define N3 8192

static __device__ __forceinline__ float leaky(float x){ return x > 0.f ? x : 0.2f*x; }

// ---------------- utility kernels ----------------
__global__ void fill_i32(int* p, int v, int n){
    int i = blockIdx.x*blockDim.x + threadIdx.x;
    if (i < n) p[i] = v;
}

__global__ void count_dst(const int* __restrict__ dst, int* __restrict__ cnt, int E){
    int i = blockIdx.x*blockDim.x + threadIdx.x;
    if (i < E) atomicAdd(&cnt[dst[i]], 1);
}

__global__ void count_dst_valid(const int* __restrict__ s, const int* __restrict__ d,
                                int* __restrict__ cnt, int E){
    int i = blockIdx.x*blockDim.x + threadIdx.x;
    if (i < E){ int ss = s[i], dd = d[i]; if (ss >= 0 && dd >= 0) atomicAdd(&cnt[dd], 1); }
}

// ---- hierarchical scan: partial sums then per-block rescan+write ----
__global__ void blocksum_k(const int* __restrict__ cnt, int* __restrict__ bs){
    __shared__ int red[4];
    int tid = threadIdx.x;
    int v = cnt[blockIdx.x*256 + tid];
    #pragma unroll
    for (int off = 32; off; off >>= 1) v += __shfl_xor(v, off);
    if ((tid & 63) == 0) red[tid >> 6] = v;
    __syncthreads();
    if (tid == 0) bs[blockIdx.x] = red[0] + red[1] + red[2] + red[3];
}

// cnt may alias cur (each thread reads its own slot before writing)
__global__ void scan_write_k(const int* __restrict__ cnt, const int* __restrict__ bs,
                             int nb, int* __restrict__ rowptr, int* __restrict__ cur, int n){
    __shared__ int sbs[128];
    __shared__ int wsum[4];
    int tid = threadIdx.x;
    int b = blockIdx.x;
    if (tid < nb) sbs[tid] = bs[tid];
    __syncthreads();
    for (int off = 1; off < nb; off <<= 1){
        int v = 0;
        if (tid < nb && tid >= off) v = sbs[tid - off];
        __syncthreads();
        if (tid < nb) sbs[tid] += v;
        __syncthreads();
    }
    int base = (b == 0) ? 0 : sbs[b-1];
    int i = b*256 + tid;
    int c = cnt[i];
    int lane = tid & 63, wv = tid >> 6;
    int x = c;
    #pragma unroll
    for (int off = 1; off < 64; off <<= 1){ int y = __shfl_up(x, off); if (lane >= off) x += y; }
    if (lane == 63) wsum[wv] = x;
    __syncthreads();
    if (tid == 0){ int run = 0; for (int w2 = 0; w2 < 4; w2++){ int t = wsum[w2]; wsum[w2] = run; run += t; } }
    __syncthreads();
    int excl = x - c + wsum[wv];
    rowptr[i] = base + excl;
    cur[i]    = base + excl;
    if (i == n-1) rowptr[n] = base + excl + c;
}

__global__ void scatter1(const int* __restrict__ dst, int* __restrict__ cur,
                         int* __restrict__ eids, int E){
    int i = blockIdx.x*blockDim.x + threadIdx.x;
    if (i < E){ int p = atomicAdd(&cur[dst[i]], 1); eids[p] = i; }
}

__global__ void scatter2(const int* __restrict__ s, const int* __restrict__ d,
                         int* __restrict__ cur, int* __restrict__ eids, int E){
    int i = blockIdx.x*blockDim.x + threadIdx.x;
    if (i < E){
        int ss = s[i], dd = d[i];
        if (ss >= 0 && dd >= 0){ int p = atomicAdd(&cur[dd], 1); eids[p] = i; }
    }
}

__global__ void dinv_k(const int* __restrict__ rowptr, float* __restrict__ dinv, int n){
    int i = blockIdx.x*blockDim.x + threadIdx.x;
    if (i < n) dinv[i] = 1.0f / sqrtf((float)(rowptr[i+1] - rowptr[i]) + 1.0f);
}

// ---------------- fp32 tiled GEMM: C[n,M] = A[n,K] @ W[M,K]^T ----------------
__global__ __launch_bounds__(256) void gemm_nt(const float* __restrict__ A,
                                               const float* __restrict__ W,
                                               float* __restrict__ C,
                                               int n, int K, int M){
    __shared__ float As[64][68];
    __shared__ float Ws[64][68];
    int t = threadIdx.x;
    int tx = t & 15, ty = t >> 4;
    int row0 = blockIdx.x * 64, col0 = blockIdx.y * 64;
    float acc[4][4] = {};
    for (int kk = 0; kk < K; kk += 64){
        #pragma unroll
        for (int it = 0; it < 4; ++it){
            int r = ty + it*16;
            float4 av = *(const float4*)(A + (size_t)(row0 + r)*K + kk + tx*4);
            As[tx*4+0][r] = av.x; As[tx*4+1][r] = av.y; As[tx*4+2][r] = av.z; As[tx*4+3][r] = av.w;
            float4 wv = *(const float4*)(W + (size_t)(col0 + r)*K + kk + tx*4);
            Ws[tx*4+0][r] = wv.x; Ws[tx*4+1][r] = wv.y; Ws[tx*4+2][r] = wv.z; Ws[tx*4+3][r] = wv.w;
        }
        __syncthreads();
        #pragma unroll
        for (int k = 0; k < 64; k++){
            float4 a  = *(const float4*)&As[k][ty*4];
            float4 bv = *(const float4*)&Ws[k][tx*4];
            float ar[4] = {a.x, a.y, a.z, a.w};
            float br[4] = {bv.x, bv.y, bv.z, bv.w};
            #pragma unroll
            for (int i = 0; i < 4; i++)
                #pragma unroll
                for (int j = 0; j < 4; j++) acc[i][j] += ar[i]*br[j];
        }
        __syncthreads();
    }
    #pragma unroll
    for (int i = 0; i < 4; i++){
        float4 o; o.x = acc[i][0]; o.y = acc[i][1]; o.z = acc[i][2]; o.w = acc[i][3];
        *(float4*)(C + (size_t)(row0 + ty*4 + i)*M + col0 + tx*4) = o;
    }
}

// ---------------- GAT attention coefficients ----------------
__global__ void attn_pre(const float* __restrict__ h, const float* __restrict__ wsrc,
                         const float* __restrict__ wdst, float* __restrict__ as_,
                         float* __restrict__ ad_){
    int lane = threadIdx.x & 63;
    int w = threadIdx.x >> 6;
    int d = blockIdx.x*4 + w;
    float4 hv = *(const float4*)(h + (size_t)d*256 + lane*4);
    float4 ws = *(const float4*)(wsrc + lane*4);
    float4 wd = *(const float4*)(wdst + lane*4);
    float ps = hv.x*ws.x + hv.y*ws.y + hv.z*ws.z + hv.w*ws.w;
    float pd = hv.x*wd.x + hv.y*wd.y + hv.z*wd.z + hv.w*wd.w;
    #pragma unroll
    for (int m = 8; m; m >>= 1){ ps += __shfl_xor(ps, m); pd += __shfl_xor(pd, m); }
    if ((lane & 15) == 0){
        as_[d*4 + (lane >> 4)] = ps;
        ad_[d*4 + (lane >> 4)] = pd;
    }
}

// ---------------- GAT aggregation ----------------
template<int RELU>
__global__ void gat_agg(const float* __restrict__ h, const float* __restrict__ as_,
                        const float* __restrict__ ad_, const float* __restrict__ bias,
                        const int* __restrict__ rowptr, const int* __restrict__ eids,
                        const int* __restrict__ src, float* __restrict__ out){
    int lane = threadIdx.x & 63;
    int w = threadIdx.x >> 6;
    int nb = gridDim.x;
    int b = blockIdx.x;
    int sb = (b & 7)*(nb >> 3) + (b >> 3);
    int d = sb*4 + w;
    int beg = rowptr[d], end = rowptr[d+1];

    float ad4[4], m[4], es[4];
    #pragma unroll
    for (int hh = 0; hh < 4; hh++) ad4[hh] = ad_[d*4 + hh];
    #pragma unroll
    for (int hh = 0; hh < 4; hh++){ es[hh] = leaky(as_[d*4 + hh] + ad4[hh]); m[hh] = es[hh]; }

    for (int i = beg + lane; i < end; i += 64){
        int s = src[eids[i]];
        #pragma unroll
        for (int hh = 0; hh < 4; hh++) m[hh] = fmaxf(m[hh], leaky(as_[s*4 + hh] + ad4[hh]));
    }
    #pragma unroll
    for (int off = 32; off; off >>= 1)
        #pragma unroll
        for (int hh = 0; hh < 4; hh++) m[hh] = fmaxf(m[hh], __shfl_xor(m[hh], off));

    float den[4] = {0.f, 0.f, 0.f, 0.f};
    for (int i = beg + lane; i < end; i += 64){
        int s = src[eids[i]];
        #pragma unroll
        for (int hh = 0; hh < 4; hh++) den[hh] += expf(leaky(as_[s*4 + hh] + ad4[hh]) - m[hh]);
    }
    #pragma unroll
    for (int off = 32; off; off >>= 1)
        #pragma unroll
        for (int hh = 0; hh < 4; hh++) den[hh] += __shfl_xor(den[hh], off);
    #pragma unroll
    for (int hh = 0; hh < 4; hh++) den[hh] += expf(es[hh] - m[hh]) + 1e-16f;

    int hh = lane >> 4;
    int c0 = lane*4;
    float rden = 1.0f / den[hh];
    float mh = m[hh];
    float aself = expf(es[hh] - mh) * rden;
    float4 hd = *(const float4*)(h + (size_t)d*256 + c0);
    float4 acc;
    acc.x = aself*hd.x; acc.y = aself*hd.y; acc.z = aself*hd.z; acc.w = aself*hd.w;
    for (int i = beg; i < end; i++){
        int s = src[eids[i]];
        float al = expf(leaky(as_[s*4 + hh] + ad4[hh]) - mh) * rden;
        float4 hv = *(const float4*)(h + (size_t)s*256 + c0);
        acc.x += al*hv.x; acc.y += al*hv.y; acc.z += al*hv.z; acc.w += al*hv.w;
    }
    float4 bv = *(const float4*)(bias + c0);
    acc.x += bv.x; acc.y += bv.y; acc.z += bv.z; acc.w += bv.w;
    if (RELU){
        acc.x = fmaxf(acc.x, 0.f); acc.y = fmaxf(acc.y, 0.f);
        acc.z = fmaxf(acc.z, 0.f); acc.w = fmaxf(acc.w, 0.f);
    }
    *(float4*)(out + (size_t)d*256 + c0) = acc;
}

// ---------------- GCN aggregation ----------------
__global__ void gcn_agg(const float* __restrict__ h, const float* __restrict__ dinv,
                        const float* __restrict__ bias, const int* __restrict__ rowptr,
                        const int* __restrict__ eids, const int* __restrict__ src,
                        float* __restrict__ out){
    int lane = threadIdx.x & 63;
    int w = threadIdx.x >> 6;
    int nb = gridDim.x;
    int b = blockIdx.x;
    int sb = (b & 7)*(nb >> 3) + (b >> 3);
    int d = sb*4 + w;
    int beg = rowptr[d], end = rowptr[d+1];
    float dv = dinv[d];
    int c0 = lane*2;
    float2 hd = *(const float2*)(h + (size_t)d*128 + c0);
    float self = dv*dv;
    float ax = self*hd.x, ay = self*hd.y;
    for (int i = beg; i < end; i++){
        int s = src[eids[i]];
        float coef = dinv[s]*dv;
        float2 hv = *(const float2*)(h + (size_t)s*128 + c0);
        ax += coef*hv.x; ay += coef*hv.y;
    }
    ax = fmaxf(ax + bias[c0], 0.f);
    ay = fmaxf(ay + bias[c0+1], 0.f);
    float2 o; o.x = ax; o.y = ay;
    *(float2*)(out + (size_t)d*128 + c0) = o;
}

// ---------------- SAGPool score ----------------
__global__ void sag_score(const float* __restrict__ x, const float* __restrict__ wrel,
                          const float* __restrict__ brel, const float* __restrict__ wroot,
                          const int* __restrict__ rowptr, const int* __restrict__ eids,
                          const int* __restrict__ src, float* __restrict__ score){
    int lane = threadIdx.x & 63;
    int w = threadIdx.x >> 6;
    int nb = gridDim.x;
    int b = blockIdx.x;
    int sb = (b & 7)*(nb >> 3) + (b >> 3);
    int d = sb*4 + w;
    int beg = rowptr[d], end = rowptr[d+1];
    int c0 = lane*2;
    float aggx = 0.f, aggy = 0.f;
    for (int i = beg; i < end; i++){
        int s = src[eids[i]];
        float2 xv = *(const float2*)(x + (size_t)s*128 + c0);
        aggx += xv.x; aggy += xv.y;
    }
    float2 xd = *(const float2*)(x + (size_t)d*128 + c0);
    float part = aggx*wrel[c0] + aggy*wrel[c0+1] + xd.x*wroot[c0] + xd.y*wroot[c0+1];
    #pragma unroll
    for (int off = 32; off; off >>= 1) part += __shfl_xor(part, off);
    if (lane == 0) score[d] = part + brel[0];
}

// ---------------- radix-select top-k (k-th largest threshold + compaction) --
// one block per graph, 1024 threads, npg <= 2048, deterministic tie-break by index
__global__ __launch_bounds__(1024) void topk_sel(const float* __restrict__ score,
        int npg, int k, int* __restrict__ perm, float* __restrict__ ssort,
        int* __restrict__ nid, int writeNid){
    __shared__ unsigned keys[2048];
    __shared__ int hist[256];
    __shared__ int cge[256];
    __shared__ int warpsum[16];
    __shared__ int s_bin, s_need;
    int g = blockIdx.x, tid = threadIdx.x;
    for (int i = tid; i < npg; i += 1024){
        unsigned u = __float_as_uint(score[g*npg + i]);
        u = (u & 0x80000000u) ? ~u : (u | 0x80000000u);   // order-preserving map
        keys[i] = u;
    }
    if (tid == 0) s_need = k;
    __syncthreads();
    unsigned prefix = 0u, pmask = 0u;
    #pragma unroll
    for (int shift = 24; shift >= 0; shift -= 8){
        if (tid < 256) hist[tid] = 0;
        __syncthreads();
        for (int i = tid; i < npg; i += 1024){
            unsigned u = keys[i];
            if ((u & pmask) == prefix) atomicAdd(&hist[(u >> shift) & 255u], 1);
        }
        __syncthreads();
        if (tid < 256) cge[tid] = hist[tid];
        __syncthreads();
        for (int off = 1; off < 256; off <<= 1){         // suffix sums (count >= bin)
            int v = 0;
            if (tid < 256 - off) v = cge[tid + off];
            __syncthreads();
            if (tid < 256) cge[tid] += v;
            __syncthreads();
        }
        int need = s_need;
        if (tid < 256){
            int above = (tid == 255) ? 0 : cge[tid + 1];
            if (cge[tid] >= need && above < need) s_bin = tid;  // unique crossing
        }
        __syncthreads();
        if (tid == 0) s_need = need - ((s_bin == 255) ? 0 : cge[s_bin + 1]);
        __syncthreads();
        prefix |= ((unsigned)s_bin) << shift;
        pmask  |= (255u << shift);
        __syncthreads();
    }
    unsigned thr = prefix;
    int m = s_need;            // how many key==thr to take, lowest index first
    int i0 = 2*tid, i1 = 2*tid + 1;
    int f0 = 0, f1 = 0;
    if (i0 < npg){
        unsigned u = keys[i0];
        if (u > thr) f0 = 1;
        else if (u == thr){
            int r = 0;
            for (int j = 0; j < i0; j++) r += (keys[j] == thr);
            f0 = (r < m) ? 1 : 0;
        }
    }
    if (i1 < npg){
        unsigned u = keys[i1];
        if (u > thr) f1 = 1;
        else if (u == thr){
            int r = 0;
            for (int j = 0; j < i1; j++) r += (keys[j] == thr);
            f1 = (r < m) ? 1 : 0;
        }
    }
    int pair = f0 + f1;
    int lane = tid & 63, wv = tid >> 6;
    int x = pair;
    #pragma unroll
    for (int off = 1; off < 64; off <<= 1){ int y = __shfl_up(x, off); if (lane >= off) x += y; }
    if (lane == 63) warpsum[wv] = x;
    __syncthreads();
    if (tid == 0){ int run = 0; for (int w2 = 0; w2 < 16; w2++){ int t = warpsum[w2]; warpsum[w2] = run; run += t; } }
    __syncthreads();
    int excl = x - pair + warpsum[wv];
    if (f0){
        int pos = excl;
        int node = g*npg + i0;
        perm[g*k + pos] = node;
        ssort[g*k + pos] = score[node];
        if (writeNid) nid[node] = g*k + pos;
    }
    if (f1){
        int pos = excl + f0;
        int node = g*npg + i1;
        perm[g*k + pos] = node;
        ssort[g*k + pos] = score[node];
        if (writeNid) nid[node] = g*k + pos;
    }
}

__global__ void edge_remap(const int* __restrict__ s, const int* __restrict__ d,
                           const int* __restrict__ nid, int* __restrict__ ns,
                           int* __restrict__ nd, int E){
    int i = blockIdx.x*blockDim.x + threadIdx.x;
    if (i < E){ ns[i] = nid[s[i]]; nd[i] = nid[d[i]]; }
}

__global__ void pool_gather(const float* __restrict__ x, const int* __restrict__ perm,
                            const float* __restrict__ ssort, float* __restrict__ xn){
    int j = blockIdx.x; int c = threadIdx.x;
    int o = perm[j];
    float t = tanhf(ssort[j]);
    xn[(size_t)j*128 + c] = x[(size_t)o*128 + c] * t;
}

__global__ void pool_mean(const float* __restrict__ x, float* __restrict__ g){
    int b = blockIdx.x, c = threadIdx.x;
    float s = 0.f;
    for (int i = 0; i < KK2; i++) s += x[((size_t)b*KK2 + i)*128 + c];
    g[b*128 + c] = s * (1.0f/KK2);
}

__global__ void mlp_k(const float* __restrict__ g,
                      const float* __restrict__ fc1w, const float* __restrict__ fc1b,
                      const float* __restrict__ fc2w, const float* __restrict__ fc2b,
                      const float* __restrict__ ow,  const float* __restrict__ ob,
                      float* __restrict__ out){
    __shared__ float gv[128], t1[256], t2[128];
    int b = blockIdx.x, t = threadIdx.x;
    if (t < 128) gv[t] = g[b*128 + t];
    __syncthreads();
    {
        float s = fc1b[t];
        for (int c = 0; c < 128; c++) s += gv[c]*fc1w[t*128 + c];
        t1[t] = fmaxf(s, 0.f);
    }
    __syncthreads();
    if (t < 128){
        float s = fc2b[t];
        for (int c = 0; c < 256; c++) s += t1[c]*fc2w[t*256 + c];
        t2[t] = fmaxf(s, 0.f);
    }
    __syncthreads();
    if (t < 10){
        float s = ob[t];
        for (int c = 0; c < 128; c++) s += t2[c]*ow[t*128 + c];
        out[b*10 + t] = s;
    }
}

// ---------------- launch ----------------
extern "C" void kernel_launch(void* const* d_in, const int* in_sizes, int n_in,
                              void* d_out, int out_size, void* d_ws, size_t ws_size,
                              hipStream_t stream){
    (void)in_sizes; (void)n_in; (void)out_size; (void)ws_size;
    const float* x    = (const float*)d_in[0];
    const int*   eidx = (const int*)d_in[1];
    const int*   src  = eidx;
    const int*   dst  = eidx + EE;
    const float* g1w  = (const float*)d_in[3];
    const float* g1as = (const float*)d_in[4];
    const float* g1ad = (const float*)d_in[5];
    const float* g1b  = (const float*)d_in[6];
    const float* g2w  = (const float*)d_in[7];
    const float* g2as = (const float*)d_in[8];
    const float* g2ad = (const float*)d_in[9];
    const float* g2b  = (const float*)d_in[10];
    const float* c1w  = (const float*)d_in[11];
    const float* c1b  = (const float*)d_in[12];
    const float* s1wrel  = (const float*)d_in[13];
    const float* s1brel  = (const float*)d_in[14];
    const float* s1wroot = (const float*)d_in[15];
    const float* c2w  = (const float*)d_in[16];
    const float* c2b  = (const float*)d_in[17];
    const float* s2wrel  = (const float*)d_in[18];
    const float* s2brel  = (const float*)d_in[19];
    const float* s2wroot = (const float*)d_in[20];
    const float* f1w  = (const float*)d_in[21];
    const float* f1b  = (const float*)d_in[22];
    const float* f2w  = (const float*)d_in[23];
    const float* f2b  = (const float*)d_in[24];
    const float* ow   = (const float*)d_in[25];
    const float* ob   = (const float*)d_in[26];
    float* out = (float*)d_out;

    char* ws = (char*)d_ws;
    size_t off = 0;
    auto alloc = [&](size_t bytes)->char*{
        char* p = ws + off;
        off += (bytes + 255) & ~(size_t)255;
        return p;
    };
    float* F0     = (float*)alloc((size_t)N1*256*4);
    float* F1     = (float*)alloc((size_t)N1*256*4);
    float* F2     = (float*)alloc((size_t)N2*128*4);
    float* AS     = (float*)alloc((size_t)N1*4*4);
    float* AD     = (float*)alloc((size_t)N1*4*4);
    int*   RP     = (int*)  alloc((size_t)(N1+1)*4);
    int*   CUR    = (int*)  alloc((size_t)N1*4);
    int*   EL     = (int*)  alloc((size_t)EE*4);
    float* DINV   = (float*)alloc((size_t)N1*4);
    float* SCORE  = (float*)alloc((size_t)N1*4);
    int*   PERM1  = (int*)  alloc((size_t)N2*4);
    float* SSORT1 = (float*)alloc((size_t)N2*4);
    int*   NID    = (int*)  alloc((size_t)N1*4);
    int*   E1S    = (int*)  alloc((size_t)EE*4);
    int*   E1D    = (int*)  alloc((size_t)EE*4);
    int*   RP2    = (int*)  alloc((size_t)(N2+1)*4);
    int*   CUR2   = (int*)  alloc((size_t)N2*4);
    int*   EL2    = (int*)  alloc((size_t)EE*4);
    float* DINV2  = (float*)alloc((size_t)N2*4);
    int*   PERM2  = (int*)  alloc((size_t)N3*4);
    float* SSORT2 = (float*)alloc((size_t)N3*4);
    float* GBUF   = (float*)alloc((size_t)NB*128*4);
    int*   BS     = (int*)  alloc((size_t)128*4);

    // ---- level-1 CSR (by dst) ----
    fill_i32<<<N1/256, 256, 0, stream>>>(CUR, 0, N1);
    count_dst<<<EE/256, 256, 0, stream>>>(dst, CUR, EE);
    blocksum_k<<<N1/256, 256, 0, stream>>>(CUR, BS);
    scan_write_k<<<N1/256, 256, 0, stream>>>(CUR, BS, N1/256, RP, CUR, N1);
    scatter1<<<EE/256, 256, 0, stream>>>(dst, CUR, EL, EE);

    // ---- GAT layer 1 (64 -> 4x64, relu) ----
    gemm_nt<<<dim3(N1/64, 4), 256, 0, stream>>>(x, g1w, F0, N1, 64, 256);
    attn_pre<<<N1/4, 256, 0, stream>>>(F0, g1as, g1ad, AS, AD);
    gat_agg<1><<<N1/4, 256, 0, stream>>>(F0, AS, AD, g1b, RP, EL, src, F1);

    // ---- GAT layer 2 (256 -> 4x64) ----
    gemm_nt<<<dim3(N1/64, 4), 256, 0, stream>>>(F1, g2w, F0, N1, 256, 256);
    attn_pre<<<N1/4, 256, 0, stream>>>(F0, g2as, g2ad, AS, AD);
    gat_agg<0><<<N1/4, 256, 0, stream>>>(F0, AS, AD, g2b, RP, EL, src, F1);

    // ---- GCN1 (256 -> 128, relu) ----
    gemm_nt<<<dim3(N1/64, 2), 256, 0, stream>>>(F1, c1w, F0, N1, 256, 128);
    dinv_k<<<N1/256, 256, 0, stream>>>(RP, DINV, N1);
    gcn_agg<<<N1/4, 256, 0, stream>>>(F0, DINV, c1b, RP, EL, src, F1);

    // ---- SAGPool1 ----
    sag_score<<<N1/4, 256, 0, stream>>>(F1, s1wrel, s1brel, s1wroot, RP, EL, src, SCORE);
    fill_i32<<<N1/256, 256, 0, stream>>>(NID, -1, N1);
    topk_sel<<<NB, 1024, 0, stream>>>(SCORE, NPG1, KK1, PERM1, SSORT1, NID, 1);
    pool_gather<<<N2, 128, 0, stream>>>(F1, PERM1, SSORT1, F0);          // x2 -> F0
    edge_remap<<<EE/256, 256, 0, stream>>>(src, dst, NID, E1S, E1D, EE);

    // ---- level-2 CSR (valid edges only) ----
    fill_i32<<<N2/256, 256, 0, stream>>>(CUR2, 0, N2);
    count_dst_valid<<<EE/256, 256, 0, stream>>>(E1S, E1D, CUR2, EE);
    blocksum_k<<<N2/256, 256, 0, stream>>>(CUR2, BS);
    scan_write_k<<<N2/256, 256, 0, stream>>>(CUR2, BS, N2/256, RP2, CUR2, N2);
    scatter2<<<EE/256, 256, 0, stream>>>(E1S, E1D, CUR2, EL2, EE);

    // ---- GCN2 (128 -> 128, relu) ----
    gemm_nt<<<dim3(N2/64, 2), 256, 0, stream>>>(F0, c2w, F1, N2, 128, 128);
    dinv_k<<<N2/256, 256, 0, stream>>>(RP2, DINV2, N2);
    gcn_agg<<<N2/4, 256, 0, stream>>>(F1, DINV2, c2b, RP2, EL2, E1S, F2);

    // ---- SAGPool2 ----
    sag_score<<<N2/4, 256, 0, stream>>>(F2, s2wrel, s2brel, s2wroot, RP2, EL2, E1S, SCORE);
    topk_sel<<<NB, 1024, 0, stream>>>(SCORE, NPG2, KK2, PERM2, SSORT2, nullptr, 0);
    pool_gather<<<N3, 128, 0, stream>>>(F2, PERM2, SSORT2, F0);          // x3 -> F0

    // ---- mean pool + MLP ----
    pool_mean<<<NB, 128, 0, stream>>>(F0, GBUF);
    mlp_k<<<NB, 256, 0, stream>>>(GBUF, f1w, f1b, f2w, f2b, ow, ob, out);
}

// Round 3
// 573.531 us; speedup vs baseline: 1.3336x; 1.0208x over previous
//
#include <hip/hip_runtime.h>

#define N1 32768
#define EE 524288
#define NB 16
#define NPG1 2048
#define KK1 1024
#define N2 16384
#define NPG2 1024
#define KK2 512
#define N3 8192

static __device__ __forceinline__ float leaky(float x){ return x > 0.f ? x : 0.2f*x; }

// ---------------- utility kernels ----------------
__global__ void fill_i32(int* p, int v, int n){
    int i = blockIdx.x*blockDim.x + threadIdx.x;
    if (i < n) p[i] = v;
}

__global__ void count_dst(const int* __restrict__ dst, int* __restrict__ cnt, int E){
    int i = blockIdx.x*blockDim.x + threadIdx.x;
    if (i < E) atomicAdd(&cnt[dst[i]], 1);
}

__global__ void count_dst_valid(const int* __restrict__ s, const int* __restrict__ d,
                                int* __restrict__ cnt, int E){
    int i = blockIdx.x*blockDim.x + threadIdx.x;
    if (i < E){ int ss = s[i], dd = d[i]; if (ss >= 0 && dd >= 0) atomicAdd(&cnt[dd], 1); }
}

// ---- hierarchical scan: partial sums then per-block rescan+write ----
__global__ void blocksum_k(const int* __restrict__ cnt, int* __restrict__ bs){
    __shared__ int red[4];
    int tid = threadIdx.x;
    int v = cnt[blockIdx.x*256 + tid];
    #pragma unroll
    for (int off = 32; off; off >>= 1) v += __shfl_xor(v, off);
    if ((tid & 63) == 0) red[tid >> 6] = v;
    __syncthreads();
    if (tid == 0) bs[blockIdx.x] = red[0] + red[1] + red[2] + red[3];
}

// cnt may alias cur (each thread reads its own slot before writing)
__global__ void scan_write_k(const int* __restrict__ cnt, const int* __restrict__ bs,
                             int nb, int* __restrict__ rowptr, int* __restrict__ cur, int n){
    __shared__ int sbs[128];
    __shared__ int wsum[4];
    int tid = threadIdx.x;
    int b = blockIdx.x;
    if (tid < nb) sbs[tid] = bs[tid];
    __syncthreads();
    for (int off = 1; off < nb; off <<= 1){
        int v = 0;
        if (tid < nb && tid >= off) v = sbs[tid - off];
        __syncthreads();
        if (tid < nb) sbs[tid] += v;
        __syncthreads();
    }
    int base = (b == 0) ? 0 : sbs[b-1];
    int i = b*256 + tid;
    int c = cnt[i];
    int lane = tid & 63, wv = tid >> 6;
    int x = c;
    #pragma unroll
    for (int off = 1; off < 64; off <<= 1){ int y = __shfl_up(x, off); if (lane >= off) x += y; }
    if (lane == 63) wsum[wv] = x;
    __syncthreads();
    if (tid == 0){ int run = 0; for (int w2 = 0; w2 < 4; w2++){ int t = wsum[w2]; wsum[w2] = run; run += t; } }
    __syncthreads();
    int excl = x - c + wsum[wv];
    rowptr[i] = base + excl;
    cur[i]    = base + excl;
    if (i == n-1) rowptr[n] = base + excl + c;
}

__global__ void scatter1(const int* __restrict__ dst, int* __restrict__ cur,
                         int* __restrict__ eids, int E){
    int i = blockIdx.x*blockDim.x + threadIdx.x;
    if (i < E){ int p = atomicAdd(&cur[dst[i]], 1); eids[p] = i; }
}

__global__ void scatter2(const int* __restrict__ s, const int* __restrict__ d,
                         int* __restrict__ cur, int* __restrict__ eids, int E){
    int i = blockIdx.x*blockDim.x + threadIdx.x;
    if (i < E){
        int ss = s[i], dd = d[i];
        if (ss >= 0 && dd >= 0){ int p = atomicAdd(&cur[dd], 1); eids[p] = i; }
    }
}

__global__ void dinv_k(const int* __restrict__ rowptr, float* __restrict__ dinv, int n){
    int i = blockIdx.x*blockDim.x + threadIdx.x;
    if (i < n) dinv[i] = 1.0f / sqrtf((float)(rowptr[i+1] - rowptr[i]) + 1.0f);
}

// ---------------- fp32 tiled GEMM: C[n,M] = A[n,K] @ W[M,K]^T ----------------
// tile 128x128, K-step 32, 256 threads, 8x8 acc/thread.
// n multiple of 128; M multiple of 128; K multiple of 32.
__global__ __launch_bounds__(256) void gemm_nt(const float* __restrict__ A,
                                               const float* __restrict__ W,
                                               float* __restrict__ C,
                                               int n, int K, int M){
    __shared__ float As[32][132];   // [k][row]
    __shared__ float Ws[32][132];   // [k][col]
    int t = threadIdx.x;
    int tx = t & 15, ty = t >> 4;
    int row0 = blockIdx.x * 128, col0 = blockIdx.y * 128;
    int lr = t >> 3;            // 0..31
    int lk = (t & 7) * 4;       // 0,4,...,28
    float acc[8][8] = {};
    for (int kk = 0; kk < K; kk += 32){
        #pragma unroll
        for (int it = 0; it < 4; ++it){
            int r = lr + it*32;
            float4 av = *(const float4*)(A + (size_t)(row0 + r)*K + kk + lk);
            As[lk+0][r] = av.x; As[lk+1][r] = av.y; As[lk+2][r] = av.z; As[lk+3][r] = av.w;
            float4 wv = *(const float4*)(W + (size_t)(col0 + r)*K + kk + lk);
            Ws[lk+0][r] = wv.x; Ws[lk+1][r] = wv.y; Ws[lk+2][r] = wv.z; Ws[lk+3][r] = wv.w;
        }
        __syncthreads();
        #pragma unroll
        for (int k = 0; k < 32; k++){
            float ar[8], br[8];
            *(float4*)&ar[0] = *(const float4*)&As[k][ty*8];
            *(float4*)&ar[4] = *(const float4*)&As[k][ty*8 + 4];
            *(float4*)&br[0] = *(const float4*)&Ws[k][tx*8];
            *(float4*)&br[4] = *(const float4*)&Ws[k][tx*8 + 4];
            #pragma unroll
            for (int i = 0; i < 8; i++)
                #pragma unroll
                for (int j = 0; j < 8; j++) acc[i][j] += ar[i]*br[j];
        }
        __syncthreads();
    }
    #pragma unroll
    for (int i = 0; i < 8; i++){
        float4 o0; o0.x = acc[i][0]; o0.y = acc[i][1]; o0.z = acc[i][2]; o0.w = acc[i][3];
        float4 o1; o1.x = acc[i][4]; o1.y = acc[i][5]; o1.z = acc[i][6]; o1.w = acc[i][7];
        *(float4*)(C + (size_t)(row0 + ty*8 + i)*M + col0 + tx*8)     = o0;
        *(float4*)(C + (size_t)(row0 + ty*8 + i)*M + col0 + tx*8 + 4) = o1;
    }
}

// ---------------- GAT attention coefficients ----------------
__global__ void attn_pre(const float* __restrict__ h, const float* __restrict__ wsrc,
                         const float* __restrict__ wdst, float* __restrict__ as_,
                         float* __restrict__ ad_){
    int lane = threadIdx.x & 63;
    int w = threadIdx.x >> 6;
    int d = blockIdx.x*4 + w;
    float4 hv = *(const float4*)(h + (size_t)d*256 + lane*4);
    float4 ws = *(const float4*)(wsrc + lane*4);
    float4 wd = *(const float4*)(wdst + lane*4);
    float ps = hv.x*ws.x + hv.y*ws.y + hv.z*ws.z + hv.w*ws.w;
    float pd = hv.x*wd.x + hv.y*wd.y + hv.z*wd.z + hv.w*wd.w;
    #pragma unroll
    for (int m = 8; m; m >>= 1){ ps += __shfl_xor(ps, m); pd += __shfl_xor(pd, m); }
    if ((lane & 15) == 0){
        as_[d*4 + (lane >> 4)] = ps;
        ad_[d*4 + (lane >> 4)] = pd;
    }
}

// ---------------- GAT aggregation ----------------
template<int RELU>
__global__ void gat_agg(const float* __restrict__ h, const float* __restrict__ as_,
                        const float* __restrict__ ad_, const float* __restrict__ bias,
                        const int* __restrict__ rowptr, const int* __restrict__ eids,
                        const int* __restrict__ src, float* __restrict__ out){
    int lane = threadIdx.x & 63;
    int w = threadIdx.x >> 6;
    int nb = gridDim.x;
    int b = blockIdx.x;
    int sb = (b & 7)*(nb >> 3) + (b >> 3);
    int d = sb*4 + w;
    int beg = rowptr[d], end = rowptr[d+1];

    float ad4[4], m[4], es[4];
    #pragma unroll
    for (int hh = 0; hh < 4; hh++) ad4[hh] = ad_[d*4 + hh];
    #pragma unroll
    for (int hh = 0; hh < 4; hh++){ es[hh] = leaky(as_[d*4 + hh] + ad4[hh]); m[hh] = es[hh]; }

    for (int i = beg + lane; i < end; i += 64){
        int s = src[eids[i]];
        #pragma unroll
        for (int hh = 0; hh < 4; hh++) m[hh] = fmaxf(m[hh], leaky(as_[s*4 + hh] + ad4[hh]));
    }
    #pragma unroll
    for (int off = 32; off; off >>= 1)
        #pragma unroll
        for (int hh = 0; hh < 4; hh++) m[hh] = fmaxf(m[hh], __shfl_xor(m[hh], off));

    float den[4] = {0.f, 0.f, 0.f, 0.f};
    for (int i = beg + lane; i < end; i += 64){
        int s = src[eids[i]];
        #pragma unroll
        for (int hh = 0; hh < 4; hh++) den[hh] += expf(leaky(as_[s*4 + hh] + ad4[hh]) - m[hh]);
    }
    #pragma unroll
    for (int off = 32; off; off >>= 1)
        #pragma unroll
        for (int hh = 0; hh < 4; hh++) den[hh] += __shfl_xor(den[hh], off);
    #pragma unroll
    for (int hh = 0; hh < 4; hh++) den[hh] += expf(es[hh] - m[hh]) + 1e-16f;

    int hh = lane >> 4;
    int c0 = lane*4;
    float rden = 1.0f / den[hh];
    float mh = m[hh];
    float aself = expf(es[hh] - mh) * rden;
    float4 hd = *(const float4*)(h + (size_t)d*256 + c0);
    float4 acc;
    acc.x = aself*hd.x; acc.y = aself*hd.y; acc.z = aself*hd.z; acc.w = aself*hd.w;
    for (int i = beg; i < end; i++){
        int s = src[eids[i]];
        float al = expf(leaky(as_[s*4 + hh] + ad4[hh]) - mh) * rden;
        float4 hv = *(const float4*)(h + (size_t)s*256 + c0);
        acc.x += al*hv.x; acc.y += al*hv.y; acc.z += al*hv.z; acc.w += al*hv.w;
    }
    float4 bv = *(const float4*)(bias + c0);
    acc.x += bv.x; acc.y += bv.y; acc.z += bv.z; acc.w += bv.w;
    if (RELU){
        acc.x = fmaxf(acc.x, 0.f); acc.y = fmaxf(acc.y, 0.f);
        acc.z = fmaxf(acc.z, 0.f); acc.w = fmaxf(acc.w, 0.f);
    }
    *(float4*)(out + (size_t)d*256 + c0) = acc;
}

// ---------------- GCN aggregation ----------------
__global__ void gcn_agg(const float* __restrict__ h, const float* __restrict__ dinv,
                        const float* __restrict__ bias, const int* __restrict__ rowptr,
                        const int* __restrict__ eids, const int* __restrict__ src,
                        float* __restrict__ out){
    int lane = threadIdx.x & 63;
    int w = threadIdx.x >> 6;
    int nb = gridDim.x;
    int b = blockIdx.x;
    int sb = (b & 7)*(nb >> 3) + (b >> 3);
    int d = sb*4 + w;
    int beg = rowptr[d], end = rowptr[d+1];
    float dv = dinv[d];
    int c0 = lane*2;
    float2 hd = *(const float2*)(h + (size_t)d*128 + c0);
    float self = dv*dv;
    float ax = self*hd.x, ay = self*hd.y;
    for (int i = beg; i < end; i++){
        int s = src[eids[i]];
        float coef = dinv[s]*dv;
        float2 hv = *(const float2*)(h + (size_t)s*128 + c0);
        ax += coef*hv.x; ay += coef*hv.y;
    }
    ax = fmaxf(ax + bias[c0], 0.f);
    ay = fmaxf(ay + bias[c0+1], 0.f);
    float2 o; o.x = ax; o.y = ay;
    *(float2*)(out + (size_t)d*128 + c0) = o;
}

// ---------------- SAGPool score ----------------
__global__ void sag_score(const float* __restrict__ x, const float* __restrict__ wrel,
                          const float* __restrict__ brel, const float* __restrict__ wroot,
                          const int* __restrict__ rowptr, const int* __restrict__ eids,
                          const int* __restrict__ src, float* __restrict__ score){
    int lane = threadIdx.x & 63;
    int w = threadIdx.x >> 6;
    int nb = gridDim.x;
    int b = blockIdx.x;
    int sb = (b & 7)*(nb >> 3) + (b >> 3);
    int d = sb*4 + w;
    int beg = rowptr[d], end = rowptr[d+1];
    int c0 = lane*2;
    float aggx = 0.f, aggy = 0.f;
    for (int i = beg; i < end; i++){
        int s = src[eids[i]];
        float2 xv = *(const float2*)(x + (size_t)s*128 + c0);
        aggx += xv.x; aggy += xv.y;
    }
    float2 xd = *(const float2*)(x + (size_t)d*128 + c0);
    float part = aggx*wrel[c0] + aggy*wrel[c0+1] + xd.x*wroot[c0] + xd.y*wroot[c0+1];
    #pragma unroll
    for (int off = 32; off; off >>= 1) part += __shfl_xor(part, off);
    if (lane == 0) score[d] = part + brel[0];
}

// ---------------- radix-select top-k ----------------
__global__ __launch_bounds__(1024) void topk_sel(const float* __restrict__ score,
        int npg, int k, int* __restrict__ perm, float* __restrict__ ssort,
        int* __restrict__ nid, int writeNid){
    __shared__ unsigned keys[2048];
    __shared__ int hist[256];
    __shared__ int cge[256];
    __shared__ int warpsum[16];
    __shared__ int s_bin, s_need;
    int g = blockIdx.x, tid = threadIdx.x;
    for (int i = tid; i < npg; i += 1024){
        unsigned u = __float_as_uint(score[g*npg + i]);
        u = (u & 0x80000000u) ? ~u : (u | 0x80000000u);
        keys[i] = u;
    }
    if (tid == 0) s_need = k;
    __syncthreads();
    unsigned prefix = 0u, pmask = 0u;
    #pragma unroll
    for (int shift = 24; shift >= 0; shift -= 8){
        if (tid < 256) hist[tid] = 0;
        __syncthreads();
        for (int i = tid; i < npg; i += 1024){
            unsigned u = keys[i];
            if ((u & pmask) == prefix) atomicAdd(&hist[(u >> shift) & 255u], 1);
        }
        __syncthreads();
        if (tid < 256) cge[tid] = hist[tid];
        __syncthreads();
        for (int off = 1; off < 256; off <<= 1){
            int v = 0;
            if (tid < 256 - off) v = cge[tid + off];
            __syncthreads();
            if (tid < 256) cge[tid] += v;
            __syncthreads();
        }
        int need = s_need;
        if (tid < 256){
            int above = (tid == 255) ? 0 : cge[tid + 1];
            if (cge[tid] >= need && above < need) s_bin = tid;
        }
        __syncthreads();
        if (tid == 0) s_need = need - ((s_bin == 255) ? 0 : cge[s_bin + 1]);
        __syncthreads();
        prefix |= ((unsigned)s_bin) << shift;
        pmask  |= (255u << shift);
        __syncthreads();
    }
    unsigned thr = prefix;
    int m = s_need;
    int i0 = 2*tid, i1 = 2*tid + 1;
    int f0 = 0, f1 = 0;
    if (i0 < npg){
        unsigned u = keys[i0];
        if (u > thr) f0 = 1;
        else if (u == thr){
            int r = 0;
            for (int j = 0; j < i0; j++) r += (keys[j] == thr);
            f0 = (r < m) ? 1 : 0;
        }
    }
    if (i1 < npg){
        unsigned u = keys[i1];
        if (u > thr) f1 = 1;
        else if (u == thr){
            int r = 0;
            for (int j = 0; j < i1; j++) r += (keys[j] == thr);
            f1 = (r < m) ? 1 : 0;
        }
    }
    int pair = f0 + f1;
    int lane = tid & 63, wv = tid >> 6;
    int x = pair;
    #pragma unroll
    for (int off = 1; off < 64; off <<= 1){ int y = __shfl_up(x, off); if (lane >= off) x += y; }
    if (lane == 63) warpsum[wv] = x;
    __syncthreads();
    if (tid == 0){ int run = 0; for (int w2 = 0; w2 < 16; w2++){ int t = warpsum[w2]; warpsum[w2] = run; run += t; } }
    __syncthreads();
    int excl = x - pair + warpsum[wv];
    if (f0){
        int pos = excl;
        int node = g*npg + i0;
        perm[g*k + pos] = node;
        ssort[g*k + pos] = score[node];
        if (writeNid) nid[node] = g*k + pos;
    }
    if (f1){
        int pos = excl + f0;
        int node = g*npg + i1;
        perm[g*k + pos] = node;
        ssort[g*k + pos] = score[node];
        if (writeNid) nid[node] = g*k + pos;
    }
}

__global__ void edge_remap(const int* __restrict__ s, const int* __restrict__ d,
                           const int* __restrict__ nid, int* __restrict__ ns,
                           int* __restrict__ nd, int E){
    int i = blockIdx.x*blockDim.x + threadIdx.x;
    if (i < E){ ns[i] = nid[s[i]]; nd[i] = nid[d[i]]; }
}

__global__ void pool_gather(const float* __restrict__ x, const int* __restrict__ perm,
                            const float* __restrict__ ssort, float* __restrict__ xn){
    int j = blockIdx.x; int c = threadIdx.x;
    int o = perm[j];
    float t = tanhf(ssort[j]);
    xn[(size_t)j*128 + c] = x[(size_t)o*128 + c] * t;
}

__global__ void pool_mean(const float* __restrict__ x, float* __restrict__ g){
    int b = blockIdx.x, c = threadIdx.x;
    float s = 0.f;
    for (int i = 0; i < KK2; i++) s += x[((size_t)b*KK2 + i)*128 + c];
    g[b*128 + c] = s * (1.0f/KK2);
}

__global__ void mlp_k(const float* __restrict__ g,
                      const float* __restrict__ fc1w, const float* __restrict__ fc1b,
                      const float* __restrict__ fc2w, const float* __restrict__ fc2b,
                      const float* __restrict__ ow,  const float* __restrict__ ob,
                      float* __restrict__ out){
    __shared__ float gv[128], t1[256], t2[128];
    int b = blockIdx.x, t = threadIdx.x;
    if (t < 128) gv[t] = g[b*128 + t];
    __syncthreads();
    {
        float s = fc1b[t];
        for (int c = 0; c < 128; c++) s += gv[c]*fc1w[t*128 + c];
        t1[t] = fmaxf(s, 0.f);
    }
    __syncthreads();
    if (t < 128){
        float s = fc2b[t];
        for (int c = 0; c < 256; c++) s += t1[c]*fc2w[t*256 + c];
        t2[t] = fmaxf(s, 0.f);
    }
    __syncthreads();
    if (t < 10){
        float s = ob[t];
        for (int c = 0; c < 128; c++) s += t2[c]*ow[t*128 + c];
        out[b*10 + t] = s;
    }
}

// ---------------- launch ----------------
extern "C" void kernel_launch(void* const* d_in, const int* in_sizes, int n_in,
                              void* d_out, int out_size, void* d_ws, size_t ws_size,
                              hipStream_t stream){
    (void)in_sizes; (void)n_in; (void)out_size; (void)ws_size;
    const float* x    = (const float*)d_in[0];
    const int*   eidx = (const int*)d_in[1];
    const int*   src  = eidx;
    const int*   dst  = eidx + EE;
    const float* g1w  = (const float*)d_in[3];
    const float* g1as = (const float*)d_in[4];
    const float* g1ad = (const float*)d_in[5];
    const float* g1b  = (const float*)d_in[6];
    const float* g2w  = (const float*)d_in[7];
    const float* g2as = (const float*)d_in[8];
    const float* g2ad = (const float*)d_in[9];
    const float* g2b  = (const float*)d_in[10];
    const float* c1w  = (const float*)d_in[11];
    const float* c1b  = (const float*)d_in[12];
    const float* s1wrel  = (const float*)d_in[13];
    const float* s1brel  = (const float*)d_in[14];
    const float* s1wroot = (const float*)d_in[15];
    const float* c2w  = (const float*)d_in[16];
    const float* c2b  = (const float*)d_in[17];
    const float* s2wrel  = (const float*)d_in[18];
    const float* s2brel  = (const float*)d_in[19];
    const float* s2wroot = (const float*)d_in[20];
    const float* f1w  = (const float*)d_in[21];
    const float* f1b  = (const float*)d_in[22];
    const float* f2w  = (const float*)d_in[23];
    const float* f2b  = (const float*)d_in[24];
    const float* ow   = (const float*)d_in[25];
    const float* ob   = (const float*)d_in[26];
    float* out = (float*)d_out;

    char* ws = (char*)d_ws;
    size_t off = 0;
    auto alloc = [&](size_t bytes)->char*{
        char* p = ws + off;
        off += (bytes + 255) & ~(size_t)255;
        return p;
    };
    float* F0     = (float*)alloc((size_t)N1*256*4);
    float* F1     = (float*)alloc((size_t)N1*256*4);
    float* F2     = (float*)alloc((size_t)N2*128*4);
    float* AS     = (float*)alloc((size_t)N1*4*4);
    float* AD     = (float*)alloc((size_t)N1*4*4);
    int*   RP     = (int*)  alloc((size_t)(N1+1)*4);
    int*   CUR    = (int*)  alloc((size_t)N1*4);
    int*   EL     = (int*)  alloc((size_t)EE*4);
    float* DINV   = (float*)alloc((size_t)N1*4);
    float* SCORE  = (float*)alloc((size_t)N1*4);
    int*   PERM1  = (int*)  alloc((size_t)N2*4);
    float* SSORT1 = (float*)alloc((size_t)N2*4);
    int*   NID    = (int*)  alloc((size_t)N1*4);
    int*   E1S    = (int*)  alloc((size_t)EE*4);
    int*   E1D    = (int*)  alloc((size_t)EE*4);
    int*   RP2    = (int*)  alloc((size_t)(N2+1)*4);
    int*   CUR2   = (int*)  alloc((size_t)N2*4);
    int*   EL2    = (int*)  alloc((size_t)EE*4);
    float* DINV2  = (float*)alloc((size_t)N2*4);
    int*   PERM2  = (int*)  alloc((size_t)N3*4);
    float* SSORT2 = (float*)alloc((size_t)N3*4);
    float* GBUF   = (float*)alloc((size_t)NB*128*4);
    int*   BS     = (int*)  alloc((size_t)128*4);

    // ---- level-1 CSR (by dst) ----
    fill_i32<<<N1/256, 256, 0, stream>>>(CUR, 0, N1);
    count_dst<<<EE/256, 256, 0, stream>>>(dst, CUR, EE);
    blocksum_k<<<N1/256, 256, 0, stream>>>(CUR, BS);
    scan_write_k<<<N1/256, 256, 0, stream>>>(CUR, BS, N1/256, RP, CUR, N1);
    scatter1<<<EE/256, 256, 0, stream>>>(dst, CUR, EL, EE);

    // ---- GAT layer 1 (64 -> 4x64, relu) ----
    gemm_nt<<<dim3(N1/128, 2), 256, 0, stream>>>(x, g1w, F0, N1, 64, 256);
    attn_pre<<<N1/4, 256, 0, stream>>>(F0, g1as, g1ad, AS, AD);
    gat_agg<1><<<N1/4, 256, 0, stream>>>(F0, AS, AD, g1b, RP, EL, src, F1);

    // ---- GAT layer 2 (256 -> 4x64) ----
    gemm_nt<<<dim3(N1/128, 2), 256, 0, stream>>>(F1, g2w, F0, N1, 256, 256);
    attn_pre<<<N1/4, 256, 0, stream>>>(F0, g2as, g2ad, AS, AD);
    gat_agg<0><<<N1/4, 256, 0, stream>>>(F0, AS, AD, g2b, RP, EL, src, F1);

    // ---- GCN1 (256 -> 128, relu) ----
    gemm_nt<<<dim3(N1/128, 1), 256, 0, stream>>>(F1, c1w, F0, N1, 256, 128);
    dinv_k<<<N1/256, 256, 0, stream>>>(RP, DINV, N1);
    gcn_agg<<<N1/4, 256, 0, stream>>>(F0, DINV, c1b, RP, EL, src, F1);

    // ---- SAGPool1 ----
    sag_score<<<N1/4, 256, 0, stream>>>(F1, s1wrel, s1brel, s1wroot, RP, EL, src, SCORE);
    fill_i32<<<N1/256, 256, 0, stream>>>(NID, -1, N1);
    topk_sel<<<NB, 1024, 0, stream>>>(SCORE, NPG1, KK1, PERM1, SSORT1, NID, 1);
    pool_gather<<<N2, 128, 0, stream>>>(F1, PERM1, SSORT1, F0);          // x2 -> F0
    edge_remap<<<EE/256, 256, 0, stream>>>(src, dst, NID, E1S, E1D, EE);

    // ---- level-2 CSR (valid edges only) ----
    fill_i32<<<N2/256, 256, 0, stream>>>(CUR2, 0, N2);
    count_dst_valid<<<EE/256, 256, 0, stream>>>(E1S, E1D, CUR2, EE);
    blocksum_k<<<N2/256, 256, 0, stream>>>(CUR2, BS);
    scan_write_k<<<N2/256, 256, 0, stream>>>(CUR2, BS, N2/256, RP2, CUR2, N2);
    scatter2<<<EE/256, 256, 0, stream>>>(E1S, E1D, CUR2, EL2, EE);

    // ---- GCN2 (128 -> 128, relu) ----
    gemm_nt<<<dim3(N2/128, 1), 256, 0, stream>>>(F0, c2w, F1, N2, 128, 128);
    dinv_k<<<N2/256, 256, 0, stream>>>(RP2, DINV2, N2);
    gcn_agg<<<N2/4, 256, 0, stream>>>(F1, DINV2, c2b, RP2, EL2, E1S, F2);

    // ---- SAGPool2 ----
    sag_score<<<N2/4, 256, 0, stream>>>(F2, s2wrel, s2brel, s2wroot, RP2, EL2, E1S, SCORE);
    topk_sel<<<NB, 1024, 0, stream>>>(SCORE, NPG2, KK2, PERM2, SSORT2, nullptr, 0);
    pool_gather<<<N3, 128, 0, stream>>>(F2, PERM2, SSORT2, F0);          // x3 -> F0

    // ---- mean pool + MLP ----
    pool_mean<<<NB, 128, 0, stream>>>(F0, GBUF);
    mlp_k<<<NB, 256, 0, stream>>>(GBUF, f1w, f1b, f2w, f2b, ow, ob, out);
}

// Round 4
// 510.678 us; speedup vs baseline: 1.4977x; 1.1231x over previous
//
#include <hip/hip_runtime.h>

#define N1 32768
#define EE 524288
#define NB 16
#define NPG1 2048
#define KK1 1024
#define N2 16384
#define NPG2 1024
#define KK2 512
#define N3 8192

static __device__ __forceinline__ float leaky(float x){ return x > 0.f ? x : 0.2f*x; }

// ---------------- CSR build ----------------
__global__ void count_dst(const int* __restrict__ dst, int* __restrict__ cnt, int E){
    int i = blockIdx.x*blockDim.x + threadIdx.x;
    if (i < E) atomicAdd(&cnt[dst[i]], 1);
}

// fused: remap edges to pooled ids and count valid by new dst
__global__ void remap_count(const int* __restrict__ src, const int* __restrict__ dst,
                            const int* __restrict__ nid, int* __restrict__ ns,
                            int* __restrict__ nd, int* __restrict__ cnt, int E){
    int i = blockIdx.x*blockDim.x + threadIdx.x;
    if (i < E){
        int a = nid[src[i]], b = nid[dst[i]];
        ns[i] = a; nd[i] = b;
        if (a >= 0 && b >= 0) atomicAdd(&cnt[b], 1);
    }
}

__global__ void blocksum_k(const int* __restrict__ cnt, int* __restrict__ bs){
    __shared__ int red[4];
    int tid = threadIdx.x;
    int v = cnt[blockIdx.x*256 + tid];
    #pragma unroll
    for (int off = 32; off; off >>= 1) v += __shfl_xor(v, off);
    if ((tid & 63) == 0) red[tid >> 6] = v;
    __syncthreads();
    if (tid == 0) bs[blockIdx.x] = red[0] + red[1] + red[2] + red[3];
}

// cnt may alias cur; also emits dinv = rsqrt(deg+1)
__global__ void scan_write_k(const int* __restrict__ cnt, const int* __restrict__ bs,
                             int nb, int* __restrict__ rowptr, int* __restrict__ cur,
                             float* __restrict__ dinv, int n){
    __shared__ int sbs[128];
    __shared__ int wsum[4];
    int tid = threadIdx.x;
    int b = blockIdx.x;
    if (tid < nb) sbs[tid] = bs[tid];
    __syncthreads();
    for (int off = 1; off < nb; off <<= 1){
        int v = 0;
        if (tid < nb && tid >= off) v = sbs[tid - off];
        __syncthreads();
        if (tid < nb) sbs[tid] += v;
        __syncthreads();
    }
    int base = (b == 0) ? 0 : sbs[b-1];
    int i = b*256 + tid;
    int c = cnt[i];
    int lane = tid & 63, wv = tid >> 6;
    int x = c;
    #pragma unroll
    for (int off = 1; off < 64; off <<= 1){ int y = __shfl_up(x, off); if (lane >= off) x += y; }
    if (lane == 63) wsum[wv] = x;
    __syncthreads();
    if (tid == 0){ int run = 0; for (int w2 = 0; w2 < 4; w2++){ int t = wsum[w2]; wsum[w2] = run; run += t; } }
    __syncthreads();
    int excl = x - c + wsum[wv];
    rowptr[i] = base + excl;
    cur[i]    = base + excl;
    dinv[i]   = rsqrtf((float)c + 1.0f);
    if (i == n-1) rowptr[n] = base + excl + c;
}

// store SOURCE NODE ID directly (edge id itself is never needed downstream)
__global__ void scatter1(const int* __restrict__ src, const int* __restrict__ dst,
                         int* __restrict__ cur, int* __restrict__ esrc, int E){
    int i = blockIdx.x*blockDim.x + threadIdx.x;
    if (i < E){ int p = atomicAdd(&cur[dst[i]], 1); esrc[p] = src[i]; }
}

__global__ void scatter2(const int* __restrict__ ns, const int* __restrict__ nd,
                         int* __restrict__ cur, int* __restrict__ esrc, int E){
    int i = blockIdx.x*blockDim.x + threadIdx.x;
    if (i < E){
        int a = ns[i], b = nd[i];
        if (a >= 0 && b >= 0){ int p = atomicAdd(&cur[b], 1); esrc[p] = a; }
    }
}

// ---------------- fp32 tiled GEMM: C[n,M] = A[n,K] @ W[M,K]^T ----------------
__global__ __launch_bounds__(256) void gemm_nt(const float* __restrict__ A,
                                               const float* __restrict__ W,
                                               float* __restrict__ C,
                                               int n, int K, int M){
    __shared__ float As[32][132];
    __shared__ float Ws[32][132];
    int t = threadIdx.x;
    int tx = t & 15, ty = t >> 4;
    int row0 = blockIdx.x * 128, col0 = blockIdx.y * 128;
    int lr = t >> 3;
    int lk = (t & 7) * 4;
    float acc[8][8] = {};
    for (int kk = 0; kk < K; kk += 32){
        #pragma unroll
        for (int it = 0; it < 4; ++it){
            int r = lr + it*32;
            float4 av = *(const float4*)(A + (size_t)(row0 + r)*K + kk + lk);
            As[lk+0][r] = av.x; As[lk+1][r] = av.y; As[lk+2][r] = av.z; As[lk+3][r] = av.w;
            float4 wv = *(const float4*)(W + (size_t)(col0 + r)*K + kk + lk);
            Ws[lk+0][r] = wv.x; Ws[lk+1][r] = wv.y; Ws[lk+2][r] = wv.z; Ws[lk+3][r] = wv.w;
        }
        __syncthreads();
        #pragma unroll
        for (int k = 0; k < 32; k++){
            float ar[8], br[8];
            *(float4*)&ar[0] = *(const float4*)&As[k][ty*8];
            *(float4*)&ar[4] = *(const float4*)&As[k][ty*8 + 4];
            *(float4*)&br[0] = *(const float4*)&Ws[k][tx*8];
            *(float4*)&br[4] = *(const float4*)&Ws[k][tx*8 + 4];
            #pragma unroll
            for (int i = 0; i < 8; i++)
                #pragma unroll
                for (int j = 0; j < 8; j++) acc[i][j] += ar[i]*br[j];
        }
        __syncthreads();
    }
    #pragma unroll
    for (int i = 0; i < 8; i++){
        float4 o0; o0.x = acc[i][0]; o0.y = acc[i][1]; o0.z = acc[i][2]; o0.w = acc[i][3];
        float4 o1; o1.x = acc[i][4]; o1.y = acc[i][5]; o1.z = acc[i][6]; o1.w = acc[i][7];
        *(float4*)(C + (size_t)(row0 + ty*8 + i)*M + col0 + tx*8)     = o0;
        *(float4*)(C + (size_t)(row0 + ty*8 + i)*M + col0 + tx*8 + 4) = o1;
    }
}

// ---------------- GAT attention coefficients ----------------
__global__ void attn_pre(const float* __restrict__ h, const float* __restrict__ wsrc,
                         const float* __restrict__ wdst, float* __restrict__ as_,
                         float* __restrict__ ad_){
    int lane = threadIdx.x & 63;
    int w = threadIdx.x >> 6;
    int d = blockIdx.x*4 + w;
    float4 hv = *(const float4*)(h + (size_t)d*256 + lane*4);
    float4 ws = *(const float4*)(wsrc + lane*4);
    float4 wd = *(const float4*)(wdst + lane*4);
    float ps = hv.x*ws.x + hv.y*ws.y + hv.z*ws.z + hv.w*ws.w;
    float pd = hv.x*wd.x + hv.y*wd.y + hv.z*wd.z + hv.w*wd.w;
    #pragma unroll
    for (int m = 8; m; m >>= 1){ ps += __shfl_xor(ps, m); pd += __shfl_xor(pd, m); }
    if ((lane & 15) == 0){
        as_[d*4 + (lane >> 4)] = ps;
        ad_[d*4 + (lane >> 4)] = pd;
    }
}

// ---------------- GAT aggregation: max pass + fused den/acc pass ------------
template<int RELU>
__global__ void gat_agg(const float* __restrict__ h, const float* __restrict__ as_,
                        const float* __restrict__ ad_, const float* __restrict__ bias,
                        const int* __restrict__ rowptr, const int* __restrict__ esrc,
                        float* __restrict__ out){
    int lane = threadIdx.x & 63;
    int w = threadIdx.x >> 6;
    int nb = gridDim.x;
    int b = blockIdx.x;
    int sb = (b & 7)*(nb >> 3) + (b >> 3);
    int d = sb*4 + w;
    int beg = rowptr[d], end = rowptr[d+1];

    float ad4[4], m[4], es[4];
    #pragma unroll
    for (int hh = 0; hh < 4; hh++) ad4[hh] = ad_[(d<<2) + hh];
    #pragma unroll
    for (int hh = 0; hh < 4; hh++){ es[hh] = leaky(as_[(d<<2) + hh] + ad4[hh]); m[hh] = es[hh]; }

    // pass 1: per-head max (lane-strided)
    for (int i = beg + lane; i < end; i += 64){
        int s = esrc[i];
        float4 a4 = *(const float4*)(as_ + (s<<2));
        m[0] = fmaxf(m[0], leaky(a4.x + ad4[0]));
        m[1] = fmaxf(m[1], leaky(a4.y + ad4[1]));
        m[2] = fmaxf(m[2], leaky(a4.z + ad4[2]));
        m[3] = fmaxf(m[3], leaky(a4.w + ad4[3]));
    }
    #pragma unroll
    for (int off = 32; off; off >>= 1)
        #pragma unroll
        for (int hh = 0; hh < 4; hh++) m[hh] = fmaxf(m[hh], __shfl_xor(m[hh], off));

    // pass 2 (fused): unnormalized accumulate + denominator, then one divide
    int hh = lane >> 4;
    int c0 = lane*4;
    float mh  = m[hh];
    float adh = ad4[hh];
    float den = __expf(es[hh] - mh);
    float4 hd = *(const float4*)(h + (d<<8) + c0);
    float4 acc;
    acc.x = den*hd.x; acc.y = den*hd.y; acc.z = den*hd.z; acc.w = den*hd.w;

    int i = beg;
    if (i < end){
        int s = esrc[i];
        float a_cur = as_[(s<<2) + hh];
        float4 hcur = *(const float4*)(h + (s<<8) + c0);
        for (++i; i < end; ++i){
            int s2 = esrc[i];
            float a_nxt = as_[(s2<<2) + hh];
            float4 hnxt = *(const float4*)(h + (s2<<8) + c0);
            float p = __expf(leaky(a_cur + adh) - mh);
            den += p;
            acc.x = fmaf(p, hcur.x, acc.x);
            acc.y = fmaf(p, hcur.y, acc.y);
            acc.z = fmaf(p, hcur.z, acc.z);
            acc.w = fmaf(p, hcur.w, acc.w);
            a_cur = a_nxt; hcur = hnxt;
        }
        float p = __expf(leaky(a_cur + adh) - mh);
        den += p;
        acc.x = fmaf(p, hcur.x, acc.x);
        acc.y = fmaf(p, hcur.y, acc.y);
        acc.z = fmaf(p, hcur.z, acc.z);
        acc.w = fmaf(p, hcur.w, acc.w);
    }
    float r = 1.0f / (den + 1e-16f);
    float4 bv = *(const float4*)(bias + c0);
    acc.x = acc.x*r + bv.x; acc.y = acc.y*r + bv.y;
    acc.z = acc.z*r + bv.z; acc.w = acc.w*r + bv.w;
    if (RELU){
        acc.x = fmaxf(acc.x, 0.f); acc.y = fmaxf(acc.y, 0.f);
        acc.z = fmaxf(acc.z, 0.f); acc.w = fmaxf(acc.w, 0.f);
    }
    *(float4*)(out + (d<<8) + c0) = acc;
}

// ---------------- GCN aggregation ----------------
__global__ void gcn_agg(const float* __restrict__ h, const float* __restrict__ dinv,
                        const float* __restrict__ bias, const int* __restrict__ rowptr,
                        const int* __restrict__ esrc, float* __restrict__ out){
    int lane = threadIdx.x & 63;
    int w = threadIdx.x >> 6;
    int nb = gridDim.x;
    int b = blockIdx.x;
    int sb = (b & 7)*(nb >> 3) + (b >> 3);
    int d = sb*4 + w;
    int beg = rowptr[d], end = rowptr[d+1];
    float dv = dinv[d];
    int c0 = lane*2;
    float2 hd = *(const float2*)(h + (d<<7) + c0);
    float self = dv*dv;
    float ax = self*hd.x, ay = self*hd.y;
    int i = beg;
    if (i < end){
        int s = esrc[i];
        float di_cur = dinv[s];
        float2 hcur = *(const float2*)(h + (s<<7) + c0);
        for (++i; i < end; ++i){
            int s2 = esrc[i];
            float di_nxt = dinv[s2];
            float2 hnxt = *(const float2*)(h + (s2<<7) + c0);
            float coef = di_cur*dv;
            ax = fmaf(coef, hcur.x, ax);
            ay = fmaf(coef, hcur.y, ay);
            di_cur = di_nxt; hcur = hnxt;
        }
        float coef = di_cur*dv;
        ax = fmaf(coef, hcur.x, ax);
        ay = fmaf(coef, hcur.y, ay);
    }
    ax = fmaxf(ax + bias[c0], 0.f);
    ay = fmaxf(ay + bias[c0+1], 0.f);
    float2 o; o.x = ax; o.y = ay;
    *(float2*)(out + (d<<7) + c0) = o;
}

// ---------------- SAGPool score ----------------
__global__ void sag_score(const float* __restrict__ x, const float* __restrict__ wrel,
                          const float* __restrict__ brel, const float* __restrict__ wroot,
                          const int* __restrict__ rowptr, const int* __restrict__ esrc,
                          float* __restrict__ score){
    int lane = threadIdx.x & 63;
    int w = threadIdx.x >> 6;
    int nb = gridDim.x;
    int b = blockIdx.x;
    int sb = (b & 7)*(nb >> 3) + (b >> 3);
    int d = sb*4 + w;
    int beg = rowptr[d], end = rowptr[d+1];
    int c0 = lane*2;
    float aggx = 0.f, aggy = 0.f;
    int i = beg;
    if (i < end){
        int s = esrc[i];
        float2 hcur = *(const float2*)(x + (s<<7) + c0);
        for (++i; i < end; ++i){
            int s2 = esrc[i];
            float2 hnxt = *(const float2*)(x + (s2<<7) + c0);
            aggx += hcur.x; aggy += hcur.y;
            hcur = hnxt;
        }
        aggx += hcur.x; aggy += hcur.y;
    }
    float2 xd = *(const float2*)(x + (d<<7) + c0);
    float part = aggx*wrel[c0] + aggy*wrel[c0+1] + xd.x*wroot[c0] + xd.y*wroot[c0+1];
    #pragma unroll
    for (int off = 32; off; off >>= 1) part += __shfl_xor(part, off);
    if (lane == 0) score[d] = part + brel[0];
}

// ---------------- radix-select top-k ----------------
__global__ __launch_bounds__(1024) void topk_sel(const float* __restrict__ score,
        int npg, int k, int* __restrict__ perm, float* __restrict__ ssort,
        int* __restrict__ nid, int writeNid){
    __shared__ unsigned keys[2048];
    __shared__ int hist[256];
    __shared__ int cge[256];
    __shared__ int warpsum[16];
    __shared__ int s_bin, s_need;
    int g = blockIdx.x, tid = threadIdx.x;
    for (int i = tid; i < npg; i += 1024){
        unsigned u = __float_as_uint(score[g*npg + i]);
        u = (u & 0x80000000u) ? ~u : (u | 0x80000000u);
        keys[i] = u;
    }
    if (tid == 0) s_need = k;
    __syncthreads();
    unsigned prefix = 0u, pmask = 0u;
    #pragma unroll
    for (int shift = 24; shift >= 0; shift -= 8){
        if (tid < 256) hist[tid] = 0;
        __syncthreads();
        for (int i = tid; i < npg; i += 1024){
            unsigned u = keys[i];
            if ((u & pmask) == prefix) atomicAdd(&hist[(u >> shift) & 255u], 1);
        }
        __syncthreads();
        if (tid < 256) cge[tid] = hist[tid];
        __syncthreads();
        for (int off = 1; off < 256; off <<= 1){
            int v = 0;
            if (tid < 256 - off) v = cge[tid + off];
            __syncthreads();
            if (tid < 256) cge[tid] += v;
            __syncthreads();
        }
        int need = s_need;
        if (tid < 256){
            int above = (tid == 255) ? 0 : cge[tid + 1];
            if (cge[tid] >= need && above < need) s_bin = tid;
        }
        __syncthreads();
        if (tid == 0) s_need = need - ((s_bin == 255) ? 0 : cge[s_bin + 1]);
        __syncthreads();
        prefix |= ((unsigned)s_bin) << shift;
        pmask  |= (255u << shift);
        __syncthreads();
    }
    unsigned thr = prefix;
    int m = s_need;
    int i0 = 2*tid, i1 = 2*tid + 1;
    int f0 = 0, f1 = 0;
    if (i0 < npg){
        unsigned u = keys[i0];
        if (u > thr) f0 = 1;
        else if (u == thr){
            int r = 0;
            for (int j = 0; j < i0; j++) r += (keys[j] == thr);
            f0 = (r < m) ? 1 : 0;
        }
    }
    if (i1 < npg){
        unsigned u = keys[i1];
        if (u > thr) f1 = 1;
        else if (u == thr){
            int r = 0;
            for (int j = 0; j < i1; j++) r += (keys[j] == thr);
            f1 = (r < m) ? 1 : 0;
        }
    }
    int pair = f0 + f1;
    int lane = tid & 63, wv = tid >> 6;
    int x = pair;
    #pragma unroll
    for (int off = 1; off < 64; off <<= 1){ int y = __shfl_up(x, off); if (lane >= off) x += y; }
    if (lane == 63) warpsum[wv] = x;
    __syncthreads();
    if (tid == 0){ int run = 0; for (int w2 = 0; w2 < 16; w2++){ int t = warpsum[w2]; warpsum[w2] = run; run += t; } }
    __syncthreads();
    int excl = x - pair + warpsum[wv];
    if (f0){
        int pos = excl;
        int node = g*npg + i0;
        perm[g*k + pos] = node;
        ssort[g*k + pos] = score[node];
        if (writeNid) nid[node] = g*k + pos;
    }
    if (f1){
        int pos = excl + f0;
        int node = g*npg + i1;
        perm[g*k + pos] = node;
        ssort[g*k + pos] = score[node];
        if (writeNid) nid[node] = g*k + pos;
    }
}

__global__ void pool_gather(const float* __restrict__ x, const int* __restrict__ perm,
                            const float* __restrict__ ssort, float* __restrict__ xn){
    int j = blockIdx.x; int c = threadIdx.x;
    int o = perm[j];
    float t = tanhf(ssort[j]);
    xn[(size_t)j*128 + c] = x[(size_t)o*128 + c] * t;
}

// fused level-2 gather + mean pool: g[b][c] = (1/KK2) * sum_i tanh(ss[i]) * x[perm[i]][c]
__global__ void pool_mean2(const float* __restrict__ x, const int* __restrict__ perm,
                           const float* __restrict__ ssort, float* __restrict__ g){
    __shared__ float tt[KK2];
    __shared__ float part[128];
    int b = blockIdx.x, t = threadIdx.x;     // 256 threads
    tt[t]       = tanhf(ssort[b*KK2 + t]);
    tt[t + 256] = tanhf(ssort[b*KK2 + t + 256]);
    __syncthreads();
    int c = t & 127, half = t >> 7;
    float s = 0.f;
    #pragma unroll 4
    for (int i = half*256; i < half*256 + 256; i++){
        int o = perm[b*KK2 + i];
        s = fmaf(tt[i], x[(size_t)o*128 + c], s);
    }
    if (half) part[c] = s;
    __syncthreads();
    if (!half) g[b*128 + c] = (s + part[c]) * (1.0f/KK2);
}

__global__ void mlp_k(const float* __restrict__ g,
                      const float* __restrict__ fc1w, const float* __restrict__ fc1b,
                      const float* __restrict__ fc2w, const float* __restrict__ fc2b,
                      const float* __restrict__ ow,  const float* __restrict__ ob,
                      float* __restrict__ out){
    __shared__ float gv[128], t1[256], t2[128];
    int b = blockIdx.x, t = threadIdx.x;
    if (t < 128) gv[t] = g[b*128 + t];
    __syncthreads();
    {
        float s = fc1b[t];
        for (int c = 0; c < 128; c++) s += gv[c]*fc1w[t*128 + c];
        t1[t] = fmaxf(s, 0.f);
    }
    __syncthreads();
    if (t < 128){
        float s = fc2b[t];
        for (int c = 0; c < 256; c++) s += t1[c]*fc2w[t*256 + c];
        t2[t] = fmaxf(s, 0.f);
    }
    __syncthreads();
    if (t < 10){
        float s = ob[t];
        for (int c = 0; c < 128; c++) s += t2[c]*ow[t*128 + c];
        out[b*10 + t] = s;
    }
}

// ---------------- launch ----------------
extern "C" void kernel_launch(void* const* d_in, const int* in_sizes, int n_in,
                              void* d_out, int out_size, void* d_ws, size_t ws_size,
                              hipStream_t stream){
    (void)in_sizes; (void)n_in; (void)out_size; (void)ws_size;
    const float* x    = (const float*)d_in[0];
    const int*   eidx = (const int*)d_in[1];
    const int*   src  = eidx;
    const int*   dst  = eidx + EE;
    const float* g1w  = (const float*)d_in[3];
    const float* g1as = (const float*)d_in[4];
    const float* g1ad = (const float*)d_in[5];
    const float* g1b  = (const float*)d_in[6];
    const float* g2w  = (const float*)d_in[7];
    const float* g2as = (const float*)d_in[8];
    const float* g2ad = (const float*)d_in[9];
    const float* g2b  = (const float*)d_in[10];
    const float* c1w  = (const float*)d_in[11];
    const float* c1b  = (const float*)d_in[12];
    const float* s1wrel  = (const float*)d_in[13];
    const float* s1brel  = (const float*)d_in[14];
    const float* s1wroot = (const float*)d_in[15];
    const float* c2w  = (const float*)d_in[16];
    const float* c2b  = (const float*)d_in[17];
    const float* s2wrel  = (const float*)d_in[18];
    const float* s2brel  = (const float*)d_in[19];
    const float* s2wroot = (const float*)d_in[20];
    const float* f1w  = (const float*)d_in[21];
    const float* f1b  = (const float*)d_in[22];
    const float* f2w  = (const float*)d_in[23];
    const float* f2b  = (const float*)d_in[24];
    const float* ow   = (const float*)d_in[25];
    const float* ob   = (const float*)d_in[26];
    float* out = (float*)d_out;

    char* ws = (char*)d_ws;
    size_t off = 0;
    auto alloc = [&](size_t bytes)->char*{
        char* p = ws + off;
        off += (bytes + 255) & ~(size_t)255;
        return p;
    };
    float* F0     = (float*)alloc((size_t)N1*256*4);
    float* F1     = (float*)alloc((size_t)N1*256*4);
    float* F2     = (float*)alloc((size_t)N2*128*4);
    float* AS     = (float*)alloc((size_t)N1*4*4);
    float* AD     = (float*)alloc((size_t)N1*4*4);
    int*   RP     = (int*)  alloc((size_t)(N1+1)*4);
    int*   CUR    = (int*)  alloc((size_t)N1*4);
    int*   EL     = (int*)  alloc((size_t)EE*4);
    float* DINV   = (float*)alloc((size_t)N1*4);
    float* SCORE  = (float*)alloc((size_t)N1*4);
    int*   PERM1  = (int*)  alloc((size_t)N2*4);
    float* SSORT1 = (float*)alloc((size_t)N2*4);
    int*   NID    = (int*)  alloc((size_t)N1*4);
    int*   E1S    = (int*)  alloc((size_t)EE*4);
    int*   E1D    = (int*)  alloc((size_t)EE*4);
    int*   RP2    = (int*)  alloc((size_t)(N2+1)*4);
    int*   CUR2   = (int*)  alloc((size_t)N2*4);
    int*   EL2    = (int*)  alloc((size_t)EE*4);
    float* DINV2  = (float*)alloc((size_t)N2*4);
    int*   PERM2  = (int*)  alloc((size_t)N3*4);
    float* SSORT2 = (float*)alloc((size_t)N3*4);
    float* GBUF   = (float*)alloc((size_t)NB*128*4);
    int*   BS     = (int*)  alloc((size_t)128*4);

    // ---- level-1 CSR (by dst; bucket entries = src node ids) ----
    hipMemsetAsync(CUR, 0, (size_t)N1*4, stream);
    count_dst<<<EE/256, 256, 0, stream>>>(dst, CUR, EE);
    blocksum_k<<<N1/256, 256, 0, stream>>>(CUR, BS);
    scan_write_k<<<N1/256, 256, 0, stream>>>(CUR, BS, N1/256, RP, CUR, DINV, N1);
    scatter1<<<EE/256, 256, 0, stream>>>(src, dst, CUR, EL, EE);

    // ---- GAT layer 1 (64 -> 4x64, relu) ----
    gemm_nt<<<dim3(N1/128, 2), 256, 0, stream>>>(x, g1w, F0, N1, 64, 256);
    attn_pre<<<N1/4, 256, 0, stream>>>(F0, g1as, g1ad, AS, AD);
    gat_agg<1><<<N1/4, 256, 0, stream>>>(F0, AS, AD, g1b, RP, EL, F1);

    // ---- GAT layer 2 (256 -> 4x64) ----
    gemm_nt<<<dim3(N1/128, 2), 256, 0, stream>>>(F1, g2w, F0, N1, 256, 256);
    attn_pre<<<N1/4, 256, 0, stream>>>(F0, g2as, g2ad, AS, AD);
    gat_agg<0><<<N1/4, 256, 0, stream>>>(F0, AS, AD, g2b, RP, EL, F1);

    // ---- GCN1 (256 -> 128, relu) ----
    gemm_nt<<<dim3(N1/128, 1), 256, 0, stream>>>(F1, c1w, F0, N1, 256, 128);
    gcn_agg<<<N1/4, 256, 0, stream>>>(F0, DINV, c1b, RP, EL, F1);

    // ---- SAGPool1 ----
    sag_score<<<N1/4, 256, 0, stream>>>(F1, s1wrel, s1brel, s1wroot, RP, EL, SCORE);
    hipMemsetAsync(NID, 0xFF, (size_t)N1*4, stream);   // -1
    topk_sel<<<NB, 1024, 0, stream>>>(SCORE, NPG1, KK1, PERM1, SSORT1, NID, 1);
    pool_gather<<<N2, 128, 0, stream>>>(F1, PERM1, SSORT1, F0);          // x2 -> F0

    // ---- level-2 CSR (remap + count fused) ----
    hipMemsetAsync(CUR2, 0, (size_t)N2*4, stream);
    remap_count<<<EE/256, 256, 0, stream>>>(src, dst, NID, E1S, E1D, CUR2, EE);
    blocksum_k<<<N2/256, 256, 0, stream>>>(CUR2, BS);
    scan_write_k<<<N2/256, 256, 0, stream>>>(CUR2, BS, N2/256, RP2, CUR2, DINV2, N2);
    scatter2<<<EE/256, 256, 0, stream>>>(E1S, E1D, CUR2, EL2, EE);

    // ---- GCN2 (128 -> 128, relu) ----
    gemm_nt<<<dim3(N2/128, 1), 256, 0, stream>>>(F0, c2w, F1, N2, 128, 128);
    gcn_agg<<<N2/4, 256, 0, stream>>>(F1, DINV2, c2b, RP2, EL2, F2);

    // ---- SAGPool2 ----
    sag_score<<<N2/4, 256, 0, stream>>>(F2, s2wrel, s2brel, s2wroot, RP2, EL2, SCORE);
    topk_sel<<<NB, 1024, 0, stream>>>(SCORE, NPG2, KK2, PERM2, SSORT2, nullptr, 0);

    // ---- fused gather + mean pool + MLP ----
    pool_mean2<<<NB, 256, 0, stream>>>(F2, PERM2, SSORT2, GBUF);
    mlp_k<<<NB, 256, 0, stream>>>(GBUF, f1w, f1b, f2w, f2b, ow, ob, out);
}

// Round 5
// 437.390 us; speedup vs baseline: 1.7487x; 1.1676x over previous
//
#include <hip/hip_runtime.h>

#define N1 32768
#define EE 524288
#define NB 16
#define NPG1 2048
#define KK1 1024
#define N2 16384
#define NPG2 1024
#define KK2 512
#define N3 8192

typedef _Float16 half8_t __attribute__((ext_vector_type(8)));
typedef float floatx16 __attribute__((ext_vector_type(16)));

static __device__ __forceinline__ float leaky(float x){ return x > 0.f ? x : 0.2f*x; }

// ---------------- CSR build ----------------
__global__ void count_dst(const int* __restrict__ dst, int* __restrict__ cnt, int E){
    int i = blockIdx.x*blockDim.x + threadIdx.x;
    if (i < E) atomicAdd(&cnt[dst[i]], 1);
}

__global__ void remap_count(const int* __restrict__ src, const int* __restrict__ dst,
                            const int* __restrict__ nid, int* __restrict__ ns,
                            int* __restrict__ nd, int* __restrict__ cnt, int E){
    int i = blockIdx.x*blockDim.x + threadIdx.x;
    if (i < E){
        int a = nid[src[i]], b = nid[dst[i]];
        ns[i] = a; nd[i] = b;
        if (a >= 0 && b >= 0) atomicAdd(&cnt[b], 1);
    }
}

__global__ void blocksum_k(const int* __restrict__ cnt, int* __restrict__ bs){
    __shared__ int red[4];
    int tid = threadIdx.x;
    int v = cnt[blockIdx.x*256 + tid];
    #pragma unroll
    for (int off = 32; off; off >>= 1) v += __shfl_xor(v, off);
    if ((tid & 63) == 0) red[tid >> 6] = v;
    __syncthreads();
    if (tid == 0) bs[blockIdx.x] = red[0] + red[1] + red[2] + red[3];
}

__global__ void scan_write_k(const int* __restrict__ cnt, const int* __restrict__ bs,
                             int nb, int* __restrict__ rowptr, int* __restrict__ cur,
                             float* __restrict__ dinv, int n){
    __shared__ int sbs[128];
    __shared__ int wsum[4];
    int tid = threadIdx.x;
    int b = blockIdx.x;
    if (tid < nb) sbs[tid] = bs[tid];
    __syncthreads();
    for (int off = 1; off < nb; off <<= 1){
        int v = 0;
        if (tid < nb && tid >= off) v = sbs[tid - off];
        __syncthreads();
        if (tid < nb) sbs[tid] += v;
        __syncthreads();
    }
    int base = (b == 0) ? 0 : sbs[b-1];
    int i = b*256 + tid;
    int c = cnt[i];
    int lane = tid & 63, wv = tid >> 6;
    int x = c;
    #pragma unroll
    for (int off = 1; off < 64; off <<= 1){ int y = __shfl_up(x, off); if (lane >= off) x += y; }
    if (lane == 63) wsum[wv] = x;
    __syncthreads();
    if (tid == 0){ int run = 0; for (int w2 = 0; w2 < 4; w2++){ int t = wsum[w2]; wsum[w2] = run; run += t; } }
    __syncthreads();
    int excl = x - c + wsum[wv];
    rowptr[i] = base + excl;
    cur[i]    = base + excl;
    dinv[i]   = rsqrtf((float)c + 1.0f);
    if (i == n-1) rowptr[n] = base + excl + c;
}

__global__ void scatter1(const int* __restrict__ src, const int* __restrict__ dst,
                         int* __restrict__ cur, int* __restrict__ esrc, int E){
    int i = blockIdx.x*blockDim.x + threadIdx.x;
    if (i < E){ int p = atomicAdd(&cur[dst[i]], 1); esrc[p] = src[i]; }
}

__global__ void scatter2(const int* __restrict__ ns, const int* __restrict__ nd,
                         int* __restrict__ cur, int* __restrict__ esrc, int E){
    int i = blockIdx.x*blockDim.x + threadIdx.x;
    if (i < E){
        int a = ns[i], b = nd[i];
        if (a >= 0 && b >= 0){ int p = atomicAdd(&cur[b], 1); esrc[p] = a; }
    }
}

// ------------- split-fp16 MFMA GEMM: C[n,M] = A[n,K] @ W[M,K]^T (fp32 I/O) --
// a = hi + lo (fp16 each); A.W = AH.WH + AH.WL + AL.WH + AL.WL, fp32 accum.
// Split done in-kernel during LDS staging. Error ~2^-22 rel (fp32-level).
// tile 128x128, KS=64, 4 waves, each wave 64x64 via 2x2 mfma_f32_32x32x16_f16.
// n mult of 128, M mult of 128, K mult of 64.
#define KS 64
static __device__ __forceinline__ int ldsoff(int row, int k8){
    return row*64 + ((k8 ^ (row & 7)) << 3);     // half-units; XOR-swizzled 16B slots
}

__global__ __launch_bounds__(256, 2) void gemm_h2(const float* __restrict__ A,
        const float* __restrict__ W, float* __restrict__ C, int n, int K, int M){
    __shared__ _Float16 sm[4*128*KS];
    _Float16* sAH = sm;
    _Float16* sAL = sm + 128*KS;
    _Float16* sWH = sm + 2*128*KS;
    _Float16* sWL = sm + 3*128*KS;
    int t = threadIdx.x;
    int lane = t & 63;
    int wid = t >> 6;
    int wr = wid >> 1, wc = wid & 1;
    int row0 = blockIdx.x*128, col0 = blockIdx.y*128;
    int srow = t >> 3;           // 0..31
    int sk8  = t & 7;            // 0..7

    floatx16 acc[2][2];
    #pragma unroll
    for (int i = 0; i < 2; i++)
        #pragma unroll
        for (int j = 0; j < 2; j++)
            #pragma unroll
            for (int q = 0; q < 16; q++) acc[i][j][q] = 0.f;

    for (int kk = 0; kk < K; kk += KS){
        #pragma unroll
        for (int p = 0; p < 4; p++){
            int r = srow + p*32;
            const float* ga = A + (size_t)(row0 + r)*K + kk + sk8*8;
            const float* gw = W + (size_t)(col0 + r)*K + kk + sk8*8;
            float4 a0 = *(const float4*)ga;
            float4 a1 = *(const float4*)(ga + 4);
            float4 w0 = *(const float4*)gw;
            float4 w1 = *(const float4*)(gw + 4);
            half8_t ahi, alo, whi, wlo;
            float av[8] = {a0.x,a0.y,a0.z,a0.w,a1.x,a1.y,a1.z,a1.w};
            float wv[8] = {w0.x,w0.y,w0.z,w0.w,w1.x,w1.y,w1.z,w1.w};
            #pragma unroll
            for (int q = 0; q < 8; q++){
                _Float16 h = (_Float16)av[q];
                ahi[q] = h; alo[q] = (_Float16)(av[q] - (float)h);
                _Float16 g = (_Float16)wv[q];
                whi[q] = g; wlo[q] = (_Float16)(wv[q] - (float)g);
            }
            int o = ldsoff(r, sk8);
            *(half8_t*)&sAH[o] = ahi;
            *(half8_t*)&sAL[o] = alo;
            *(half8_t*)&sWH[o] = whi;
            *(half8_t*)&sWL[o] = wlo;
        }
        __syncthreads();
        #pragma unroll
        for (int kc = 0; kc < 4; kc++){
            int k8 = kc*2 + (lane >> 5);
            int ra = wr*64 + (lane & 31);
            int rb = wc*64 + (lane & 31);
            half8_t ah0 = *(const half8_t*)&sAH[ldsoff(ra,      k8)];
            half8_t ah1 = *(const half8_t*)&sAH[ldsoff(ra + 32, k8)];
            half8_t al0 = *(const half8_t*)&sAL[ldsoff(ra,      k8)];
            half8_t al1 = *(const half8_t*)&sAL[ldsoff(ra + 32, k8)];
            half8_t bh0 = *(const half8_t*)&sWH[ldsoff(rb,      k8)];
            half8_t bh1 = *(const half8_t*)&sWH[ldsoff(rb + 32, k8)];
            half8_t bl0 = *(const half8_t*)&sWL[ldsoff(rb,      k8)];
            half8_t bl1 = *(const half8_t*)&sWL[ldsoff(rb + 32, k8)];
            acc[0][0] = __builtin_amdgcn_mfma_f32_32x32x16_f16(ah0, bh0, acc[0][0], 0,0,0);
            acc[0][0] = __builtin_amdgcn_mfma_f32_32x32x16_f16(ah0, bl0, acc[0][0], 0,0,0);
            acc[0][0] = __builtin_amdgcn_mfma_f32_32x32x16_f16(al0, bh0, acc[0][0], 0,0,0);
            acc[0][0] = __builtin_amdgcn_mfma_f32_32x32x16_f16(al0, bl0, acc[0][0], 0,0,0);
            acc[0][1] = __builtin_amdgcn_mfma_f32_32x32x16_f16(ah0, bh1, acc[0][1], 0,0,0);
            acc[0][1] = __builtin_amdgcn_mfma_f32_32x32x16_f16(ah0, bl1, acc[0][1], 0,0,0);
            acc[0][1] = __builtin_amdgcn_mfma_f32_32x32x16_f16(al0, bh1, acc[0][1], 0,0,0);
            acc[0][1] = __builtin_amdgcn_mfma_f32_32x32x16_f16(al0, bl1, acc[0][1], 0,0,0);
            acc[1][0] = __builtin_amdgcn_mfma_f32_32x32x16_f16(ah1, bh0, acc[1][0], 0,0,0);
            acc[1][0] = __builtin_amdgcn_mfma_f32_32x32x16_f16(ah1, bl0, acc[1][0], 0,0,0);
            acc[1][0] = __builtin_amdgcn_mfma_f32_32x32x16_f16(al1, bh0, acc[1][0], 0,0,0);
            acc[1][0] = __builtin_amdgcn_mfma_f32_32x32x16_f16(al1, bl0, acc[1][0], 0,0,0);
            acc[1][1] = __builtin_amdgcn_mfma_f32_32x32x16_f16(ah1, bh1, acc[1][1], 0,0,0);
            acc[1][1] = __builtin_amdgcn_mfma_f32_32x32x16_f16(ah1, bl1, acc[1][1], 0,0,0);
            acc[1][1] = __builtin_amdgcn_mfma_f32_32x32x16_f16(al1, bh1, acc[1][1], 0,0,0);
            acc[1][1] = __builtin_amdgcn_mfma_f32_32x32x16_f16(al1, bl1, acc[1][1], 0,0,0);
        }
        __syncthreads();
    }
    // C/D layout (verified): col = lane&31, row = (reg&3) + 8*(reg>>2) + 4*(lane>>5)
    #pragma unroll
    for (int rt = 0; rt < 2; rt++)
        #pragma unroll
        for (int ct = 0; ct < 2; ct++){
            int baser = row0 + wr*64 + rt*32 + 4*(lane >> 5);
            int c = col0 + wc*64 + ct*32 + (lane & 31);
            #pragma unroll
            for (int r = 0; r < 16; r++){
                int rr = baser + (r & 3) + 8*(r >> 2);
                C[(size_t)rr*M + c] = acc[rt][ct][r];
            }
        }
}

// ---------------- GAT attention coefficients ----------------
__global__ void attn_pre(const float* __restrict__ h, const float* __restrict__ wsrc,
                         const float* __restrict__ wdst, float* __restrict__ as_,
                         float* __restrict__ ad_){
    int lane = threadIdx.x & 63;
    int w = threadIdx.x >> 6;
    int d = blockIdx.x*4 + w;
    float4 hv = *(const float4*)(h + (size_t)d*256 + lane*4);
    float4 ws = *(const float4*)(wsrc + lane*4);
    float4 wd = *(const float4*)(wdst + lane*4);
    float ps = hv.x*ws.x + hv.y*ws.y + hv.z*ws.z + hv.w*ws.w;
    float pd = hv.x*wd.x + hv.y*wd.y + hv.z*wd.z + hv.w*wd.w;
    #pragma unroll
    for (int m = 8; m; m >>= 1){ ps += __shfl_xor(ps, m); pd += __shfl_xor(pd, m); }
    if ((lane & 15) == 0){
        as_[d*4 + (lane >> 4)] = ps;
        ad_[d*4 + (lane >> 4)] = pd;
    }
}

// ---------------- GAT aggregation: max pass + fused den/acc pass ------------
template<int RELU>
__global__ void gat_agg(const float* __restrict__ h, const float* __restrict__ as_,
                        const float* __restrict__ ad_, const float* __restrict__ bias,
                        const int* __restrict__ rowptr, const int* __restrict__ esrc,
                        float* __restrict__ out){
    int lane = threadIdx.x & 63;
    int w = threadIdx.x >> 6;
    int nb = gridDim.x;
    int b = blockIdx.x;
    int sb = (b & 7)*(nb >> 3) + (b >> 3);
    int d = sb*4 + w;
    int beg = rowptr[d], end = rowptr[d+1];

    float ad4[4], m[4], es[4];
    #pragma unroll
    for (int hh = 0; hh < 4; hh++) ad4[hh] = ad_[(d<<2) + hh];
    #pragma unroll
    for (int hh = 0; hh < 4; hh++){ es[hh] = leaky(as_[(d<<2) + hh] + ad4[hh]); m[hh] = es[hh]; }

    for (int i = beg + lane; i < end; i += 64){
        int s = esrc[i];
        float4 a4 = *(const float4*)(as_ + (s<<2));
        m[0] = fmaxf(m[0], leaky(a4.x + ad4[0]));
        m[1] = fmaxf(m[1], leaky(a4.y + ad4[1]));
        m[2] = fmaxf(m[2], leaky(a4.z + ad4[2]));
        m[3] = fmaxf(m[3], leaky(a4.w + ad4[3]));
    }
    #pragma unroll
    for (int off = 32; off; off >>= 1)
        #pragma unroll
        for (int hh = 0; hh < 4; hh++) m[hh] = fmaxf(m[hh], __shfl_xor(m[hh], off));

    int hh = lane >> 4;
    int c0 = lane*4;
    float mh  = m[hh];
    float adh = ad4[hh];
    float den = __expf(es[hh] - mh);
    float4 hd = *(const float4*)(h + (d<<8) + c0);
    float4 acc;
    acc.x = den*hd.x; acc.y = den*hd.y; acc.z = den*hd.z; acc.w = den*hd.w;

    int i = beg;
    if (i < end){
        int s = esrc[i];
        float a_cur = as_[(s<<2) + hh];
        float4 hcur = *(const float4*)(h + (s<<8) + c0);
        for (++i; i < end; ++i){
            int s2 = esrc[i];
            float a_nxt = as_[(s2<<2) + hh];
            float4 hnxt = *(const float4*)(h + (s2<<8) + c0);
            float p = __expf(leaky(a_cur + adh) - mh);
            den += p;
            acc.x = fmaf(p, hcur.x, acc.x);
            acc.y = fmaf(p, hcur.y, acc.y);
            acc.z = fmaf(p, hcur.z, acc.z);
            acc.w = fmaf(p, hcur.w, acc.w);
            a_cur = a_nxt; hcur = hnxt;
        }
        float p = __expf(leaky(a_cur + adh) - mh);
        den += p;
        acc.x = fmaf(p, hcur.x, acc.x);
        acc.y = fmaf(p, hcur.y, acc.y);
        acc.z = fmaf(p, hcur.z, acc.z);
        acc.w = fmaf(p, hcur.w, acc.w);
    }
    float r = 1.0f / (den + 1e-16f);
    float4 bv = *(const float4*)(bias + c0);
    acc.x = acc.x*r + bv.x; acc.y = acc.y*r + bv.y;
    acc.z = acc.z*r + bv.z; acc.w = acc.w*r + bv.w;
    if (RELU){
        acc.x = fmaxf(acc.x, 0.f); acc.y = fmaxf(acc.y, 0.f);
        acc.z = fmaxf(acc.z, 0.f); acc.w = fmaxf(acc.w, 0.f);
    }
    *(float4*)(out + (d<<8) + c0) = acc;
}

// ---------------- GCN aggregation ----------------
__global__ void gcn_agg(const float* __restrict__ h, const float* __restrict__ dinv,
                        const float* __restrict__ bias, const int* __restrict__ rowptr,
                        const int* __restrict__ esrc, float* __restrict__ out){
    int lane = threadIdx.x & 63;
    int w = threadIdx.x >> 6;
    int nb = gridDim.x;
    int b = blockIdx.x;
    int sb = (b & 7)*(nb >> 3) + (b >> 3);
    int d = sb*4 + w;
    int beg = rowptr[d], end = rowptr[d+1];
    float dv = dinv[d];
    int c0 = lane*2;
    float2 hd = *(const float2*)(h + (d<<7) + c0);
    float self = dv*dv;
    float ax = self*hd.x, ay = self*hd.y;
    int i = beg;
    if (i < end){
        int s = esrc[i];
        float di_cur = dinv[s];
        float2 hcur = *(const float2*)(h + (s<<7) + c0);
        for (++i; i < end; ++i){
            int s2 = esrc[i];
            float di_nxt = dinv[s2];
            float2 hnxt = *(const float2*)(h + (s2<<7) + c0);
            float coef = di_cur*dv;
            ax = fmaf(coef, hcur.x, ax);
            ay = fmaf(coef, hcur.y, ay);
            di_cur = di_nxt; hcur = hnxt;
        }
        float coef = di_cur*dv;
        ax = fmaf(coef, hcur.x, ax);
        ay = fmaf(coef, hcur.y, ay);
    }
    ax = fmaxf(ax + bias[c0], 0.f);
    ay = fmaxf(ay + bias[c0+1], 0.f);
    float2 o; o.x = ax; o.y = ay;
    *(float2*)(out + (d<<7) + c0) = o;
}

// ---------------- SAGPool score ----------------
__global__ void sag_score(const float* __restrict__ x, const float* __restrict__ wrel,
                          const float* __restrict__ brel, const float* __restrict__ wroot,
                          const int* __restrict__ rowptr, const int* __restrict__ esrc,
                          float* __restrict__ score){
    int lane = threadIdx.x & 63;
    int w = threadIdx.x >> 6;
    int nb = gridDim.x;
    int b = blockIdx.x;
    int sb = (b & 7)*(nb >> 3) + (b >> 3);
    int d = sb*4 + w;
    int beg = rowptr[d], end = rowptr[d+1];
    int c0 = lane*2;
    float aggx = 0.f, aggy = 0.f;
    int i = beg;
    if (i < end){
        int s = esrc[i];
        float2 hcur = *(const float2*)(x + (s<<7) + c0);
        for (++i; i < end; ++i){
            int s2 = esrc[i];
            float2 hnxt = *(const float2*)(x + (s2<<7) + c0);
            aggx += hcur.x; aggy += hcur.y;
            hcur = hnxt;
        }
        aggx += hcur.x; aggy += hcur.y;
    }
    float2 xd = *(const float2*)(x + (d<<7) + c0);
    float part = aggx*wrel[c0] + aggy*wrel[c0+1] + xd.x*wroot[c0] + xd.y*wroot[c0+1];
    #pragma unroll
    for (int off = 32; off; off >>= 1) part += __shfl_xor(part, off);
    if (lane == 0) score[d] = part + brel[0];
}

// ---------------- radix-select top-k ----------------
__global__ __launch_bounds__(1024) void topk_sel(const float* __restrict__ score,
        int npg, int k, int* __restrict__ perm, float* __restrict__ ssort,
        int* __restrict__ nid, int writeNid){
    __shared__ unsigned keys[2048];
    __shared__ int hist[256];
    __shared__ int cge[256];
    __shared__ int warpsum[16];
    __shared__ int s_bin, s_need;
    int g = blockIdx.x, tid = threadIdx.x;
    for (int i = tid; i < npg; i += 1024){
        unsigned u = __float_as_uint(score[g*npg + i]);
        u = (u & 0x80000000u) ? ~u : (u | 0x80000000u);
        keys[i] = u;
    }
    if (tid == 0) s_need = k;
    __syncthreads();
    unsigned prefix = 0u, pmask = 0u;
    #pragma unroll
    for (int shift = 24; shift >= 0; shift -= 8){
        if (tid < 256) hist[tid] = 0;
        __syncthreads();
        for (int i = tid; i < npg; i += 1024){
            unsigned u = keys[i];
            if ((u & pmask) == prefix) atomicAdd(&hist[(u >> shift) & 255u], 1);
        }
        __syncthreads();
        if (tid < 256) cge[tid] = hist[tid];
        __syncthreads();
        for (int off = 1; off < 256; off <<= 1){
            int v = 0;
            if (tid < 256 - off) v = cge[tid + off];
            __syncthreads();
            if (tid < 256) cge[tid] += v;
            __syncthreads();
        }
        int need = s_need;
        if (tid < 256){
            int above = (tid == 255) ? 0 : cge[tid + 1];
            if (cge[tid] >= need && above < need) s_bin = tid;
        }
        __syncthreads();
        if (tid == 0) s_need = need - ((s_bin == 255) ? 0 : cge[s_bin + 1]);
        __syncthreads();
        prefix |= ((unsigned)s_bin) << shift;
        pmask  |= (255u << shift);
        __syncthreads();
    }
    unsigned thr = prefix;
    int m = s_need;
    int i0 = 2*tid, i1 = 2*tid + 1;
    int f0 = 0, f1 = 0;
    if (i0 < npg){
        unsigned u = keys[i0];
        if (u > thr) f0 = 1;
        else if (u == thr){
            int r = 0;
            for (int j = 0; j < i0; j++) r += (keys[j] == thr);
            f0 = (r < m) ? 1 : 0;
        }
    }
    if (i1 < npg){
        unsigned u = keys[i1];
        if (u > thr) f1 = 1;
        else if (u == thr){
            int r = 0;
            for (int j = 0; j < i1; j++) r += (keys[j] == thr);
            f1 = (r < m) ? 1 : 0;
        }
    }
    int pair = f0 + f1;
    int lane = tid & 63, wv = tid >> 6;
    int x = pair;
    #pragma unroll
    for (int off = 1; off < 64; off <<= 1){ int y = __shfl_up(x, off); if (lane >= off) x += y; }
    if (lane == 63) warpsum[wv] = x;
    __syncthreads();
    if (tid == 0){ int run = 0; for (int w2 = 0; w2 < 16; w2++){ int t = warpsum[w2]; warpsum[w2] = run; run += t; } }
    __syncthreads();
    int excl = x - pair + warpsum[wv];
    if (f0){
        int pos = excl;
        int node = g*npg + i0;
        perm[g*k + pos] = node;
        ssort[g*k + pos] = score[node];
        if (writeNid) nid[node] = g*k + pos;
    }
    if (f1){
        int pos = excl + f0;
        int node = g*npg + i1;
        perm[g*k + pos] = node;
        ssort[g*k + pos] = score[node];
        if (writeNid) nid[node] = g*k + pos;
    }
}

__global__ void pool_gather(const float* __restrict__ x, const int* __restrict__ perm,
                            const float* __restrict__ ssort, float* __restrict__ xn){
    int j = blockIdx.x; int c = threadIdx.x;
    int o = perm[j];
    float t = tanhf(ssort[j]);
    xn[(size_t)j*128 + c] = x[(size_t)o*128 + c] * t;
}

__global__ void pool_mean2(const float* __restrict__ x, const int* __restrict__ perm,
                           const float* __restrict__ ssort, float* __restrict__ g){
    __shared__ float tt[KK2];
    __shared__ float part[128];
    int b = blockIdx.x, t = threadIdx.x;     // 256 threads
    tt[t]       = tanhf(ssort[b*KK2 + t]);
    tt[t + 256] = tanhf(ssort[b*KK2 + t + 256]);
    __syncthreads();
    int c = t & 127, half = t >> 7;
    float s = 0.f;
    #pragma unroll 4
    for (int i = half*256; i < half*256 + 256; i++){
        int o = perm[b*KK2 + i];
        s = fmaf(tt[i], x[(size_t)o*128 + c], s);
    }
    if (half) part[c] = s;
    __syncthreads();
    if (!half) g[b*128 + c] = (s + part[c]) * (1.0f/KK2);
}

__global__ void mlp_k(const float* __restrict__ g,
                      const float* __restrict__ fc1w, const float* __restrict__ fc1b,
                      const float* __restrict__ fc2w, const float* __restrict__ fc2b,
                      const float* __restrict__ ow,  const float* __restrict__ ob,
                      float* __restrict__ out){
    __shared__ float gv[128], t1[256], t2[128];
    int b = blockIdx.x, t = threadIdx.x;
    if (t < 128) gv[t] = g[b*128 + t];
    __syncthreads();
    {
        float s = fc1b[t];
        for (int c = 0; c < 128; c++) s += gv[c]*fc1w[t*128 + c];
        t1[t] = fmaxf(s, 0.f);
    }
    __syncthreads();
    if (t < 128){
        float s = fc2b[t];
        for (int c = 0; c < 256; c++) s += t1[c]*fc2w[t*256 + c];
        t2[t] = fmaxf(s, 0.f);
    }
    __syncthreads();
    if (t < 10){
        float s = ob[t];
        for (int c = 0; c < 128; c++) s += t2[c]*ow[t*128 + c];
        out[b*10 + t] = s;
    }
}

// ---------------- launch ----------------
extern "C" void kernel_launch(void* const* d_in, const int* in_sizes, int n_in,
                              void* d_out, int out_size, void* d_ws, size_t ws_size,
                              hipStream_t stream){
    (void)in_sizes; (void)n_in; (void)out_size; (void)ws_size;
    const float* x    = (const float*)d_in[0];
    const int*   eidx = (const int*)d_in[1];
    const int*   src  = eidx;
    const int*   dst  = eidx + EE;
    const float* g1w  = (const float*)d_in[3];
    const float* g1as = (const float*)d_in[4];
    const float* g1ad = (const float*)d_in[5];
    const float* g1b  = (const float*)d_in[6];
    const float* g2w  = (const float*)d_in[7];
    const float* g2as = (const float*)d_in[8];
    const float* g2ad = (const float*)d_in[9];
    const float* g2b  = (const float*)d_in[10];
    const float* c1w  = (const float*)d_in[11];
    const float* c1b  = (const float*)d_in[12];
    const float* s1wrel  = (const float*)d_in[13];
    const float* s1brel  = (const float*)d_in[14];
    const float* s1wroot = (const float*)d_in[15];
    const float* c2w  = (const float*)d_in[16];
    const float* c2b  = (const float*)d_in[17];
    const float* s2wrel  = (const float*)d_in[18];
    const float* s2brel  = (const float*)d_in[19];
    const float* s2wroot = (const float*)d_in[20];
    const float* f1w  = (const float*)d_in[21];
    const float* f1b  = (const float*)d_in[22];
    const float* f2w  = (const float*)d_in[23];
    const float* f2b  = (const float*)d_in[24];
    const float* ow   = (const float*)d_in[25];
    const float* ob   = (const float*)d_in[26];
    float* out = (float*)d_out;

    char* ws = (char*)d_ws;
    size_t off = 0;
    auto alloc = [&](size_t bytes)->char*{
        char* p = ws + off;
        off += (bytes + 255) & ~(size_t)255;
        return p;
    };
    float* F0     = (float*)alloc((size_t)N1*256*4);
    float* F1     = (float*)alloc((size_t)N1*256*4);
    float* F2     = (float*)alloc((size_t)N2*128*4);
    float* AS     = (float*)alloc((size_t)N1*4*4);
    float* AD     = (float*)alloc((size_t)N1*4*4);
    int*   RP     = (int*)  alloc((size_t)(N1+1)*4);
    int*   CUR    = (int*)  alloc((size_t)N1*4);
    int*   EL     = (int*)  alloc((size_t)EE*4);
    float* DINV   = (float*)alloc((size_t)N1*4);
    float* SCORE  = (float*)alloc((size_t)N1*4);
    int*   PERM1  = (int*)  alloc((size_t)N2*4);
    float* SSORT1 = (float*)alloc((size_t)N2*4);
    int*   NID    = (int*)  alloc((size_t)N1*4);
    int*   E1S    = (int*)  alloc((size_t)EE*4);
    int*   E1D    = (int*)  alloc((size_t)EE*4);
    int*   RP2    = (int*)  alloc((size_t)(N2+1)*4);
    int*   CUR2   = (int*)  alloc((size_t)N2*4);
    int*   EL2    = (int*)  alloc((size_t)EE*4);
    float* DINV2  = (float*)alloc((size_t)N2*4);
    int*   PERM2  = (int*)  alloc((size_t)N3*4);
    float* SSORT2 = (float*)alloc((size_t)N3*4);
    float* GBUF   = (float*)alloc((size_t)NB*128*4);
    int*   BS     = (int*)  alloc((size_t)128*4);

    // ---- level-1 CSR (by dst; bucket entries = src node ids) ----
    hipMemsetAsync(CUR, 0, (size_t)N1*4, stream);
    count_dst<<<EE/256, 256, 0, stream>>>(dst, CUR, EE);
    blocksum_k<<<N1/256, 256, 0, stream>>>(CUR, BS);
    scan_write_k<<<N1/256, 256, 0, stream>>>(CUR, BS, N1/256, RP, CUR, DINV, N1);
    scatter1<<<EE/256, 256, 0, stream>>>(src, dst, CUR, EL, EE);

    // ---- GAT layer 1 (64 -> 4x64, relu) ----
    gemm_h2<<<dim3(N1/128, 2), 256, 0, stream>>>(x, g1w, F0, N1, 64, 256);
    attn_pre<<<N1/4, 256, 0, stream>>>(F0, g1as, g1ad, AS, AD);
    gat_agg<1><<<N1/4, 256, 0, stream>>>(F0, AS, AD, g1b, RP, EL, F1);

    // ---- GAT layer 2 (256 -> 4x64) ----
    gemm_h2<<<dim3(N1/128, 2), 256, 0, stream>>>(F1, g2w, F0, N1, 256, 256);
    attn_pre<<<N1/4, 256, 0, stream>>>(F0, g2as, g2ad, AS, AD);
    gat_agg<0><<<N1/4, 256, 0, stream>>>(F0, AS, AD, g2b, RP, EL, F1);

    // ---- GCN1 (256 -> 128, relu) ----
    gemm_h2<<<dim3(N1/128, 1), 256, 0, stream>>>(F1, c1w, F0, N1, 256, 128);
    gcn_agg<<<N1/4, 256, 0, stream>>>(F0, DINV, c1b, RP, EL, F1);

    // ---- SAGPool1 ----
    sag_score<<<N1/4, 256, 0, stream>>>(F1, s1wrel, s1brel, s1wroot, RP, EL, SCORE);
    hipMemsetAsync(NID, 0xFF, (size_t)N1*4, stream);   // -1
    topk_sel<<<NB, 1024, 0, stream>>>(SCORE, NPG1, KK1, PERM1, SSORT1, NID, 1);
    pool_gather<<<N2, 128, 0, stream>>>(F1, PERM1, SSORT1, F0);          // x2 -> F0

    // ---- level-2 CSR (remap + count fused) ----
    hipMemsetAsync(CUR2, 0, (size_t)N2*4, stream);
    remap_count<<<EE/256, 256, 0, stream>>>(src, dst, NID, E1S, E1D, CUR2, EE);
    blocksum_k<<<N2/256, 256, 0, stream>>>(CUR2, BS);
    scan_write_k<<<N2/256, 256, 0, stream>>>(CUR2, BS, N2/256, RP2, CUR2, DINV2, N2);
    scatter2<<<EE/256, 256, 0, stream>>>(E1S, E1D, CUR2, EL2, EE);

    // ---- GCN2 (128 -> 128, relu) ----
    gemm_h2<<<dim3(N2/128, 1), 256, 0, stream>>>(F0, c2w, F1, N2, 128, 128);
    gcn_agg<<<N2/4, 256, 0, stream>>>(F1, DINV2, c2b, RP2, EL2, F2);

    // ---- SAGPool2 ----
    sag_score<<<N2/4, 256, 0, stream>>>(F2, s2wrel, s2brel, s2wroot, RP2, EL2, SCORE);
    topk_sel<<<NB, 1024, 0, stream>>>(SCORE, NPG2, KK2, PERM2, SSORT2, nullptr, 0);

    // ---- fused gather + mean pool + MLP ----
    pool_mean2<<<NB, 256, 0, stream>>>(F2, PERM2, SSORT2, GBUF);
    mlp_k<<<NB, 256, 0, stream>>>(GBUF, f1w, f1b, f2w, f2b, ow, ob, out);
}

// Round 6
// 403.994 us; speedup vs baseline: 1.8933x; 1.0827x over previous
//
#include <hip/hip_runtime.h>

#define N1 32768
#define EE 524288
#define NB 16
#define NPG1 2048
#define KK1 1024
#define N2 16384
#define NPG2 1024
#define KK2 512
#define N3 8192

typedef _Float16 half8_t __attribute__((ext_vector_type(8)));
typedef float floatx16 __attribute__((ext_vector_type(16)));

static __device__ __forceinline__ float leaky(float x){ return x > 0.f ? x : 0.2f*x; }

// ---------------- CSR build ----------------
__global__ void count_dst(const int* __restrict__ dst, int* __restrict__ cnt, int E){
    int i = blockIdx.x*blockDim.x + threadIdx.x;
    if (i < E) atomicAdd(&cnt[dst[i]], 1);
}

__global__ void remap_count(const int* __restrict__ src, const int* __restrict__ dst,
                            const int* __restrict__ nid, int* __restrict__ ns,
                            int* __restrict__ nd, int* __restrict__ cnt, int E){
    int i = blockIdx.x*blockDim.x + threadIdx.x;
    if (i < E){
        int a = nid[src[i]], b = nid[dst[i]];
        ns[i] = a; nd[i] = b;
        if (a >= 0 && b >= 0) atomicAdd(&cnt[b], 1);
    }
}

__global__ void blocksum_k(const int* __restrict__ cnt, int* __restrict__ bs){
    __shared__ int red[4];
    int tid = threadIdx.x;
    int v = cnt[blockIdx.x*256 + tid];
    #pragma unroll
    for (int off = 32; off; off >>= 1) v += __shfl_xor(v, off);
    if ((tid & 63) == 0) red[tid >> 6] = v;
    __syncthreads();
    if (tid == 0) bs[blockIdx.x] = red[0] + red[1] + red[2] + red[3];
}

__global__ void scan_write_k(const int* __restrict__ cnt, const int* __restrict__ bs,
                             int nb, int* __restrict__ rowptr, int* __restrict__ cur,
                             float* __restrict__ dinv, int n){
    __shared__ int sbs[128];
    __shared__ int wsum[4];
    int tid = threadIdx.x;
    int b = blockIdx.x;
    if (tid < nb) sbs[tid] = bs[tid];
    __syncthreads();
    for (int off = 1; off < nb; off <<= 1){
        int v = 0;
        if (tid < nb && tid >= off) v = sbs[tid - off];
        __syncthreads();
        if (tid < nb) sbs[tid] += v;
        __syncthreads();
    }
    int base = (b == 0) ? 0 : sbs[b-1];
    int i = b*256 + tid;
    int c = cnt[i];
    int lane = tid & 63, wv = tid >> 6;
    int x = c;
    #pragma unroll
    for (int off = 1; off < 64; off <<= 1){ int y = __shfl_up(x, off); if (lane >= off) x += y; }
    if (lane == 63) wsum[wv] = x;
    __syncthreads();
    if (tid == 0){ int run = 0; for (int w2 = 0; w2 < 4; w2++){ int t = wsum[w2]; wsum[w2] = run; run += t; } }
    __syncthreads();
    int excl = x - c + wsum[wv];
    rowptr[i] = base + excl;
    cur[i]    = base + excl;
    dinv[i]   = rsqrtf((float)c + 1.0f);
    if (i == n-1) rowptr[n] = base + excl + c;
}

__global__ void scatter1(const int* __restrict__ src, const int* __restrict__ dst,
                         int* __restrict__ cur, int* __restrict__ esrc, int E){
    int i = blockIdx.x*blockDim.x + threadIdx.x;
    if (i < E){ int p = atomicAdd(&cur[dst[i]], 1); esrc[p] = src[i]; }
}

__global__ void scatter2(const int* __restrict__ ns, const int* __restrict__ nd,
                         int* __restrict__ cur, int* __restrict__ esrc, int E){
    int i = blockIdx.x*blockDim.x + threadIdx.x;
    if (i < E){
        int a = ns[i], b = nd[i];
        if (a >= 0 && b >= 0){ int p = atomicAdd(&cur[b], 1); esrc[p] = a; }
    }
}

// ------------- split-fp16 MFMA GEMM: C = A @ W^T (fp32 I/O) ----------------
// a = hi + lo; A.W ≈ AH.WH + AH.WL + AL.WH (ll term ~2^-22, dropped).
#define KS 64
static __device__ __forceinline__ int ldsoff(int row, int k8){
    return row*64 + ((k8 ^ (row & 7)) << 3);     // half-units; XOR-swizzled 16B slots
}

__global__ __launch_bounds__(256, 2) void gemm_h2(const float* __restrict__ A,
        const float* __restrict__ W, float* __restrict__ C, int n, int K, int M){
    __shared__ _Float16 sm[4*128*KS];
    _Float16* sAH = sm;
    _Float16* sAL = sm + 128*KS;
    _Float16* sWH = sm + 2*128*KS;
    _Float16* sWL = sm + 3*128*KS;
    int t = threadIdx.x;
    int lane = t & 63;
    int wid = t >> 6;
    int wr = wid >> 1, wc = wid & 1;
    int row0 = blockIdx.x*128, col0 = blockIdx.y*128;
    int srow = t >> 3;           // 0..31
    int sk8  = t & 7;            // 0..7

    floatx16 acc[2][2];
    #pragma unroll
    for (int i = 0; i < 2; i++)
        #pragma unroll
        for (int j = 0; j < 2; j++)
            #pragma unroll
            for (int q = 0; q < 16; q++) acc[i][j][q] = 0.f;

    for (int kk = 0; kk < K; kk += KS){
        #pragma unroll
        for (int p = 0; p < 4; p++){
            int r = srow + p*32;
            const float* ga = A + (size_t)(row0 + r)*K + kk + sk8*8;
            const float* gw = W + (size_t)(col0 + r)*K + kk + sk8*8;
            float4 a0 = *(const float4*)ga;
            float4 a1 = *(const float4*)(ga + 4);
            float4 w0 = *(const float4*)gw;
            float4 w1 = *(const float4*)(gw + 4);
            half8_t ahi, alo, whi, wlo;
            float av[8] = {a0.x,a0.y,a0.z,a0.w,a1.x,a1.y,a1.z,a1.w};
            float wv[8] = {w0.x,w0.y,w0.z,w0.w,w1.x,w1.y,w1.z,w1.w};
            #pragma unroll
            for (int q = 0; q < 8; q++){
                _Float16 h = (_Float16)av[q];
                ahi[q] = h; alo[q] = (_Float16)(av[q] - (float)h);
                _Float16 g = (_Float16)wv[q];
                whi[q] = g; wlo[q] = (_Float16)(wv[q] - (float)g);
            }
            int o = ldsoff(r, sk8);
            *(half8_t*)&sAH[o] = ahi;
            *(half8_t*)&sAL[o] = alo;
            *(half8_t*)&sWH[o] = whi;
            *(half8_t*)&sWL[o] = wlo;
        }
        __syncthreads();
        #pragma unroll
        for (int kc = 0; kc < 4; kc++){
            int k8 = kc*2 + (lane >> 5);
            int ra = wr*64 + (lane & 31);
            int rb = wc*64 + (lane & 31);
            half8_t ah0 = *(const half8_t*)&sAH[ldsoff(ra,      k8)];
            half8_t ah1 = *(const half8_t*)&sAH[ldsoff(ra + 32, k8)];
            half8_t al0 = *(const half8_t*)&sAL[ldsoff(ra,      k8)];
            half8_t al1 = *(const half8_t*)&sAL[ldsoff(ra + 32, k8)];
            half8_t bh0 = *(const half8_t*)&sWH[ldsoff(rb,      k8)];
            half8_t bh1 = *(const half8_t*)&sWH[ldsoff(rb + 32, k8)];
            half8_t bl0 = *(const half8_t*)&sWL[ldsoff(rb,      k8)];
            half8_t bl1 = *(const half8_t*)&sWL[ldsoff(rb + 32, k8)];
            acc[0][0] = __builtin_amdgcn_mfma_f32_32x32x16_f16(ah0, bh0, acc[0][0], 0,0,0);
            acc[0][0] = __builtin_amdgcn_mfma_f32_32x32x16_f16(ah0, bl0, acc[0][0], 0,0,0);
            acc[0][0] = __builtin_amdgcn_mfma_f32_32x32x16_f16(al0, bh0, acc[0][0], 0,0,0);
            acc[0][1] = __builtin_amdgcn_mfma_f32_32x32x16_f16(ah0, bh1, acc[0][1], 0,0,0);
            acc[0][1] = __builtin_amdgcn_mfma_f32_32x32x16_f16(ah0, bl1, acc[0][1], 0,0,0);
            acc[0][1] = __builtin_amdgcn_mfma_f32_32x32x16_f16(al0, bh1, acc[0][1], 0,0,0);
            acc[1][0] = __builtin_amdgcn_mfma_f32_32x32x16_f16(ah1, bh0, acc[1][0], 0,0,0);
            acc[1][0] = __builtin_amdgcn_mfma_f32_32x32x16_f16(ah1, bl0, acc[1][0], 0,0,0);
            acc[1][0] = __builtin_amdgcn_mfma_f32_32x32x16_f16(al1, bh0, acc[1][0], 0,0,0);
            acc[1][1] = __builtin_amdgcn_mfma_f32_32x32x16_f16(ah1, bh1, acc[1][1], 0,0,0);
            acc[1][1] = __builtin_amdgcn_mfma_f32_32x32x16_f16(ah1, bl1, acc[1][1], 0,0,0);
            acc[1][1] = __builtin_amdgcn_mfma_f32_32x32x16_f16(al1, bh1, acc[1][1], 0,0,0);
        }
        __syncthreads();
    }
    // C/D layout: col = lane&31, row = (reg&3) + 8*(reg>>2) + 4*(lane>>5)
    #pragma unroll
    for (int rt = 0; rt < 2; rt++)
        #pragma unroll
        for (int ct = 0; ct < 2; ct++){
            int baser = row0 + wr*64 + rt*32 + 4*(lane >> 5);
            int c = col0 + wc*64 + ct*32 + (lane & 31);
            #pragma unroll
            for (int r = 0; r < 16; r++){
                int rr = baser + (r & 3) + 8*(r >> 2);
                C[(size_t)rr*M + c] = acc[rt][ct][r];
            }
        }
}

// ---------------- GAT attention coefficients ----------------
__global__ void attn_pre(const float* __restrict__ h, const float* __restrict__ wsrc,
                         const float* __restrict__ wdst, float* __restrict__ as_,
                         float* __restrict__ ad_){
    int lane = threadIdx.x & 63;
    int w = threadIdx.x >> 6;
    int d = blockIdx.x*4 + w;
    float4 hv = *(const float4*)(h + (size_t)d*256 + lane*4);
    float4 ws = *(const float4*)(wsrc + lane*4);
    float4 wd = *(const float4*)(wdst + lane*4);
    float ps = hv.x*ws.x + hv.y*ws.y + hv.z*ws.z + hv.w*ws.w;
    float pd = hv.x*wd.x + hv.y*wd.y + hv.z*wd.z + hv.w*wd.w;
    #pragma unroll
    for (int m = 8; m; m >>= 1){ ps += __shfl_xor(ps, m); pd += __shfl_xor(pd, m); }
    if ((lane & 15) == 0){
        as_[d*4 + (lane >> 4)] = ps;
        ad_[d*4 + (lane >> 4)] = pd;
    }
}

// ---------------- GAT aggregation: max pass + fused, unrolled-x4 pass -------
template<int RELU>
__global__ void gat_agg(const float* __restrict__ h, const float* __restrict__ as_,
                        const float* __restrict__ ad_, const float* __restrict__ bias,
                        const int* __restrict__ rowptr, const int* __restrict__ esrc,
                        float* __restrict__ out){
    int lane = threadIdx.x & 63;
    int w = threadIdx.x >> 6;
    int nb = gridDim.x;
    int b = blockIdx.x;
    int sb = (b & 7)*(nb >> 3) + (b >> 3);
    int d = sb*4 + w;
    int beg = rowptr[d], end = rowptr[d+1];

    float ad4[4], m[4], es[4];
    #pragma unroll
    for (int hh = 0; hh < 4; hh++) ad4[hh] = ad_[(d<<2) + hh];
    #pragma unroll
    for (int hh = 0; hh < 4; hh++){ es[hh] = leaky(as_[(d<<2) + hh] + ad4[hh]); m[hh] = es[hh]; }

    for (int i = beg + lane; i < end; i += 64){
        int s = esrc[i];
        float4 a4 = *(const float4*)(as_ + (s<<2));
        m[0] = fmaxf(m[0], leaky(a4.x + ad4[0]));
        m[1] = fmaxf(m[1], leaky(a4.y + ad4[1]));
        m[2] = fmaxf(m[2], leaky(a4.z + ad4[2]));
        m[3] = fmaxf(m[3], leaky(a4.w + ad4[3]));
    }
    #pragma unroll
    for (int off = 32; off; off >>= 1)
        #pragma unroll
        for (int hh = 0; hh < 4; hh++) m[hh] = fmaxf(m[hh], __shfl_xor(m[hh], off));

    int hh = lane >> 4;
    int c0 = lane*4;
    float mh  = m[hh];
    float adh = ad4[hh];
    float den0 = __expf(es[hh] - mh), den1 = 0.f, den2 = 0.f, den3 = 0.f;
    float4 hd = *(const float4*)(h + (d<<8) + c0);
    float4 A0, A1 = {0,0,0,0}, A2 = {0,0,0,0}, A3 = {0,0,0,0};
    A0.x = den0*hd.x; A0.y = den0*hd.y; A0.z = den0*hd.z; A0.w = den0*hd.w;

    int i = beg;
    int endu = beg + ((end - beg) & ~3);
    for (; i < endu; i += 4){
        int s0 = esrc[i], s1 = esrc[i+1], s2 = esrc[i+2], s3 = esrc[i+3];
        float a0 = as_[(s0<<2) + hh];
        float a1 = as_[(s1<<2) + hh];
        float a2 = as_[(s2<<2) + hh];
        float a3 = as_[(s3<<2) + hh];
        float4 h0 = *(const float4*)(h + (s0<<8) + c0);
        float4 h1 = *(const float4*)(h + (s1<<8) + c0);
        float4 h2 = *(const float4*)(h + (s2<<8) + c0);
        float4 h3 = *(const float4*)(h + (s3<<8) + c0);
        float p0 = __expf(leaky(a0 + adh) - mh);
        float p1 = __expf(leaky(a1 + adh) - mh);
        float p2 = __expf(leaky(a2 + adh) - mh);
        float p3 = __expf(leaky(a3 + adh) - mh);
        den0 += p0; den1 += p1; den2 += p2; den3 += p3;
        A0.x = fmaf(p0,h0.x,A0.x); A0.y = fmaf(p0,h0.y,A0.y); A0.z = fmaf(p0,h0.z,A0.z); A0.w = fmaf(p0,h0.w,A0.w);
        A1.x = fmaf(p1,h1.x,A1.x); A1.y = fmaf(p1,h1.y,A1.y); A1.z = fmaf(p1,h1.z,A1.z); A1.w = fmaf(p1,h1.w,A1.w);
        A2.x = fmaf(p2,h2.x,A2.x); A2.y = fmaf(p2,h2.y,A2.y); A2.z = fmaf(p2,h2.z,A2.z); A2.w = fmaf(p2,h2.w,A2.w);
        A3.x = fmaf(p3,h3.x,A3.x); A3.y = fmaf(p3,h3.y,A3.y); A3.z = fmaf(p3,h3.z,A3.z); A3.w = fmaf(p3,h3.w,A3.w);
    }
    for (; i < end; ++i){
        int s = esrc[i];
        float a = as_[(s<<2) + hh];
        float4 hv = *(const float4*)(h + (s<<8) + c0);
        float p = __expf(leaky(a + adh) - mh);
        den0 += p;
        A0.x = fmaf(p,hv.x,A0.x); A0.y = fmaf(p,hv.y,A0.y); A0.z = fmaf(p,hv.z,A0.z); A0.w = fmaf(p,hv.w,A0.w);
    }
    float den = ((den0 + den1) + (den2 + den3)) + 1e-16f;
    float r = 1.0f / den;
    float4 bv = *(const float4*)(bias + c0);
    float4 acc;
    acc.x = ((A0.x+A1.x)+(A2.x+A3.x))*r + bv.x;
    acc.y = ((A0.y+A1.y)+(A2.y+A3.y))*r + bv.y;
    acc.z = ((A0.z+A1.z)+(A2.z+A3.z))*r + bv.z;
    acc.w = ((A0.w+A1.w)+(A2.w+A3.w))*r + bv.w;
    if (RELU){
        acc.x = fmaxf(acc.x, 0.f); acc.y = fmaxf(acc.y, 0.f);
        acc.z = fmaxf(acc.z, 0.f); acc.w = fmaxf(acc.w, 0.f);
    }
    *(float4*)(out + (d<<8) + c0) = acc;
}

// ---------------- GCN aggregation (unrolled x4) ----------------
__global__ void gcn_agg(const float* __restrict__ h, const float* __restrict__ dinv,
                        const float* __restrict__ bias, const int* __restrict__ rowptr,
                        const int* __restrict__ esrc, float* __restrict__ out){
    int lane = threadIdx.x & 63;
    int w = threadIdx.x >> 6;
    int nb = gridDim.x;
    int b = blockIdx.x;
    int sb = (b & 7)*(nb >> 3) + (b >> 3);
    int d = sb*4 + w;
    int beg = rowptr[d], end = rowptr[d+1];
    float dv = dinv[d];
    int c0 = lane*2;
    float2 hd = *(const float2*)(h + (d<<7) + c0);
    float self = dv*dv;
    float ax0 = self*hd.x, ay0 = self*hd.y;
    float ax1 = 0.f, ay1 = 0.f, ax2 = 0.f, ay2 = 0.f, ax3 = 0.f, ay3 = 0.f;
    int i = beg;
    int endu = beg + ((end - beg) & ~3);
    for (; i < endu; i += 4){
        int s0 = esrc[i], s1 = esrc[i+1], s2 = esrc[i+2], s3 = esrc[i+3];
        float d0 = dinv[s0], d1 = dinv[s1], d2 = dinv[s2], d3 = dinv[s3];
        float2 h0 = *(const float2*)(h + (s0<<7) + c0);
        float2 h1 = *(const float2*)(h + (s1<<7) + c0);
        float2 h2 = *(const float2*)(h + (s2<<7) + c0);
        float2 h3 = *(const float2*)(h + (s3<<7) + c0);
        float c0f = d0*dv, c1f = d1*dv, c2f = d2*dv, c3f = d3*dv;
        ax0 = fmaf(c0f, h0.x, ax0); ay0 = fmaf(c0f, h0.y, ay0);
        ax1 = fmaf(c1f, h1.x, ax1); ay1 = fmaf(c1f, h1.y, ay1);
        ax2 = fmaf(c2f, h2.x, ax2); ay2 = fmaf(c2f, h2.y, ay2);
        ax3 = fmaf(c3f, h3.x, ax3); ay3 = fmaf(c3f, h3.y, ay3);
    }
    for (; i < end; ++i){
        int s = esrc[i];
        float coef = dinv[s]*dv;
        float2 hv = *(const float2*)(h + (s<<7) + c0);
        ax0 = fmaf(coef, hv.x, ax0); ay0 = fmaf(coef, hv.y, ay0);
    }
    float ax = ((ax0+ax1)+(ax2+ax3));
    float ay = ((ay0+ay1)+(ay2+ay3));
    ax = fmaxf(ax + bias[c0], 0.f);
    ay = fmaxf(ay + bias[c0+1], 0.f);
    float2 o; o.x = ax; o.y = ay;
    *(float2*)(out + (d<<7) + c0) = o;
}

// ---------------- SAGPool score (unrolled x4) ----------------
__global__ void sag_score(const float* __restrict__ x, const float* __restrict__ wrel,
                          const float* __restrict__ brel, const float* __restrict__ wroot,
                          const int* __restrict__ rowptr, const int* __restrict__ esrc,
                          float* __restrict__ score){
    int lane = threadIdx.x & 63;
    int w = threadIdx.x >> 6;
    int nb = gridDim.x;
    int b = blockIdx.x;
    int sb = (b & 7)*(nb >> 3) + (b >> 3);
    int d = sb*4 + w;
    int beg = rowptr[d], end = rowptr[d+1];
    int c0 = lane*2;
    float ax0 = 0.f, ay0 = 0.f, ax1 = 0.f, ay1 = 0.f;
    float ax2 = 0.f, ay2 = 0.f, ax3 = 0.f, ay3 = 0.f;
    int i = beg;
    int endu = beg + ((end - beg) & ~3);
    for (; i < endu; i += 4){
        int s0 = esrc[i], s1 = esrc[i+1], s2 = esrc[i+2], s3 = esrc[i+3];
        float2 h0 = *(const float2*)(x + (s0<<7) + c0);
        float2 h1 = *(const float2*)(x + (s1<<7) + c0);
        float2 h2 = *(const float2*)(x + (s2<<7) + c0);
        float2 h3 = *(const float2*)(x + (s3<<7) + c0);
        ax0 += h0.x; ay0 += h0.y;
        ax1 += h1.x; ay1 += h1.y;
        ax2 += h2.x; ay2 += h2.y;
        ax3 += h3.x; ay3 += h3.y;
    }
    for (; i < end; ++i){
        int s = esrc[i];
        float2 hv = *(const float2*)(x + (s<<7) + c0);
        ax0 += hv.x; ay0 += hv.y;
    }
    float aggx = ((ax0+ax1)+(ax2+ax3));
    float aggy = ((ay0+ay1)+(ay2+ay3));
    float2 xd = *(const float2*)(x + (d<<7) + c0);
    float part = aggx*wrel[c0] + aggy*wrel[c0+1] + xd.x*wroot[c0] + xd.y*wroot[c0+1];
    #pragma unroll
    for (int off = 32; off; off >>= 1) part += __shfl_xor(part, off);
    if (lane == 0) score[d] = part + brel[0];
}

// ---------------- radix-select top-k ----------------
__global__ __launch_bounds__(1024) void topk_sel(const float* __restrict__ score,
        int npg, int k, int* __restrict__ perm, float* __restrict__ ssort,
        int* __restrict__ nid, int writeNid){
    __shared__ unsigned keys[2048];
    __shared__ int hist[256];
    __shared__ int cge[256];
    __shared__ int warpsum[16];
    __shared__ int s_bin, s_need;
    int g = blockIdx.x, tid = threadIdx.x;
    for (int i = tid; i < npg; i += 1024){
        unsigned u = __float_as_uint(score[g*npg + i]);
        u = (u & 0x80000000u) ? ~u : (u | 0x80000000u);
        keys[i] = u;
    }
    if (tid == 0) s_need = k;
    __syncthreads();
    unsigned prefix = 0u, pmask = 0u;
    #pragma unroll
    for (int shift = 24; shift >= 0; shift -= 8){
        if (tid < 256) hist[tid] = 0;
        __syncthreads();
        for (int i = tid; i < npg; i += 1024){
            unsigned u = keys[i];
            if ((u & pmask) == prefix) atomicAdd(&hist[(u >> shift) & 255u], 1);
        }
        __syncthreads();
        if (tid < 256) cge[tid] = hist[tid];
        __syncthreads();
        for (int off = 1; off < 256; off <<= 1){
            int v = 0;
            if (tid < 256 - off) v = cge[tid + off];
            __syncthreads();
            if (tid < 256) cge[tid] += v;
            __syncthreads();
        }
        int need = s_need;
        if (tid < 256){
            int above = (tid == 255) ? 0 : cge[tid + 1];
            if (cge[tid] >= need && above < need) s_bin = tid;
        }
        __syncthreads();
        if (tid == 0) s_need = need - ((s_bin == 255) ? 0 : cge[s_bin + 1]);
        __syncthreads();
        prefix |= ((unsigned)s_bin) << shift;
        pmask  |= (255u << shift);
        __syncthreads();
    }
    unsigned thr = prefix;
    int m = s_need;
    int i0 = 2*tid, i1 = 2*tid + 1;
    int f0 = 0, f1 = 0;
    if (i0 < npg){
        unsigned u = keys[i0];
        if (u > thr) f0 = 1;
        else if (u == thr){
            int r = 0;
            for (int j = 0; j < i0; j++) r += (keys[j] == thr);
            f0 = (r < m) ? 1 : 0;
        }
    }
    if (i1 < npg){
        unsigned u = keys[i1];
        if (u > thr) f1 = 1;
        else if (u == thr){
            int r = 0;
            for (int j = 0; j < i1; j++) r += (keys[j] == thr);
            f1 = (r < m) ? 1 : 0;
        }
    }
    int pair = f0 + f1;
    int lane = tid & 63, wv = tid >> 6;
    int x = pair;
    #pragma unroll
    for (int off = 1; off < 64; off <<= 1){ int y = __shfl_up(x, off); if (lane >= off) x += y; }
    if (lane == 63) warpsum[wv] = x;
    __syncthreads();
    if (tid == 0){ int run = 0; for (int w2 = 0; w2 < 16; w2++){ int t = warpsum[w2]; warpsum[w2] = run; run += t; } }
    __syncthreads();
    int excl = x - pair + warpsum[wv];
    if (f0){
        int pos = excl;
        int node = g*npg + i0;
        perm[g*k + pos] = node;
        ssort[g*k + pos] = score[node];
        if (writeNid) nid[node] = g*k + pos;
    }
    if (f1){
        int pos = excl + f0;
        int node = g*npg + i1;
        perm[g*k + pos] = node;
        ssort[g*k + pos] = score[node];
        if (writeNid) nid[node] = g*k + pos;
    }
}

__global__ void pool_gather(const float* __restrict__ x, const int* __restrict__ perm,
                            const float* __restrict__ ssort, float* __restrict__ xn){
    int j = blockIdx.x; int c = threadIdx.x;
    int o = perm[j];
    float t = tanhf(ssort[j]);
    xn[(size_t)j*128 + c] = x[(size_t)o*128 + c] * t;
}

__global__ void pool_mean2(const float* __restrict__ x, const int* __restrict__ perm,
                           const float* __restrict__ ssort, float* __restrict__ g){
    __shared__ float tt[KK2];
    __shared__ float part[128];
    int b = blockIdx.x, t = threadIdx.x;     // 256 threads
    tt[t]       = tanhf(ssort[b*KK2 + t]);
    tt[t + 256] = tanhf(ssort[b*KK2 + t + 256]);
    __syncthreads();
    int c = t & 127, half = t >> 7;
    float s = 0.f;
    #pragma unroll 4
    for (int i = half*256; i < half*256 + 256; i++){
        int o = perm[b*KK2 + i];
        s = fmaf(tt[i], x[(size_t)o*128 + c], s);
    }
    if (half) part[c] = s;
    __syncthreads();
    if (!half) g[b*128 + c] = (s + part[c]) * (1.0f/KK2);
}

__global__ void mlp_k(const float* __restrict__ g,
                      const float* __restrict__ fc1w, const float* __restrict__ fc1b,
                      const float* __restrict__ fc2w, const float* __restrict__ fc2b,
                      const float* __restrict__ ow,  const float* __restrict__ ob,
                      float* __restrict__ out){
    __shared__ float gv[128], t1[256], t2[128];
    int b = blockIdx.x, t = threadIdx.x;
    if (t < 128) gv[t] = g[b*128 + t];
    __syncthreads();
    {
        float s = fc1b[t];
        for (int c = 0; c < 128; c++) s += gv[c]*fc1w[t*128 + c];
        t1[t] = fmaxf(s, 0.f);
    }
    __syncthreads();
    if (t < 128){
        float s = fc2b[t];
        for (int c = 0; c < 256; c++) s += t1[c]*fc2w[t*256 + c];
        t2[t] = fmaxf(s, 0.f);
    }
    __syncthreads();
    if (t < 10){
        float s = ob[t];
        for (int c = 0; c < 128; c++) s += t2[c]*ow[t*128 + c];
        out[b*10 + t] = s;
    }
}

// ---------------- launch ----------------
extern "C" void kernel_launch(void* const* d_in, const int* in_sizes, int n_in,
                              void* d_out, int out_size, void* d_ws, size_t ws_size,
                              hipStream_t stream){
    (void)in_sizes; (void)n_in; (void)out_size; (void)ws_size;
    const float* x    = (const float*)d_in[0];
    const int*   eidx = (const int*)d_in[1];
    const int*   src  = eidx;
    const int*   dst  = eidx + EE;
    const float* g1w  = (const float*)d_in[3];
    const float* g1as = (const float*)d_in[4];
    const float* g1ad = (const float*)d_in[5];
    const float* g1b  = (const float*)d_in[6];
    const float* g2w  = (const float*)d_in[7];
    const float* g2as = (const float*)d_in[8];
    const float* g2ad = (const float*)d_in[9];
    const float* g2b  = (const float*)d_in[10];
    const float* c1w  = (const float*)d_in[11];
    const float* c1b  = (const float*)d_in[12];
    const float* s1wrel  = (const float*)d_in[13];
    const float* s1brel  = (const float*)d_in[14];
    const float* s1wroot = (const float*)d_in[15];
    const float* c2w  = (const float*)d_in[16];
    const float* c2b  = (const float*)d_in[17];
    const float* s2wrel  = (const float*)d_in[18];
    const float* s2brel  = (const float*)d_in[19];
    const float* s2wroot = (const float*)d_in[20];
    const float* f1w  = (const float*)d_in[21];
    const float* f1b  = (const float*)d_in[22];
    const float* f2w  = (const float*)d_in[23];
    const float* f2b  = (const float*)d_in[24];
    const float* ow   = (const float*)d_in[25];
    const float* ob   = (const float*)d_in[26];
    float* out = (float*)d_out;

    char* ws = (char*)d_ws;
    size_t off = 0;
    auto alloc = [&](size_t bytes)->char*{
        char* p = ws + off;
        off += (bytes + 255) & ~(size_t)255;
        return p;
    };
    float* F0     = (float*)alloc((size_t)N1*256*4);
    float* F1     = (float*)alloc((size_t)N1*256*4);
    float* F2     = (float*)alloc((size_t)N2*128*4);
    float* AS     = (float*)alloc((size_t)N1*4*4);
    float* AD     = (float*)alloc((size_t)N1*4*4);
    int*   RP     = (int*)  alloc((size_t)(N1+1)*4);
    int*   CUR    = (int*)  alloc((size_t)N1*4);
    int*   EL     = (int*)  alloc((size_t)EE*4);
    float* DINV   = (float*)alloc((size_t)N1*4);
    float* SCORE  = (float*)alloc((size_t)N1*4);
    int*   PERM1  = (int*)  alloc((size_t)N2*4);
    float* SSORT1 = (float*)alloc((size_t)N2*4);
    int*   NID    = (int*)  alloc((size_t)N1*4);
    int*   E1S    = (int*)  alloc((size_t)EE*4);
    int*   E1D    = (int*)  alloc((size_t)EE*4);
    int*   RP2    = (int*)  alloc((size_t)(N2+1)*4);
    int*   CUR2   = (int*)  alloc((size_t)N2*4);
    int*   EL2    = (int*)  alloc((size_t)EE*4);
    float* DINV2  = (float*)alloc((size_t)N2*4);
    int*   PERM2  = (int*)  alloc((size_t)N3*4);
    float* SSORT2 = (float*)alloc((size_t)N3*4);
    float* GBUF   = (float*)alloc((size_t)NB*128*4);
    int*   BS     = (int*)  alloc((size_t)128*4);

    // ---- level-1 CSR (by dst; bucket entries = src node ids) ----
    hipMemsetAsync(CUR, 0, (size_t)N1*4, stream);
    count_dst<<<EE/256, 256, 0, stream>>>(dst, CUR, EE);
    blocksum_k<<<N1/256, 256, 0, stream>>>(CUR, BS);
    scan_write_k<<<N1/256, 256, 0, stream>>>(CUR, BS, N1/256, RP, CUR, DINV, N1);
    scatter1<<<EE/256, 256, 0, stream>>>(src, dst, CUR, EL, EE);

    // ---- GAT layer 1 (64 -> 4x64, relu) ----
    gemm_h2<<<dim3(N1/128, 2), 256, 0, stream>>>(x, g1w, F0, N1, 64, 256);
    attn_pre<<<N1/4, 256, 0, stream>>>(F0, g1as, g1ad, AS, AD);
    gat_agg<1><<<N1/4, 256, 0, stream>>>(F0, AS, AD, g1b, RP, EL, F1);

    // ---- GAT layer 2 (256 -> 4x64) ----
    gemm_h2<<<dim3(N1/128, 2), 256, 0, stream>>>(F1, g2w, F0, N1, 256, 256);
    attn_pre<<<N1/4, 256, 0, stream>>>(F0, g2as, g2ad, AS, AD);
    gat_agg<0><<<N1/4, 256, 0, stream>>>(F0, AS, AD, g2b, RP, EL, F1);

    // ---- GCN1 (256 -> 128, relu) ----
    gemm_h2<<<dim3(N1/128, 1), 256, 0, stream>>>(F1, c1w, F0, N1, 256, 128);
    gcn_agg<<<N1/4, 256, 0, stream>>>(F0, DINV, c1b, RP, EL, F1);

    // ---- SAGPool1 ----
    sag_score<<<N1/4, 256, 0, stream>>>(F1, s1wrel, s1brel, s1wroot, RP, EL, SCORE);
    hipMemsetAsync(NID, 0xFF, (size_t)N1*4, stream);   // -1
    topk_sel<<<NB, 1024, 0, stream>>>(SCORE, NPG1, KK1, PERM1, SSORT1, NID, 1);
    pool_gather<<<N2, 128, 0, stream>>>(F1, PERM1, SSORT1, F0);          // x2 -> F0

    // ---- level-2 CSR (remap + count fused) ----
    hipMemsetAsync(CUR2, 0, (size_t)N2*4, stream);
    remap_count<<<EE/256, 256, 0, stream>>>(src, dst, NID, E1S, E1D, CUR2, EE);
    blocksum_k<<<N2/256, 256, 0, stream>>>(CUR2, BS);
    scan_write_k<<<N2/256, 256, 0, stream>>>(CUR2, BS, N2/256, RP2, CUR2, DINV2, N2);
    scatter2<<<EE/256, 256, 0, stream>>>(E1S, E1D, CUR2, EL2, EE);

    // ---- GCN2 (128 -> 128, relu) ----
    gemm_h2<<<dim3(N2/128, 1), 256, 0, stream>>>(F0, c2w, F1, N2, 128, 128);
    gcn_agg<<<N2/4, 256, 0, stream>>>(F1, DINV2, c2b, RP2, EL2, F2);

    // ---- SAGPool2 ----
    sag_score<<<N2/4, 256, 0, stream>>>(F2, s2wrel, s2brel, s2wroot, RP2, EL2, SCORE);
    topk_sel<<<NB, 1024, 0, stream>>>(SCORE, NPG2, KK2, PERM2, SSORT2, nullptr, 0);

    // ---- fused gather + mean pool + MLP ----
    pool_mean2<<<NB, 256, 0, stream>>>(F2, PERM2, SSORT2, GBUF);
    mlp_k<<<NB, 256, 0, stream>>>(GBUF, f1w, f1b, f2w, f2b, ow, ob, out);
}

// Round 7
// 401.580 us; speedup vs baseline: 1.9046x; 1.0060x over previous
//
#include <hip/hip_runtime.h>

#define N1 32768
#define EE 524288
#define NB 16
#define NPG1 2048
#define KK1 1024
#define N2 16384
#define NPG2 1024
#define KK2 512
#define N3 8192

typedef _Float16 half8_t __attribute__((ext_vector_type(8)));
typedef float floatx16 __attribute__((ext_vector_type(16)));

static __device__ __forceinline__ float leaky(float x){ return fmaxf(x, 0.2f*x); }

// ---------------- CSR build ----------------
__global__ void count_dst(const int* __restrict__ dst, int* __restrict__ cnt, int E){
    int i = blockIdx.x*blockDim.x + threadIdx.x;
    if (i < E) atomicAdd(&cnt[dst[i]], 1);
}

__global__ void remap_count(const int* __restrict__ src, const int* __restrict__ dst,
                            const int* __restrict__ nid, int* __restrict__ ns,
                            int* __restrict__ nd, int* __restrict__ cnt, int E){
    int i = blockIdx.x*blockDim.x + threadIdx.x;
    if (i < E){
        int a = nid[src[i]], b = nid[dst[i]];
        ns[i] = a; nd[i] = b;
        if (a >= 0 && b >= 0) atomicAdd(&cnt[b], 1);
    }
}

__global__ void blocksum_k(const int* __restrict__ cnt, int* __restrict__ bs){
    __shared__ int red[4];
    int tid = threadIdx.x;
    int v = cnt[blockIdx.x*256 + tid];
    #pragma unroll
    for (int off = 32; off; off >>= 1) v += __shfl_xor(v, off);
    if ((tid & 63) == 0) red[tid >> 6] = v;
    __syncthreads();
    if (tid == 0) bs[blockIdx.x] = red[0] + red[1] + red[2] + red[3];
}

__global__ void scan_write_k(const int* __restrict__ cnt, const int* __restrict__ bs,
                             int nb, int* __restrict__ rowptr, int* __restrict__ cur,
                             float* __restrict__ dinv, int n){
    __shared__ int sbs[128];
    __shared__ int wsum[4];
    int tid = threadIdx.x;
    int b = blockIdx.x;
    if (tid < nb) sbs[tid] = bs[tid];
    __syncthreads();
    for (int off = 1; off < nb; off <<= 1){
        int v = 0;
        if (tid < nb && tid >= off) v = sbs[tid - off];
        __syncthreads();
        if (tid < nb) sbs[tid] += v;
        __syncthreads();
    }
    int base = (b == 0) ? 0 : sbs[b-1];
    int i = b*256 + tid;
    int c = cnt[i];
    int lane = tid & 63, wv = tid >> 6;
    int x = c;
    #pragma unroll
    for (int off = 1; off < 64; off <<= 1){ int y = __shfl_up(x, off); if (lane >= off) x += y; }
    if (lane == 63) wsum[wv] = x;
    __syncthreads();
    if (tid == 0){ int run = 0; for (int w2 = 0; w2 < 4; w2++){ int t = wsum[w2]; wsum[w2] = run; run += t; } }
    __syncthreads();
    int excl = x - c + wsum[wv];
    rowptr[i] = base + excl;
    cur[i]    = base + excl;
    dinv[i]   = rsqrtf((float)c + 1.0f);
    if (i == n-1) rowptr[n] = base + excl + c;
}

__global__ void scatter1(const int* __restrict__ src, const int* __restrict__ dst,
                         int* __restrict__ cur, int* __restrict__ esrc, int E){
    int i = blockIdx.x*blockDim.x + threadIdx.x;
    if (i < E){ int p = atomicAdd(&cur[dst[i]], 1); esrc[p] = src[i]; }
}

__global__ void scatter2(const int* __restrict__ ns, const int* __restrict__ nd,
                         int* __restrict__ cur, int* __restrict__ esrc, int E){
    int i = blockIdx.x*blockDim.x + threadIdx.x;
    if (i < E){
        int a = ns[i], b = nd[i];
        if (a >= 0 && b >= 0){ int p = atomicAdd(&cur[b], 1); esrc[p] = a; }
    }
}

// ------------- split-fp16 MFMA GEMM: C = A @ W^T (fp32 I/O) ----------------
#define KS 64
static __device__ __forceinline__ int ldsoff(int row, int k8){
    return row*64 + ((k8 ^ (row & 7)) << 3);
}

__global__ __launch_bounds__(256, 2) void gemm_h2(const float* __restrict__ A,
        const float* __restrict__ W, float* __restrict__ C, int n, int K, int M){
    __shared__ _Float16 sm[4*128*KS];
    _Float16* sAH = sm;
    _Float16* sAL = sm + 128*KS;
    _Float16* sWH = sm + 2*128*KS;
    _Float16* sWL = sm + 3*128*KS;
    int t = threadIdx.x;
    int lane = t & 63;
    int wid = t >> 6;
    int wr = wid >> 1, wc = wid & 1;
    int row0 = blockIdx.x*128, col0 = blockIdx.y*128;
    int srow = t >> 3;
    int sk8  = t & 7;

    floatx16 acc[2][2];
    #pragma unroll
    for (int i = 0; i < 2; i++)
        #pragma unroll
        for (int j = 0; j < 2; j++)
            #pragma unroll
            for (int q = 0; q < 16; q++) acc[i][j][q] = 0.f;

    for (int kk = 0; kk < K; kk += KS){
        #pragma unroll
        for (int p = 0; p < 4; p++){
            int r = srow + p*32;
            const float* ga = A + (size_t)(row0 + r)*K + kk + sk8*8;
            const float* gw = W + (size_t)(col0 + r)*K + kk + sk8*8;
            float4 a0 = *(const float4*)ga;
            float4 a1 = *(const float4*)(ga + 4);
            float4 w0 = *(const float4*)gw;
            float4 w1 = *(const float4*)(gw + 4);
            half8_t ahi, alo, whi, wlo;
            float av[8] = {a0.x,a0.y,a0.z,a0.w,a1.x,a1.y,a1.z,a1.w};
            float wv[8] = {w0.x,w0.y,w0.z,w0.w,w1.x,w1.y,w1.z,w1.w};
            #pragma unroll
            for (int q = 0; q < 8; q++){
                _Float16 h = (_Float16)av[q];
                ahi[q] = h; alo[q] = (_Float16)(av[q] - (float)h);
                _Float16 g = (_Float16)wv[q];
                whi[q] = g; wlo[q] = (_Float16)(wv[q] - (float)g);
            }
            int o = ldsoff(r, sk8);
            *(half8_t*)&sAH[o] = ahi;
            *(half8_t*)&sAL[o] = alo;
            *(half8_t*)&sWH[o] = whi;
            *(half8_t*)&sWL[o] = wlo;
        }
        __syncthreads();
        #pragma unroll
        for (int kc = 0; kc < 4; kc++){
            int k8 = kc*2 + (lane >> 5);
            int ra = wr*64 + (lane & 31);
            int rb = wc*64 + (lane & 31);
            half8_t ah0 = *(const half8_t*)&sAH[ldsoff(ra,      k8)];
            half8_t ah1 = *(const half8_t*)&sAH[ldsoff(ra + 32, k8)];
            half8_t al0 = *(const half8_t*)&sAL[ldsoff(ra,      k8)];
            half8_t al1 = *(const half8_t*)&sAL[ldsoff(ra + 32, k8)];
            half8_t bh0 = *(const half8_t*)&sWH[ldsoff(rb,      k8)];
            half8_t bh1 = *(const half8_t*)&sWH[ldsoff(rb + 32, k8)];
            half8_t bl0 = *(const half8_t*)&sWL[ldsoff(rb,      k8)];
            half8_t bl1 = *(const half8_t*)&sWL[ldsoff(rb + 32, k8)];
            acc[0][0] = __builtin_amdgcn_mfma_f32_32x32x16_f16(ah0, bh0, acc[0][0], 0,0,0);
            acc[0][0] = __builtin_amdgcn_mfma_f32_32x32x16_f16(ah0, bl0, acc[0][0], 0,0,0);
            acc[0][0] = __builtin_amdgcn_mfma_f32_32x32x16_f16(al0, bh0, acc[0][0], 0,0,0);
            acc[0][1] = __builtin_amdgcn_mfma_f32_32x32x16_f16(ah0, bh1, acc[0][1], 0,0,0);
            acc[0][1] = __builtin_amdgcn_mfma_f32_32x32x16_f16(ah0, bl1, acc[0][1], 0,0,0);
            acc[0][1] = __builtin_amdgcn_mfma_f32_32x32x16_f16(al0, bh1, acc[0][1], 0,0,0);
            acc[1][0] = __builtin_amdgcn_mfma_f32_32x32x16_f16(ah1, bh0, acc[1][0], 0,0,0);
            acc[1][0] = __builtin_amdgcn_mfma_f32_32x32x16_f16(ah1, bl0, acc[1][0], 0,0,0);
            acc[1][0] = __builtin_amdgcn_mfma_f32_32x32x16_f16(al1, bh0, acc[1][0], 0,0,0);
            acc[1][1] = __builtin_amdgcn_mfma_f32_32x32x16_f16(ah1, bh1, acc[1][1], 0,0,0);
            acc[1][1] = __builtin_amdgcn_mfma_f32_32x32x16_f16(ah1, bl1, acc[1][1], 0,0,0);
            acc[1][1] = __builtin_amdgcn_mfma_f32_32x32x16_f16(al1, bh1, acc[1][1], 0,0,0);
        }
        __syncthreads();
    }
    #pragma unroll
    for (int rt = 0; rt < 2; rt++)
        #pragma unroll
        for (int ct = 0; ct < 2; ct++){
            int baser = row0 + wr*64 + rt*32 + 4*(lane >> 5);
            int c = col0 + wc*64 + ct*32 + (lane & 31);
            #pragma unroll
            for (int r = 0; r < 16; r++){
                int rr = baser + (r & 3) + 8*(r >> 2);
                C[(size_t)rr*M + c] = acc[rt][ct][r];
            }
        }
}

// ---------------- GAT attention coefficients ----------------
__global__ void attn_pre(const float* __restrict__ h, const float* __restrict__ wsrc,
                         const float* __restrict__ wdst, float* __restrict__ as_,
                         float* __restrict__ ad_){
    int lane = threadIdx.x & 63;
    int w = threadIdx.x >> 6;
    int d = blockIdx.x*4 + w;
    float4 hv = *(const float4*)(h + (size_t)d*256 + lane*4);
    float4 ws = *(const float4*)(wsrc + lane*4);
    float4 wd = *(const float4*)(wdst + lane*4);
    float ps = hv.x*ws.x + hv.y*ws.y + hv.z*ws.z + hv.w*ws.w;
    float pd = hv.x*wd.x + hv.y*wd.y + hv.z*wd.z + hv.w*wd.w;
    #pragma unroll
    for (int m = 8; m; m >>= 1){ ps += __shfl_xor(ps, m); pd += __shfl_xor(pd, m); }
    if ((lane & 15) == 0){
        as_[d*4 + (lane >> 4)] = ps;
        ad_[d*4 + (lane >> 4)] = pd;
    }
}

// ---- GAT aggregation: no-max softmax (shift-invariant), 8-wide pipeline ----
// exp(e)/Σexp(e) == exp(e-m)/Σexp(e-m); |e| is O(30) here so fp32 exp is safe.
template<int RELU>
__global__ void gat_agg(const float* __restrict__ h, const float* __restrict__ as_,
                        const float* __restrict__ ad_, const float* __restrict__ bias,
                        const int* __restrict__ rowptr, const int* __restrict__ esrc,
                        float* __restrict__ out){
    int lane = threadIdx.x & 63;
    int w = threadIdx.x >> 6;
    int nb = gridDim.x;
    int b = blockIdx.x;
    int sb = (b & 7)*(nb >> 3) + (b >> 3);
    int d = sb*4 + w;
    int beg = rowptr[d], end = rowptr[d+1];

    int hh = lane >> 4;
    int c0 = lane*4;
    float adh = ad_[(d<<2) + hh];
    float aself = as_[(d<<2) + hh];

    float dn[4];
    dn[0] = __expf(leaky(aself + adh)); dn[1] = 0.f; dn[2] = 0.f; dn[3] = 0.f;
    float4 hd = *(const float4*)(h + (d<<8) + c0);
    float4 AX[4];
    AX[0].x = dn[0]*hd.x; AX[0].y = dn[0]*hd.y; AX[0].z = dn[0]*hd.z; AX[0].w = dn[0]*hd.w;
    AX[1] = {0,0,0,0}; AX[2] = {0,0,0,0}; AX[3] = {0,0,0,0};

    int i = beg;
    int endu = beg + ((end - beg) & ~7);
    for (; i < endu; i += 8){
        int s_[8];
        #pragma unroll
        for (int j = 0; j < 8; j++) s_[j] = esrc[i + j];
        float a_[8];
        #pragma unroll
        for (int j = 0; j < 8; j++) a_[j] = as_[(s_[j]<<2) + hh];
        float4 hv_[8];
        #pragma unroll
        for (int j = 0; j < 8; j++) hv_[j] = *(const float4*)(h + (s_[j]<<8) + c0);
        #pragma unroll
        for (int j = 0; j < 8; j++){
            float x = a_[j] + adh;
            float p = __expf(fmaxf(x, 0.2f*x));
            dn[j & 3] += p;
            AX[j & 3].x = fmaf(p, hv_[j].x, AX[j & 3].x);
            AX[j & 3].y = fmaf(p, hv_[j].y, AX[j & 3].y);
            AX[j & 3].z = fmaf(p, hv_[j].z, AX[j & 3].z);
            AX[j & 3].w = fmaf(p, hv_[j].w, AX[j & 3].w);
        }
    }
    for (; i < end; ++i){
        int s = esrc[i];
        float x = as_[(s<<2) + hh] + adh;
        float4 hv = *(const float4*)(h + (s<<8) + c0);
        float p = __expf(fmaxf(x, 0.2f*x));
        dn[0] += p;
        AX[0].x = fmaf(p, hv.x, AX[0].x); AX[0].y = fmaf(p, hv.y, AX[0].y);
        AX[0].z = fmaf(p, hv.z, AX[0].z); AX[0].w = fmaf(p, hv.w, AX[0].w);
    }
    float den = ((dn[0] + dn[1]) + (dn[2] + dn[3])) + 1e-16f;
    float r = 1.0f / den;
    float4 bv = *(const float4*)(bias + c0);
    float4 acc;
    acc.x = ((AX[0].x+AX[1].x)+(AX[2].x+AX[3].x))*r + bv.x;
    acc.y = ((AX[0].y+AX[1].y)+(AX[2].y+AX[3].y))*r + bv.y;
    acc.z = ((AX[0].z+AX[1].z)+(AX[2].z+AX[3].z))*r + bv.z;
    acc.w = ((AX[0].w+AX[1].w)+(AX[2].w+AX[3].w))*r + bv.w;
    if (RELU){
        acc.x = fmaxf(acc.x, 0.f); acc.y = fmaxf(acc.y, 0.f);
        acc.z = fmaxf(acc.z, 0.f); acc.w = fmaxf(acc.w, 0.f);
    }
    *(float4*)(out + (d<<8) + c0) = acc;
}

// ---------------- GCN aggregation (8-wide pipeline) ----------------
__global__ void gcn_agg(const float* __restrict__ h, const float* __restrict__ dinv,
                        const float* __restrict__ bias, const int* __restrict__ rowptr,
                        const int* __restrict__ esrc, float* __restrict__ out){
    int lane = threadIdx.x & 63;
    int w = threadIdx.x >> 6;
    int nb = gridDim.x;
    int b = blockIdx.x;
    int sb = (b & 7)*(nb >> 3) + (b >> 3);
    int d = sb*4 + w;
    int beg = rowptr[d], end = rowptr[d+1];
    float dv = dinv[d];
    int c0 = lane*2;
    float2 hd = *(const float2*)(h + (d<<7) + c0);
    float self = dv*dv;
    float ax[4] = {self*hd.x, 0.f, 0.f, 0.f};
    float ay[4] = {self*hd.y, 0.f, 0.f, 0.f};
    int i = beg;
    int endu = beg + ((end - beg) & ~7);
    for (; i < endu; i += 8){
        int s_[8];
        #pragma unroll
        for (int j = 0; j < 8; j++) s_[j] = esrc[i + j];
        float di_[8];
        #pragma unroll
        for (int j = 0; j < 8; j++) di_[j] = dinv[s_[j]];
        float2 hv_[8];
        #pragma unroll
        for (int j = 0; j < 8; j++) hv_[j] = *(const float2*)(h + (s_[j]<<7) + c0);
        #pragma unroll
        for (int j = 0; j < 8; j++){
            float coef = di_[j]*dv;
            ax[j & 3] = fmaf(coef, hv_[j].x, ax[j & 3]);
            ay[j & 3] = fmaf(coef, hv_[j].y, ay[j & 3]);
        }
    }
    for (; i < end; ++i){
        int s = esrc[i];
        float coef = dinv[s]*dv;
        float2 hv = *(const float2*)(h + (s<<7) + c0);
        ax[0] = fmaf(coef, hv.x, ax[0]); ay[0] = fmaf(coef, hv.y, ay[0]);
    }
    float axs = ((ax[0]+ax[1])+(ax[2]+ax[3]));
    float ays = ((ay[0]+ay[1])+(ay[2]+ay[3]));
    axs = fmaxf(axs + bias[c0], 0.f);
    ays = fmaxf(ays + bias[c0+1], 0.f);
    float2 o; o.x = axs; o.y = ays;
    *(float2*)(out + (d<<7) + c0) = o;
}

// ---------------- SAGPool score (8-wide pipeline) ----------------
__global__ void sag_score(const float* __restrict__ x, const float* __restrict__ wrel,
                          const float* __restrict__ brel, const float* __restrict__ wroot,
                          const int* __restrict__ rowptr, const int* __restrict__ esrc,
                          float* __restrict__ score){
    int lane = threadIdx.x & 63;
    int w = threadIdx.x >> 6;
    int nb = gridDim.x;
    int b = blockIdx.x;
    int sb = (b & 7)*(nb >> 3) + (b >> 3);
    int d = sb*4 + w;
    int beg = rowptr[d], end = rowptr[d+1];
    int c0 = lane*2;
    float ax[4] = {0.f,0.f,0.f,0.f};
    float ay[4] = {0.f,0.f,0.f,0.f};
    int i = beg;
    int endu = beg + ((end - beg) & ~7);
    for (; i < endu; i += 8){
        int s_[8];
        #pragma unroll
        for (int j = 0; j < 8; j++) s_[j] = esrc[i + j];
        float2 hv_[8];
        #pragma unroll
        for (int j = 0; j < 8; j++) hv_[j] = *(const float2*)(x + (s_[j]<<7) + c0);
        #pragma unroll
        for (int j = 0; j < 8; j++){
            ax[j & 3] += hv_[j].x;
            ay[j & 3] += hv_[j].y;
        }
    }
    for (; i < end; ++i){
        int s = esrc[i];
        float2 hv = *(const float2*)(x + (s<<7) + c0);
        ax[0] += hv.x; ay[0] += hv.y;
    }
    float aggx = ((ax[0]+ax[1])+(ax[2]+ax[3]));
    float aggy = ((ay[0]+ay[1])+(ay[2]+ay[3]));
    float2 xd = *(const float2*)(x + (d<<7) + c0);
    float part = aggx*wrel[c0] + aggy*wrel[c0+1] + xd.x*wroot[c0] + xd.y*wroot[c0+1];
    #pragma unroll
    for (int off = 32; off; off >>= 1) part += __shfl_xor(part, off);
    if (lane == 0) score[d] = part + brel[0];
}

// ---------------- radix-select top-k ----------------
__global__ __launch_bounds__(1024) void topk_sel(const float* __restrict__ score,
        int npg, int k, int* __restrict__ perm, float* __restrict__ ssort,
        int* __restrict__ nid, int writeNid){
    __shared__ unsigned keys[2048];
    __shared__ int hist[256];
    __shared__ int cge[256];
    __shared__ int warpsum[16];
    __shared__ int s_bin, s_need;
    int g = blockIdx.x, tid = threadIdx.x;
    for (int i = tid; i < npg; i += 1024){
        unsigned u = __float_as_uint(score[g*npg + i]);
        u = (u & 0x80000000u) ? ~u : (u | 0x80000000u);
        keys[i] = u;
    }
    if (tid == 0) s_need = k;
    __syncthreads();
    unsigned prefix = 0u, pmask = 0u;
    #pragma unroll
    for (int shift = 24; shift >= 0; shift -= 8){
        if (tid < 256) hist[tid] = 0;
        __syncthreads();
        for (int i = tid; i < npg; i += 1024){
            unsigned u = keys[i];
            if ((u & pmask) == prefix) atomicAdd(&hist[(u >> shift) & 255u], 1);
        }
        __syncthreads();
        if (tid < 256) cge[tid] = hist[tid];
        __syncthreads();
        for (int off = 1; off < 256; off <<= 1){
            int v = 0;
            if (tid < 256 - off) v = cge[tid + off];
            __syncthreads();
            if (tid < 256) cge[tid] += v;
            __syncthreads();
        }
        int need = s_need;
        if (tid < 256){
            int above = (tid == 255) ? 0 : cge[tid + 1];
            if (cge[tid] >= need && above < need) s_bin = tid;
        }
        __syncthreads();
        if (tid == 0) s_need = need - ((s_bin == 255) ? 0 : cge[s_bin + 1]);
        __syncthreads();
        prefix |= ((unsigned)s_bin) << shift;
        pmask  |= (255u << shift);
        __syncthreads();
    }
    unsigned thr = prefix;
    int m = s_need;
    int i0 = 2*tid, i1 = 2*tid + 1;
    int f0 = 0, f1 = 0;
    if (i0 < npg){
        unsigned u = keys[i0];
        if (u > thr) f0 = 1;
        else if (u == thr){
            int r = 0;
            for (int j = 0; j < i0; j++) r += (keys[j] == thr);
            f0 = (r < m) ? 1 : 0;
        }
    }
    if (i1 < npg){
        unsigned u = keys[i1];
        if (u > thr) f1 = 1;
        else if (u == thr){
            int r = 0;
            for (int j = 0; j < i1; j++) r += (keys[j] == thr);
            f1 = (r < m) ? 1 : 0;
        }
    }
    int pair = f0 + f1;
    int lane = tid & 63, wv = tid >> 6;
    int x = pair;
    #pragma unroll
    for (int off = 1; off < 64; off <<= 1){ int y = __shfl_up(x, off); if (lane >= off) x += y; }
    if (lane == 63) warpsum[wv] = x;
    __syncthreads();
    if (tid == 0){ int run = 0; for (int w2 = 0; w2 < 16; w2++){ int t = warpsum[w2]; warpsum[w2] = run; run += t; } }
    __syncthreads();
    int excl = x - pair + warpsum[wv];
    if (f0){
        int pos = excl;
        int node = g*npg + i0;
        perm[g*k + pos] = node;
        ssort[g*k + pos] = score[node];
        if (writeNid) nid[node] = g*k + pos;
    }
    if (f1){
        int pos = excl + f0;
        int node = g*npg + i1;
        perm[g*k + pos] = node;
        ssort[g*k + pos] = score[node];
        if (writeNid) nid[node] = g*k + pos;
    }
}

__global__ void pool_gather(const float* __restrict__ x, const int* __restrict__ perm,
                            const float* __restrict__ ssort, float* __restrict__ xn){
    int j = blockIdx.x; int c = threadIdx.x;
    int o = perm[j];
    float t = tanhf(ssort[j]);
    xn[(size_t)j*128 + c] = x[(size_t)o*128 + c] * t;
}

__global__ void pool_mean2(const float* __restrict__ x, const int* __restrict__ perm,
                           const float* __restrict__ ssort, float* __restrict__ g){
    __shared__ float tt[KK2];
    __shared__ float part[128];
    int b = blockIdx.x, t = threadIdx.x;     // 256 threads
    tt[t]       = tanhf(ssort[b*KK2 + t]);
    tt[t + 256] = tanhf(ssort[b*KK2 + t + 256]);
    __syncthreads();
    int c = t & 127, half = t >> 7;
    float s = 0.f;
    #pragma unroll 4
    for (int i = half*256; i < half*256 + 256; i++){
        int o = perm[b*KK2 + i];
        s = fmaf(tt[i], x[(size_t)o*128 + c], s);
    }
    if (half) part[c] = s;
    __syncthreads();
    if (!half) g[b*128 + c] = (s + part[c]) * (1.0f/KK2);
}

__global__ void mlp_k(const float* __restrict__ g,
                      const float* __restrict__ fc1w, const float* __restrict__ fc1b,
                      const float* __restrict__ fc2w, const float* __restrict__ fc2b,
                      const float* __restrict__ ow,  const float* __restrict__ ob,
                      float* __restrict__ out){
    __shared__ float gv[128], t1[256], t2[128];
    int b = blockIdx.x, t = threadIdx.x;
    if (t < 128) gv[t] = g[b*128 + t];
    __syncthreads();
    {
        float s = fc1b[t];
        for (int c = 0; c < 128; c++) s += gv[c]*fc1w[t*128 + c];
        t1[t] = fmaxf(s, 0.f);
    }
    __syncthreads();
    if (t < 128){
        float s = fc2b[t];
        for (int c = 0; c < 256; c++) s += t1[c]*fc2w[t*256 + c];
        t2[t] = fmaxf(s, 0.f);
    }
    __syncthreads();
    if (t < 10){
        float s = ob[t];
        for (int c = 0; c < 128; c++) s += t2[c]*ow[t*128 + c];
        out[b*10 + t] = s;
    }
}

// ---------------- launch ----------------
extern "C" void kernel_launch(void* const* d_in, const int* in_sizes, int n_in,
                              void* d_out, int out_size, void* d_ws, size_t ws_size,
                              hipStream_t stream){
    (void)in_sizes; (void)n_in; (void)out_size; (void)ws_size;
    const float* x    = (const float*)d_in[0];
    const int*   eidx = (const int*)d_in[1];
    const int*   src  = eidx;
    const int*   dst  = eidx + EE;
    const float* g1w  = (const float*)d_in[3];
    const float* g1as = (const float*)d_in[4];
    const float* g1ad = (const float*)d_in[5];
    const float* g1b  = (const float*)d_in[6];
    const float* g2w  = (const float*)d_in[7];
    const float* g2as = (const float*)d_in[8];
    const float* g2ad = (const float*)d_in[9];
    const float* g2b  = (const float*)d_in[10];
    const float* c1w  = (const float*)d_in[11];
    const float* c1b  = (const float*)d_in[12];
    const float* s1wrel  = (const float*)d_in[13];
    const float* s1brel  = (const float*)d_in[14];
    const float* s1wroot = (const float*)d_in[15];
    const float* c2w  = (const float*)d_in[16];
    const float* c2b  = (const float*)d_in[17];
    const float* s2wrel  = (const float*)d_in[18];
    const float* s2brel  = (const float*)d_in[19];
    const float* s2wroot = (const float*)d_in[20];
    const float* f1w  = (const float*)d_in[21];
    const float* f1b  = (const float*)d_in[22];
    const float* f2w  = (const float*)d_in[23];
    const float* f2b  = (const float*)d_in[24];
    const float* ow   = (const float*)d_in[25];
    const float* ob   = (const float*)d_in[26];
    float* out = (float*)d_out;

    char* ws = (char*)d_ws;
    size_t off = 0;
    auto alloc = [&](size_t bytes)->char*{
        char* p = ws + off;
        off += (bytes + 255) & ~(size_t)255;
        return p;
    };
    float* F0     = (float*)alloc((size_t)N1*256*4);
    float* F1     = (float*)alloc((size_t)N1*256*4);
    float* F2     = (float*)alloc((size_t)N2*128*4);
    float* AS     = (float*)alloc((size_t)N1*4*4);
    float* AD     = (float*)alloc((size_t)N1*4*4);
    int*   RP     = (int*)  alloc((size_t)(N1+1)*4);
    int*   CUR    = (int*)  alloc((size_t)N1*4);
    int*   EL     = (int*)  alloc((size_t)EE*4);
    float* DINV   = (float*)alloc((size_t)N1*4);
    float* SCORE  = (float*)alloc((size_t)N1*4);
    int*   PERM1  = (int*)  alloc((size_t)N2*4);
    float* SSORT1 = (float*)alloc((size_t)N2*4);
    int*   NID    = (int*)  alloc((size_t)N1*4);
    int*   E1S    = (int*)  alloc((size_t)EE*4);
    int*   E1D    = (int*)  alloc((size_t)EE*4);
    int*   RP2    = (int*)  alloc((size_t)(N2+1)*4);
    int*   CUR2   = (int*)  alloc((size_t)N2*4);
    int*   EL2    = (int*)  alloc((size_t)EE*4);
    float* DINV2  = (float*)alloc((size_t)N2*4);
    int*   PERM2  = (int*)  alloc((size_t)N3*4);
    float* SSORT2 = (float*)alloc((size_t)N3*4);
    float* GBUF   = (float*)alloc((size_t)NB*128*4);
    int*   BS     = (int*)  alloc((size_t)128*4);

    // ---- level-1 CSR (by dst; bucket entries = src node ids) ----
    hipMemsetAsync(CUR, 0, (size_t)N1*4, stream);
    count_dst<<<EE/256, 256, 0, stream>>>(dst, CUR, EE);
    blocksum_k<<<N1/256, 256, 0, stream>>>(CUR, BS);
    scan_write_k<<<N1/256, 256, 0, stream>>>(CUR, BS, N1/256, RP, CUR, DINV, N1);
    scatter1<<<EE/256, 256, 0, stream>>>(src, dst, CUR, EL, EE);

    // ---- GAT layer 1 (64 -> 4x64, relu) ----
    gemm_h2<<<dim3(N1/128, 2), 256, 0, stream>>>(x, g1w, F0, N1, 64, 256);
    attn_pre<<<N1/4, 256, 0, stream>>>(F0, g1as, g1ad, AS, AD);
    gat_agg<1><<<N1/4, 256, 0, stream>>>(F0, AS, AD, g1b, RP, EL, F1);

    // ---- GAT layer 2 (256 -> 4x64) ----
    gemm_h2<<<dim3(N1/128, 2), 256, 0, stream>>>(F1, g2w, F0, N1, 256, 256);
    attn_pre<<<N1/4, 256, 0, stream>>>(F0, g2as, g2ad, AS, AD);
    gat_agg<0><<<N1/4, 256, 0, stream>>>(F0, AS, AD, g2b, RP, EL, F1);

    // ---- GCN1 (256 -> 128, relu) ----
    gemm_h2<<<dim3(N1/128, 1), 256, 0, stream>>>(F1, c1w, F0, N1, 256, 128);
    gcn_agg<<<N1/4, 256, 0, stream>>>(F0, DINV, c1b, RP, EL, F1);

    // ---- SAGPool1 ----
    sag_score<<<N1/4, 256, 0, stream>>>(F1, s1wrel, s1brel, s1wroot, RP, EL, SCORE);
    hipMemsetAsync(NID, 0xFF, (size_t)N1*4, stream);   // -1
    topk_sel<<<NB, 1024, 0, stream>>>(SCORE, NPG1, KK1, PERM1, SSORT1, NID, 1);
    pool_gather<<<N2, 128, 0, stream>>>(F1, PERM1, SSORT1, F0);          // x2 -> F0

    // ---- level-2 CSR (remap + count fused) ----
    hipMemsetAsync(CUR2, 0, (size_t)N2*4, stream);
    remap_count<<<EE/256, 256, 0, stream>>>(src, dst, NID, E1S, E1D, CUR2, EE);
    blocksum_k<<<N2/256, 256, 0, stream>>>(CUR2, BS);
    scan_write_k<<<N2/256, 256, 0, stream>>>(CUR2, BS, N2/256, RP2, CUR2, DINV2, N2);
    scatter2<<<EE/256, 256, 0, stream>>>(E1S, E1D, CUR2, EL2, EE);

    // ---- GCN2 (128 -> 128, relu) ----
    gemm_h2<<<dim3(N2/128, 1), 256, 0, stream>>>(F0, c2w, F1, N2, 128, 128);
    gcn_agg<<<N2/4, 256, 0, stream>>>(F1, DINV2, c2b, RP2, EL2, F2);

    // ---- SAGPool2 ----
    sag_score<<<N2/4, 256, 0, stream>>>(F2, s2wrel, s2brel, s2wroot, RP2, EL2, SCORE);
    topk_sel<<<NB, 1024, 0, stream>>>(SCORE, NPG2, KK2, PERM2, SSORT2, nullptr, 0);

    // ---- fused gather + mean pool + MLP ----
    pool_mean2<<<NB, 256, 0, stream>>>(F2, PERM2, SSORT2, GBUF);
    mlp_k<<<NB, 256, 0, stream>>>(GBUF, f1w, f1b, f2w, f2b, ow, ob, out);
}

// Round 8
// 394.053 us; speedup vs baseline: 1.9410x; 1.0191x over previous
//
#include <hip/hip_runtime.h>

#define N1 32768
#define EE 524288
#define NB 16
#define DEG 16
#define NPG1 2048
#define KK1 1024
#define N2 16384
#define NPG2 1024
#define KK2 512
#define N3 8192
#define EPG 32768   // edges per graph (NPG1*DEG), contiguous per graph

typedef _Float16 half8_t __attribute__((ext_vector_type(8)));
typedef float floatx16 __attribute__((ext_vector_type(16)));

static __device__ __forceinline__ float leaky(float x){ return fmaxf(x, 0.2f*x); }

// ---------------- single-kernel CSR build, level 1 ----------------
// one block per graph; edges [g*EPG,(g+1)*EPG); buckets at base g*EPG.
__global__ __launch_bounds__(1024) void csr_build1(const int* __restrict__ src,
        const int* __restrict__ dst, int2* __restrict__ rpx,
        float* __restrict__ dinv, int* __restrict__ esrc){
    __shared__ int cnt[NPG1];
    __shared__ int pos[NPG1];
    __shared__ int wsum[16];
    int g = blockIdx.x, tid = threadIdx.x;
    int e0 = g*EPG;
    int nb0 = g*NPG1;
    cnt[tid] = 0; cnt[tid + 1024] = 0;
    __syncthreads();
    for (int e = tid; e < EPG; e += 1024)
        atomicAdd(&cnt[dst[e0 + e] - nb0], 1);
    __syncthreads();
    int c0 = cnt[2*tid], c1 = cnt[2*tid + 1];
    int pair = c0 + c1;
    int lane = tid & 63, wv = tid >> 6;
    int x = pair;
    #pragma unroll
    for (int off = 1; off < 64; off <<= 1){ int y = __shfl_up(x, off); if (lane >= off) x += y; }
    if (lane == 63) wsum[wv] = x;
    __syncthreads();
    if (tid == 0){ int run = 0; for (int w = 0; w < 16; w++){ int t = wsum[w]; wsum[w] = run; run += t; } }
    __syncthreads();
    int excl = x - pair + wsum[wv];
    pos[2*tid]   = excl;
    pos[2*tid+1] = excl + c0;
    rpx[nb0 + 2*tid]   = make_int2(e0 + excl,      e0 + excl + c0);
    rpx[nb0 + 2*tid+1] = make_int2(e0 + excl + c0, e0 + excl + pair);
    dinv[nb0 + 2*tid]   = rsqrtf((float)c0 + 1.0f);
    dinv[nb0 + 2*tid+1] = rsqrtf((float)c1 + 1.0f);
    __syncthreads();
    for (int e = tid; e < EPG; e += 1024){
        int s = src[e0 + e];
        int dl = dst[e0 + e] - nb0;
        int p = atomicAdd(&pos[dl], 1);
        esrc[e0 + p] = s;
    }
}

// ---------------- single-kernel CSR build, level 2 (remap via nid) ----------
__global__ __launch_bounds__(1024) void csr_build2(const int* __restrict__ src,
        const int* __restrict__ dst, const int* __restrict__ nid,
        int2* __restrict__ rpx, float* __restrict__ dinv, int* __restrict__ esrc){
    __shared__ int cnt[KK1];
    __shared__ int pos[KK1];
    __shared__ int wsum[16];
    int g = blockIdx.x, tid = threadIdx.x;
    int e0 = g*EPG;
    int nb0 = g*KK1;
    cnt[tid] = 0;
    __syncthreads();
    for (int e = tid; e < EPG; e += 1024){
        int a = nid[src[e0 + e]], b = nid[dst[e0 + e]];
        if (a >= 0 && b >= 0) atomicAdd(&cnt[b - nb0], 1);
    }
    __syncthreads();
    int c = cnt[tid];
    int lane = tid & 63, wv = tid >> 6;
    int x = c;
    #pragma unroll
    for (int off = 1; off < 64; off <<= 1){ int y = __shfl_up(x, off); if (lane >= off) x += y; }
    if (lane == 63) wsum[wv] = x;
    __syncthreads();
    if (tid == 0){ int run = 0; for (int w = 0; w < 16; w++){ int t = wsum[w]; wsum[w] = run; run += t; } }
    __syncthreads();
    int excl = x - c + wsum[wv];
    pos[tid] = excl;
    rpx[nb0 + tid] = make_int2(e0 + excl, e0 + excl + c);
    dinv[nb0 + tid] = rsqrtf((float)c + 1.0f);
    __syncthreads();
    for (int e = tid; e < EPG; e += 1024){
        int a = nid[src[e0 + e]], b = nid[dst[e0 + e]];
        if (a >= 0 && b >= 0){
            int p = atomicAdd(&pos[b - nb0], 1);
            esrc[e0 + p] = a;
        }
    }
}

// ---------------- weight pre-split (fp32 -> fp16 hi/lo), all 4 GEMMs -------
__global__ void wsplit4(const float* __restrict__ w0, int n0,
                        const float* __restrict__ w1, int n1,
                        const float* __restrict__ w2, int n2,
                        const float* __restrict__ w3, int n3,
                        _Float16* __restrict__ wh, _Float16* __restrict__ wl){
    int i = blockIdx.x*256 + threadIdx.x;
    int n01 = n0 + n1, n012 = n01 + n2, nt = n012 + n3;
    if (i >= nt) return;
    float v = (i < n0) ? w0[i] : (i < n01) ? w1[i - n0] : (i < n012) ? w2[i - n01] : w3[i - n012];
    _Float16 h = (_Float16)v;
    wh[i] = h; wl[i] = (_Float16)(v - (float)h);
}

// ------------- split-fp16 MFMA GEMM: C = A @ W^T (fp32 A, pre-split W) ------
#define KS 64
static __device__ __forceinline__ int ldsoff(int row, int k8){
    return row*64 + ((k8 ^ (row & 7)) << 3);
}

__global__ __launch_bounds__(256, 2) void gemm_h2(const float* __restrict__ A,
        const _Float16* __restrict__ WHp, const _Float16* __restrict__ WLp,
        float* __restrict__ C, int n, int K, int M){
    __shared__ _Float16 sm[4*128*KS];
    _Float16* sAH = sm;
    _Float16* sAL = sm + 128*KS;
    _Float16* sWH = sm + 2*128*KS;
    _Float16* sWL = sm + 3*128*KS;
    int t = threadIdx.x;
    int lane = t & 63;
    int wid = t >> 6;
    int wr = wid >> 1, wc = wid & 1;
    int row0 = blockIdx.x*128, col0 = blockIdx.y*128;
    int srow = t >> 3;
    int sk8  = t & 7;

    floatx16 acc[2][2];
    #pragma unroll
    for (int i = 0; i < 2; i++)
        #pragma unroll
        for (int j = 0; j < 2; j++)
            #pragma unroll
            for (int q = 0; q < 16; q++) acc[i][j][q] = 0.f;

    for (int kk = 0; kk < K; kk += KS){
        #pragma unroll
        for (int p = 0; p < 4; p++){
            int r = srow + p*32;
            const float* ga = A + (size_t)(row0 + r)*K + kk + sk8*8;
            float4 a0 = *(const float4*)ga;
            float4 a1 = *(const float4*)(ga + 4);
            half8_t ahi, alo;
            float av[8] = {a0.x,a0.y,a0.z,a0.w,a1.x,a1.y,a1.z,a1.w};
            #pragma unroll
            for (int q = 0; q < 8; q++){
                _Float16 h = (_Float16)av[q];
                ahi[q] = h; alo[q] = (_Float16)(av[q] - (float)h);
            }
            size_t wo = (size_t)(col0 + r)*K + kk + sk8*8;
            half8_t whi = *(const half8_t*)(WHp + wo);
            half8_t wlo = *(const half8_t*)(WLp + wo);
            int o = ldsoff(r, sk8);
            *(half8_t*)&sAH[o] = ahi;
            *(half8_t*)&sAL[o] = alo;
            *(half8_t*)&sWH[o] = whi;
            *(half8_t*)&sWL[o] = wlo;
        }
        __syncthreads();
        #pragma unroll
        for (int kc = 0; kc < 4; kc++){
            int k8 = kc*2 + (lane >> 5);
            int ra = wr*64 + (lane & 31);
            int rb = wc*64 + (lane & 31);
            half8_t ah0 = *(const half8_t*)&sAH[ldsoff(ra,      k8)];
            half8_t ah1 = *(const half8_t*)&sAH[ldsoff(ra + 32, k8)];
            half8_t al0 = *(const half8_t*)&sAL[ldsoff(ra,      k8)];
            half8_t al1 = *(const half8_t*)&sAL[ldsoff(ra + 32, k8)];
            half8_t bh0 = *(const half8_t*)&sWH[ldsoff(rb,      k8)];
            half8_t bh1 = *(const half8_t*)&sWH[ldsoff(rb + 32, k8)];
            half8_t bl0 = *(const half8_t*)&sWL[ldsoff(rb,      k8)];
            half8_t bl1 = *(const half8_t*)&sWL[ldsoff(rb + 32, k8)];
            acc[0][0] = __builtin_amdgcn_mfma_f32_32x32x16_f16(ah0, bh0, acc[0][0], 0,0,0);
            acc[0][0] = __builtin_amdgcn_mfma_f32_32x32x16_f16(ah0, bl0, acc[0][0], 0,0,0);
            acc[0][0] = __builtin_amdgcn_mfma_f32_32x32x16_f16(al0, bh0, acc[0][0], 0,0,0);
            acc[0][1] = __builtin_amdgcn_mfma_f32_32x32x16_f16(ah0, bh1, acc[0][1], 0,0,0);
            acc[0][1] = __builtin_amdgcn_mfma_f32_32x32x16_f16(ah0, bl1, acc[0][1], 0,0,0);
            acc[0][1] = __builtin_amdgcn_mfma_f32_32x32x16_f16(al0, bh1, acc[0][1], 0,0,0);
            acc[1][0] = __builtin_amdgcn_mfma_f32_32x32x16_f16(ah1, bh0, acc[1][0], 0,0,0);
            acc[1][0] = __builtin_amdgcn_mfma_f32_32x32x16_f16(ah1, bl0, acc[1][0], 0,0,0);
            acc[1][0] = __builtin_amdgcn_mfma_f32_32x32x16_f16(al1, bh0, acc[1][0], 0,0,0);
            acc[1][1] = __builtin_amdgcn_mfma_f32_32x32x16_f16(ah1, bh1, acc[1][1], 0,0,0);
            acc[1][1] = __builtin_amdgcn_mfma_f32_32x32x16_f16(ah1, bl1, acc[1][1], 0,0,0);
            acc[1][1] = __builtin_amdgcn_mfma_f32_32x32x16_f16(al1, bh1, acc[1][1], 0,0,0);
        }
        __syncthreads();
    }
    #pragma unroll
    for (int rt = 0; rt < 2; rt++)
        #pragma unroll
        for (int ct = 0; ct < 2; ct++){
            int baser = row0 + wr*64 + rt*32 + 4*(lane >> 5);
            int c = col0 + wc*64 + ct*32 + (lane & 31);
            #pragma unroll
            for (int r = 0; r < 16; r++){
                int rr = baser + (r & 3) + 8*(r >> 2);
                C[(size_t)rr*M + c] = acc[rt][ct][r];
            }
        }
}

// ---------------- GAT attention coefficients ----------------
__global__ void attn_pre(const float* __restrict__ h, const float* __restrict__ wsrc,
                         const float* __restrict__ wdst, float* __restrict__ as_,
                         float* __restrict__ ad_){
    int lane = threadIdx.x & 63;
    int w = threadIdx.x >> 6;
    int d = blockIdx.x*4 + w;
    float4 hv = *(const float4*)(h + (size_t)d*256 + lane*4);
    float4 ws = *(const float4*)(wsrc + lane*4);
    float4 wd = *(const float4*)(wdst + lane*4);
    float ps = hv.x*ws.x + hv.y*ws.y + hv.z*ws.z + hv.w*ws.w;
    float pd = hv.x*wd.x + hv.y*wd.y + hv.z*wd.z + hv.w*wd.w;
    #pragma unroll
    for (int m = 8; m; m >>= 1){ ps += __shfl_xor(ps, m); pd += __shfl_xor(pd, m); }
    if ((lane & 15) == 0){
        as_[d*4 + (lane >> 4)] = ps;
        ad_[d*4 + (lane >> 4)] = pd;
    }
}

// ---- GAT aggregation: no-max softmax, 8-wide pipeline ----
template<int RELU>
__global__ void gat_agg(const float* __restrict__ h, const float* __restrict__ as_,
                        const float* __restrict__ ad_, const float* __restrict__ bias,
                        const int2* __restrict__ rpx, const int* __restrict__ esrc,
                        float* __restrict__ out){
    int lane = threadIdx.x & 63;
    int w = threadIdx.x >> 6;
    int nb = gridDim.x;
    int b = blockIdx.x;
    int sb = (b & 7)*(nb >> 3) + (b >> 3);
    int d = sb*4 + w;
    int2 re = rpx[d];
    int beg = re.x, end = re.y;

    int hh = lane >> 4;
    int c0 = lane*4;
    float adh = ad_[(d<<2) + hh];
    float aself = as_[(d<<2) + hh];

    float dn[4];
    dn[0] = __expf(leaky(aself + adh)); dn[1] = 0.f; dn[2] = 0.f; dn[3] = 0.f;
    float4 hd = *(const float4*)(h + (d<<8) + c0);
    float4 AX[4];
    AX[0].x = dn[0]*hd.x; AX[0].y = dn[0]*hd.y; AX[0].z = dn[0]*hd.z; AX[0].w = dn[0]*hd.w;
    AX[1] = {0,0,0,0}; AX[2] = {0,0,0,0}; AX[3] = {0,0,0,0};

    int i = beg;
    int endu = beg + ((end - beg) & ~7);
    for (; i < endu; i += 8){
        int s_[8];
        #pragma unroll
        for (int j = 0; j < 8; j++) s_[j] = esrc[i + j];
        float a_[8];
        #pragma unroll
        for (int j = 0; j < 8; j++) a_[j] = as_[(s_[j]<<2) + hh];
        float4 hv_[8];
        #pragma unroll
        for (int j = 0; j < 8; j++) hv_[j] = *(const float4*)(h + (s_[j]<<8) + c0);
        #pragma unroll
        for (int j = 0; j < 8; j++){
            float x = a_[j] + adh;
            float p = __expf(fmaxf(x, 0.2f*x));
            dn[j & 3] += p;
            AX[j & 3].x = fmaf(p, hv_[j].x, AX[j & 3].x);
            AX[j & 3].y = fmaf(p, hv_[j].y, AX[j & 3].y);
            AX[j & 3].z = fmaf(p, hv_[j].z, AX[j & 3].z);
            AX[j & 3].w = fmaf(p, hv_[j].w, AX[j & 3].w);
        }
    }
    for (; i < end; ++i){
        int s = esrc[i];
        float x = as_[(s<<2) + hh] + adh;
        float4 hv = *(const float4*)(h + (s<<8) + c0);
        float p = __expf(fmaxf(x, 0.2f*x));
        dn[0] += p;
        AX[0].x = fmaf(p, hv.x, AX[0].x); AX[0].y = fmaf(p, hv.y, AX[0].y);
        AX[0].z = fmaf(p, hv.z, AX[0].z); AX[0].w = fmaf(p, hv.w, AX[0].w);
    }
    float den = ((dn[0] + dn[1]) + (dn[2] + dn[3])) + 1e-16f;
    float r = 1.0f / den;
    float4 bv = *(const float4*)(bias + c0);
    float4 acc;
    acc.x = ((AX[0].x+AX[1].x)+(AX[2].x+AX[3].x))*r + bv.x;
    acc.y = ((AX[0].y+AX[1].y)+(AX[2].y+AX[3].y))*r + bv.y;
    acc.z = ((AX[0].z+AX[1].z)+(AX[2].z+AX[3].z))*r + bv.z;
    acc.w = ((AX[0].w+AX[1].w)+(AX[2].w+AX[3].w))*r + bv.w;
    if (RELU){
        acc.x = fmaxf(acc.x, 0.f); acc.y = fmaxf(acc.y, 0.f);
        acc.z = fmaxf(acc.z, 0.f); acc.w = fmaxf(acc.w, 0.f);
    }
    *(float4*)(out + (d<<8) + c0) = acc;
}

// ---- GCN aggregation + fused SAG-score partial dots (y = out.wrel, z = out.wroot+b)
__global__ void gcn_agg_sag(const float* __restrict__ h, const float* __restrict__ dinv,
                            const float* __restrict__ bias,
                            const float* __restrict__ wrel, const float* __restrict__ wroot,
                            const float* __restrict__ brel,
                            const int2* __restrict__ rpx, const int* __restrict__ esrc,
                            float* __restrict__ out, float* __restrict__ Y, float* __restrict__ Z){
    int lane = threadIdx.x & 63;
    int w = threadIdx.x >> 6;
    int nb = gridDim.x;
    int b = blockIdx.x;
    int sb = (b & 7)*(nb >> 3) + (b >> 3);
    int d = sb*4 + w;
    int2 re = rpx[d];
    int beg = re.x, end = re.y;
    float dv = dinv[d];
    int c0 = lane*2;
    float2 hd = *(const float2*)(h + (d<<7) + c0);
    float self = dv*dv;
    float ax[4] = {self*hd.x, 0.f, 0.f, 0.f};
    float ay[4] = {self*hd.y, 0.f, 0.f, 0.f};
    int i = beg;
    int endu = beg + ((end - beg) & ~7);
    for (; i < endu; i += 8){
        int s_[8];
        #pragma unroll
        for (int j = 0; j < 8; j++) s_[j] = esrc[i + j];
        float di_[8];
        #pragma unroll
        for (int j = 0; j < 8; j++) di_[j] = dinv[s_[j]];
        float2 hv_[8];
        #pragma unroll
        for (int j = 0; j < 8; j++) hv_[j] = *(const float2*)(h + (s_[j]<<7) + c0);
        #pragma unroll
        for (int j = 0; j < 8; j++){
            float coef = di_[j]*dv;
            ax[j & 3] = fmaf(coef, hv_[j].x, ax[j & 3]);
            ay[j & 3] = fmaf(coef, hv_[j].y, ay[j & 3]);
        }
    }
    for (; i < end; ++i){
        int s = esrc[i];
        float coef = dinv[s]*dv;
        float2 hv = *(const float2*)(h + (s<<7) + c0);
        ax[0] = fmaf(coef, hv.x, ax[0]); ay[0] = fmaf(coef, hv.y, ay[0]);
    }
    float axs = ((ax[0]+ax[1])+(ax[2]+ax[3]));
    float ays = ((ay[0]+ay[1])+(ay[2]+ay[3]));
    axs = fmaxf(axs + bias[c0], 0.f);
    ays = fmaxf(ays + bias[c0+1], 0.f);
    float2 o; o.x = axs; o.y = ays;
    *(float2*)(out + (d<<7) + c0) = o;
    // fused score partials
    float py = axs*wrel[c0]  + ays*wrel[c0+1];
    float pz = axs*wroot[c0] + ays*wroot[c0+1];
    #pragma unroll
    for (int off = 32; off; off >>= 1){ py += __shfl_xor(py, off); pz += __shfl_xor(pz, off); }
    if (lane == 0){ Y[d] = py; Z[d] = pz + brel[0]; }
}

// ---------------- SAG score via scalar gather ----------------
__global__ void sag_lite(const float* __restrict__ Y, const float* __restrict__ Z,
                         const int2* __restrict__ rpx, const int* __restrict__ esrc,
                         float* __restrict__ score){
    int lane = threadIdx.x & 63;
    int w = threadIdx.x >> 6;
    int nb = gridDim.x;
    int b = blockIdx.x;
    int sb = (b & 7)*(nb >> 3) + (b >> 3);
    int d = sb*4 + w;
    int2 re = rpx[d];
    float s = 0.f;
    for (int i = re.x + lane; i < re.y; i += 64) s += Y[esrc[i]];
    #pragma unroll
    for (int off = 32; off; off >>= 1) s += __shfl_xor(s, off);
    if (lane == 0) score[d] = s + Z[d];
}

// ---------------- radix-select top-k ----------------
__global__ __launch_bounds__(1024) void topk_sel(const float* __restrict__ score,
        int npg, int k, int* __restrict__ perm, float* __restrict__ ssort,
        int* __restrict__ nid, int writeNid){
    __shared__ unsigned keys[2048];
    __shared__ int hist[256];
    __shared__ int cge[256];
    __shared__ int warpsum[16];
    __shared__ int s_bin, s_need;
    int g = blockIdx.x, tid = threadIdx.x;
    for (int i = tid; i < npg; i += 1024){
        unsigned u = __float_as_uint(score[g*npg + i]);
        u = (u & 0x80000000u) ? ~u : (u | 0x80000000u);
        keys[i] = u;
    }
    if (tid == 0) s_need = k;
    __syncthreads();
    unsigned prefix = 0u, pmask = 0u;
    #pragma unroll
    for (int shift = 24; shift >= 0; shift -= 8){
        if (tid < 256) hist[tid] = 0;
        __syncthreads();
        for (int i = tid; i < npg; i += 1024){
            unsigned u = keys[i];
            if ((u & pmask) == prefix) atomicAdd(&hist[(u >> shift) & 255u], 1);
        }
        __syncthreads();
        if (tid < 256) cge[tid] = hist[tid];
        __syncthreads();
        for (int off = 1; off < 256; off <<= 1){
            int v = 0;
            if (tid < 256 - off) v = cge[tid + off];
            __syncthreads();
            if (tid < 256) cge[tid] += v;
            __syncthreads();
        }
        int need = s_need;
        if (tid < 256){
            int above = (tid == 255) ? 0 : cge[tid + 1];
            if (cge[tid] >= need && above < need) s_bin = tid;
        }
        __syncthreads();
        if (tid == 0) s_need = need - ((s_bin == 255) ? 0 : cge[s_bin + 1]);
        __syncthreads();
        prefix |= ((unsigned)s_bin) << shift;
        pmask  |= (255u << shift);
        __syncthreads();
    }
    unsigned thr = prefix;
    int m = s_need;
    int i0 = 2*tid, i1 = 2*tid + 1;
    int f0 = 0, f1 = 0;
    if (i0 < npg){
        unsigned u = keys[i0];
        if (u > thr) f0 = 1;
        else if (u == thr){
            int r = 0;
            for (int j = 0; j < i0; j++) r += (keys[j] == thr);
            f0 = (r < m) ? 1 : 0;
        }
    }
    if (i1 < npg){
        unsigned u = keys[i1];
        if (u > thr) f1 = 1;
        else if (u == thr){
            int r = 0;
            for (int j = 0; j < i1; j++) r += (keys[j] == thr);
            f1 = (r < m) ? 1 : 0;
        }
    }
    int pair = f0 + f1;
    int lane = tid & 63, wv = tid >> 6;
    int x = pair;
    #pragma unroll
    for (int off = 1; off < 64; off <<= 1){ int y = __shfl_up(x, off); if (lane >= off) x += y; }
    if (lane == 63) warpsum[wv] = x;
    __syncthreads();
    if (tid == 0){ int run = 0; for (int w2 = 0; w2 < 16; w2++){ int t = warpsum[w2]; warpsum[w2] = run; run += t; } }
    __syncthreads();
    int excl = x - pair + warpsum[wv];
    if (f0){
        int pos = excl;
        int node = g*npg + i0;
        perm[g*k + pos] = node;
        ssort[g*k + pos] = score[node];
        if (writeNid) nid[node] = g*k + pos;
    }
    if (f1){
        int pos = excl + f0;
        int node = g*npg + i1;
        perm[g*k + pos] = node;
        ssort[g*k + pos] = score[node];
        if (writeNid) nid[node] = g*k + pos;
    }
}

__global__ void pool_gather(const float* __restrict__ x, const int* __restrict__ perm,
                            const float* __restrict__ ssort, float* __restrict__ xn){
    int j = blockIdx.x; int c = threadIdx.x;
    int o = perm[j];
    float t = tanhf(ssort[j]);
    xn[(size_t)j*128 + c] = x[(size_t)o*128 + c] * t;
}

__global__ void pool_mean2(const float* __restrict__ x, const int* __restrict__ perm,
                           const float* __restrict__ ssort, float* __restrict__ g){
    __shared__ float tt[KK2];
    __shared__ float part[128];
    int b = blockIdx.x, t = threadIdx.x;     // 256 threads
    tt[t]       = tanhf(ssort[b*KK2 + t]);
    tt[t + 256] = tanhf(ssort[b*KK2 + t + 256]);
    __syncthreads();
    int c = t & 127, half = t >> 7;
    float s = 0.f;
    #pragma unroll 4
    for (int i = half*256; i < half*256 + 256; i++){
        int o = perm[b*KK2 + i];
        s = fmaf(tt[i], x[(size_t)o*128 + c], s);
    }
    if (half) part[c] = s;
    __syncthreads();
    if (!half) g[b*128 + c] = (s + part[c]) * (1.0f/KK2);
}

__global__ void mlp_k(const float* __restrict__ g,
                      const float* __restrict__ fc1w, const float* __restrict__ fc1b,
                      const float* __restrict__ fc2w, const float* __restrict__ fc2b,
                      const float* __restrict__ ow,  const float* __restrict__ ob,
                      float* __restrict__ out){
    __shared__ float gv[128], t1[256], t2[128];
    int b = blockIdx.x, t = threadIdx.x;
    if (t < 128) gv[t] = g[b*128 + t];
    __syncthreads();
    {
        float s = fc1b[t];
        for (int c = 0; c < 128; c++) s += gv[c]*fc1w[t*128 + c];
        t1[t] = fmaxf(s, 0.f);
    }
    __syncthreads();
    if (t < 128){
        float s = fc2b[t];
        for (int c = 0; c < 256; c++) s += t1[c]*fc2w[t*256 + c];
        t2[t] = fmaxf(s, 0.f);
    }
    __syncthreads();
    if (t < 10){
        float s = ob[t];
        for (int c = 0; c < 128; c++) s += t2[c]*ow[t*128 + c];
        out[b*10 + t] = s;
    }
}

// ---------------- launch ----------------
extern "C" void kernel_launch(void* const* d_in, const int* in_sizes, int n_in,
                              void* d_out, int out_size, void* d_ws, size_t ws_size,
                              hipStream_t stream){
    (void)in_sizes; (void)n_in; (void)out_size; (void)ws_size;
    const float* x    = (const float*)d_in[0];
    const int*   eidx = (const int*)d_in[1];
    const int*   src  = eidx;
    const int*   dst  = eidx + EE;
    const float* g1w  = (const float*)d_in[3];
    const float* g1as = (const float*)d_in[4];
    const float* g1ad = (const float*)d_in[5];
    const float* g1b  = (const float*)d_in[6];
    const float* g2w  = (const float*)d_in[7];
    const float* g2as = (const float*)d_in[8];
    const float* g2ad = (const float*)d_in[9];
    const float* g2b  = (const float*)d_in[10];
    const float* c1w  = (const float*)d_in[11];
    const float* c1b  = (const float*)d_in[12];
    const float* s1wrel  = (const float*)d_in[13];
    const float* s1brel  = (const float*)d_in[14];
    const float* s1wroot = (const float*)d_in[15];
    const float* c2w  = (const float*)d_in[16];
    const float* c2b  = (const float*)d_in[17];
    const float* s2wrel  = (const float*)d_in[18];
    const float* s2brel  = (const float*)d_in[19];
    const float* s2wroot = (const float*)d_in[20];
    const float* f1w  = (const float*)d_in[21];
    const float* f1b  = (const float*)d_in[22];
    const float* f2w  = (const float*)d_in[23];
    const float* f2b  = (const float*)d_in[24];
    const float* ow   = (const float*)d_in[25];
    const float* ob   = (const float*)d_in[26];
    float* out = (float*)d_out;

    char* ws = (char*)d_ws;
    size_t off = 0;
    auto alloc = [&](size_t bytes)->char*{
        char* p = ws + off;
        off += (bytes + 255) & ~(size_t)255;
        return p;
    };
    float* F0     = (float*)alloc((size_t)N1*256*4);
    float* F1     = (float*)alloc((size_t)N1*256*4);
    float* F2     = (float*)alloc((size_t)N2*128*4);
    float* AS     = (float*)alloc((size_t)N1*4*4);
    float* AD     = (float*)alloc((size_t)N1*4*4);
    int2*  RPX    = (int2*) alloc((size_t)N1*8);
    int*   EL     = (int*)  alloc((size_t)EE*4);
    float* DINV   = (float*)alloc((size_t)N1*4);
    float* SCORE  = (float*)alloc((size_t)N1*4);
    float* Y      = (float*)alloc((size_t)N1*4);
    float* Z      = (float*)alloc((size_t)N1*4);
    int*   PERM1  = (int*)  alloc((size_t)N2*4);
    float* SSORT1 = (float*)alloc((size_t)N2*4);
    int*   NID    = (int*)  alloc((size_t)N1*4);
    int2*  RPX2   = (int2*) alloc((size_t)N2*8);
    int*   EL2    = (int*)  alloc((size_t)EE*4);
    float* DINV2  = (float*)alloc((size_t)N2*4);
    int*   PERM2  = (int*)  alloc((size_t)N3*4);
    float* SSORT2 = (float*)alloc((size_t)N3*4);
    float* GBUF   = (float*)alloc((size_t)NB*128*4);
    _Float16* WH  = (_Float16*)alloc((size_t)131072*2);
    _Float16* WL  = (_Float16*)alloc((size_t)131072*2);
    // pre-split weight offsets (g1w:16384, g2w:65536, c1w:32768, c2w:16384)
    const int o_g1 = 0, o_g2 = 16384, o_c1 = 81920, o_c2 = 114688;

    // ---- CSR level 1 (single kernel) + weight pre-split ----
    csr_build1<<<NB, 1024, 0, stream>>>(src, dst, RPX, DINV, EL);
    wsplit4<<<512, 256, 0, stream>>>(g1w, 16384, g2w, 65536, c1w, 32768, c2w, 16384, WH, WL);

    // ---- GAT layer 1 (64 -> 4x64, relu) ----
    gemm_h2<<<dim3(N1/128, 2), 256, 0, stream>>>(x, WH + o_g1, WL + o_g1, F0, N1, 64, 256);
    attn_pre<<<N1/4, 256, 0, stream>>>(F0, g1as, g1ad, AS, AD);
    gat_agg<1><<<N1/4, 256, 0, stream>>>(F0, AS, AD, g1b, RPX, EL, F1);

    // ---- GAT layer 2 (256 -> 4x64) ----
    gemm_h2<<<dim3(N1/128, 2), 256, 0, stream>>>(F1, WH + o_g2, WL + o_g2, F0, N1, 256, 256);
    attn_pre<<<N1/4, 256, 0, stream>>>(F0, g2as, g2ad, AS, AD);
    gat_agg<0><<<N1/4, 256, 0, stream>>>(F0, AS, AD, g2b, RPX, EL, F1);

    // ---- GCN1 (256 -> 128, relu) + fused SAG1 partial dots ----
    gemm_h2<<<dim3(N1/128, 1), 256, 0, stream>>>(F1, WH + o_c1, WL + o_c1, F0, N1, 256, 128);
    gcn_agg_sag<<<N1/4, 256, 0, stream>>>(F0, DINV, c1b, s1wrel, s1wroot, s1brel,
                                          RPX, EL, F1, Y, Z);

    // ---- SAGPool1 ----
    sag_lite<<<N1/4, 256, 0, stream>>>(Y, Z, RPX, EL, SCORE);
    hipMemsetAsync(NID, 0xFF, (size_t)N1*4, stream);   // -1
    topk_sel<<<NB, 1024, 0, stream>>>(SCORE, NPG1, KK1, PERM1, SSORT1, NID, 1);
    pool_gather<<<N2, 128, 0, stream>>>(F1, PERM1, SSORT1, F0);          // x2 -> F0

    // ---- CSR level 2 (single kernel, remap in-kernel) ----
    csr_build2<<<NB, 1024, 0, stream>>>(src, dst, NID, RPX2, DINV2, EL2);

    // ---- GCN2 (128 -> 128, relu) + fused SAG2 partial dots ----
    gemm_h2<<<dim3(N2/128, 1), 256, 0, stream>>>(F0, WH + o_c2, WL + o_c2, F1, N2, 128, 128);
    gcn_agg_sag<<<N2/4, 256, 0, stream>>>(F1, DINV2, c2b, s2wrel, s2wroot, s2brel,
                                          RPX2, EL2, F2, Y, Z);

    // ---- SAGPool2 ----
    sag_lite<<<N2/4, 256, 0, stream>>>(Y, Z, RPX2, EL2, SCORE);
    topk_sel<<<NB, 1024, 0, stream>>>(SCORE, NPG2, KK2, PERM2, SSORT2, nullptr, 0);

    // ---- fused gather + mean pool + MLP ----
    pool_mean2<<<NB, 256, 0, stream>>>(F2, PERM2, SSORT2, GBUF);
    mlp_k<<<NB, 256, 0, stream>>>(GBUF, f1w, f1b, f2w, f2b, ow, ob, out);
}

// Round 9
// 378.423 us; speedup vs baseline: 2.0212x; 1.0413x over previous
//
#include <hip/hip_runtime.h>

#define N1 32768
#define EE 524288
#define NB 16
#define DEG 16
#define NPG1 2048
#define KK1 1024
#define N2 16384
#define NPG2 1024
#define KK2 512
#define N3 8192

typedef _Float16 half8_t __attribute__((ext_vector_type(8)));
typedef float floatx16 __attribute__((ext_vector_type(16)));

static __device__ __forceinline__ float leaky(float x){ return fmaxf(x, 0.2f*x); }

// ---------------- CSR build (wide multi-kernel) ----------------
__global__ void count_dst(const int* __restrict__ dst, int* __restrict__ cnt, int E){
    int i = blockIdx.x*blockDim.x + threadIdx.x;
    if (i < E) atomicAdd(&cnt[dst[i]], 1);
}

// remap edges to pooled ids and count valid by new dst
__global__ void remap_count(const int* __restrict__ src, const int* __restrict__ dst,
                            const int* __restrict__ nid, int* __restrict__ ns,
                            int* __restrict__ nd, int* __restrict__ cnt, int E){
    int i = blockIdx.x*blockDim.x + threadIdx.x;
    if (i < E){
        int a = nid[src[i]], b = nid[dst[i]];
        ns[i] = a; nd[i] = b;
        if (a >= 0 && b >= 0) atomicAdd(&cnt[b], 1);
    }
}

__global__ void blocksum_k(const int* __restrict__ cnt, int* __restrict__ bs){
    __shared__ int red[4];
    int tid = threadIdx.x;
    int v = cnt[blockIdx.x*256 + tid];
    #pragma unroll
    for (int off = 32; off; off >>= 1) v += __shfl_xor(v, off);
    if ((tid & 63) == 0) red[tid >> 6] = v;
    __syncthreads();
    if (tid == 0) bs[blockIdx.x] = red[0] + red[1] + red[2] + red[3];
}

// cnt may alias cur; emits int2 (beg,end) rowptr + dinv = rsqrt(deg+1)
__global__ void scan_write_k(const int* __restrict__ cnt, const int* __restrict__ bs,
                             int nb, int2* __restrict__ rpx, int* __restrict__ cur,
                             float* __restrict__ dinv){
    __shared__ int sbs[128];
    __shared__ int wsum[4];
    int tid = threadIdx.x;
    int b = blockIdx.x;
    if (tid < nb) sbs[tid] = bs[tid];
    __syncthreads();
    for (int off = 1; off < nb; off <<= 1){
        int v = 0;
        if (tid < nb && tid >= off) v = sbs[tid - off];
        __syncthreads();
        if (tid < nb) sbs[tid] += v;
        __syncthreads();
    }
    int base = (b == 0) ? 0 : sbs[b-1];
    int i = b*256 + tid;
    int c = cnt[i];
    int lane = tid & 63, wv = tid >> 6;
    int x = c;
    #pragma unroll
    for (int off = 1; off < 64; off <<= 1){ int y = __shfl_up(x, off); if (lane >= off) x += y; }
    if (lane == 63) wsum[wv] = x;
    __syncthreads();
    if (tid == 0){ int run = 0; for (int w2 = 0; w2 < 4; w2++){ int t = wsum[w2]; wsum[w2] = run; run += t; } }
    __syncthreads();
    int excl = x - c + wsum[wv];
    int beg = base + excl;
    rpx[i]  = make_int2(beg, beg + c);
    cur[i]  = beg;
    dinv[i] = rsqrtf((float)c + 1.0f);
}

__global__ void scatter1(const int* __restrict__ src, const int* __restrict__ dst,
                         int* __restrict__ cur, int* __restrict__ esrc, int E){
    int i = blockIdx.x*blockDim.x + threadIdx.x;
    if (i < E){ int p = atomicAdd(&cur[dst[i]], 1); esrc[p] = src[i]; }
}

__global__ void scatter2(const int* __restrict__ ns, const int* __restrict__ nd,
                         int* __restrict__ cur, int* __restrict__ esrc, int E){
    int i = blockIdx.x*blockDim.x + threadIdx.x;
    if (i < E){
        int a = ns[i], b = nd[i];
        if (a >= 0 && b >= 0){ int p = atomicAdd(&cur[b], 1); esrc[p] = a; }
    }
}

// ---------------- weight pre-split (fp32 -> fp16 hi/lo), all 4 GEMMs -------
__global__ void wsplit4(const float* __restrict__ w0, int n0,
                        const float* __restrict__ w1, int n1,
                        const float* __restrict__ w2, int n2,
                        const float* __restrict__ w3, int n3,
                        _Float16* __restrict__ wh, _Float16* __restrict__ wl){
    int i = blockIdx.x*256 + threadIdx.x;
    int n01 = n0 + n1, n012 = n01 + n2, nt = n012 + n3;
    if (i >= nt) return;
    float v = (i < n0) ? w0[i] : (i < n01) ? w1[i - n0] : (i < n012) ? w2[i - n01] : w3[i - n012];
    _Float16 h = (_Float16)v;
    wh[i] = h; wl[i] = (_Float16)(v - (float)h);
}

// ------------- split-fp16 MFMA GEMM: C = A @ W^T (fp32 A, pre-split W) ------
#define KS 64
static __device__ __forceinline__ int ldsoff(int row, int k8){
    return row*64 + ((k8 ^ (row & 7)) << 3);
}

__global__ __launch_bounds__(256, 2) void gemm_h2(const float* __restrict__ A,
        const _Float16* __restrict__ WHp, const _Float16* __restrict__ WLp,
        float* __restrict__ C, int n, int K, int M){
    __shared__ _Float16 sm[4*128*KS];
    _Float16* sAH = sm;
    _Float16* sAL = sm + 128*KS;
    _Float16* sWH = sm + 2*128*KS;
    _Float16* sWL = sm + 3*128*KS;
    int t = threadIdx.x;
    int lane = t & 63;
    int wid = t >> 6;
    int wr = wid >> 1, wc = wid & 1;
    int row0 = blockIdx.x*128, col0 = blockIdx.y*128;
    int srow = t >> 3;
    int sk8  = t & 7;

    floatx16 acc[2][2];
    #pragma unroll
    for (int i = 0; i < 2; i++)
        #pragma unroll
        for (int j = 0; j < 2; j++)
            #pragma unroll
            for (int q = 0; q < 16; q++) acc[i][j][q] = 0.f;

    for (int kk = 0; kk < K; kk += KS){
        #pragma unroll
        for (int p = 0; p < 4; p++){
            int r = srow + p*32;
            const float* ga = A + (size_t)(row0 + r)*K + kk + sk8*8;
            float4 a0 = *(const float4*)ga;
            float4 a1 = *(const float4*)(ga + 4);
            half8_t ahi, alo;
            float av[8] = {a0.x,a0.y,a0.z,a0.w,a1.x,a1.y,a1.z,a1.w};
            #pragma unroll
            for (int q = 0; q < 8; q++){
                _Float16 h = (_Float16)av[q];
                ahi[q] = h; alo[q] = (_Float16)(av[q] - (float)h);
            }
            size_t wo = (size_t)(col0 + r)*K + kk + sk8*8;
            half8_t whi = *(const half8_t*)(WHp + wo);
            half8_t wlo = *(const half8_t*)(WLp + wo);
            int o = ldsoff(r, sk8);
            *(half8_t*)&sAH[o] = ahi;
            *(half8_t*)&sAL[o] = alo;
            *(half8_t*)&sWH[o] = whi;
            *(half8_t*)&sWL[o] = wlo;
        }
        __syncthreads();
        #pragma unroll
        for (int kc = 0; kc < 4; kc++){
            int k8 = kc*2 + (lane >> 5);
            int ra = wr*64 + (lane & 31);
            int rb = wc*64 + (lane & 31);
            half8_t ah0 = *(const half8_t*)&sAH[ldsoff(ra,      k8)];
            half8_t ah1 = *(const half8_t*)&sAH[ldsoff(ra + 32, k8)];
            half8_t al0 = *(const half8_t*)&sAL[ldsoff(ra,      k8)];
            half8_t al1 = *(const half8_t*)&sAL[ldsoff(ra + 32, k8)];
            half8_t bh0 = *(const half8_t*)&sWH[ldsoff(rb,      k8)];
            half8_t bh1 = *(const half8_t*)&sWH[ldsoff(rb + 32, k8)];
            half8_t bl0 = *(const half8_t*)&sWL[ldsoff(rb,      k8)];
            half8_t bl1 = *(const half8_t*)&sWL[ldsoff(rb + 32, k8)];
            acc[0][0] = __builtin_amdgcn_mfma_f32_32x32x16_f16(ah0, bh0, acc[0][0], 0,0,0);
            acc[0][0] = __builtin_amdgcn_mfma_f32_32x32x16_f16(ah0, bl0, acc[0][0], 0,0,0);
            acc[0][0] = __builtin_amdgcn_mfma_f32_32x32x16_f16(al0, bh0, acc[0][0], 0,0,0);
            acc[0][1] = __builtin_amdgcn_mfma_f32_32x32x16_f16(ah0, bh1, acc[0][1], 0,0,0);
            acc[0][1] = __builtin_amdgcn_mfma_f32_32x32x16_f16(ah0, bl1, acc[0][1], 0,0,0);
            acc[0][1] = __builtin_amdgcn_mfma_f32_32x32x16_f16(al0, bh1, acc[0][1], 0,0,0);
            acc[1][0] = __builtin_amdgcn_mfma_f32_32x32x16_f16(ah1, bh0, acc[1][0], 0,0,0);
            acc[1][0] = __builtin_amdgcn_mfma_f32_32x32x16_f16(ah1, bl0, acc[1][0], 0,0,0);
            acc[1][0] = __builtin_amdgcn_mfma_f32_32x32x16_f16(al1, bh0, acc[1][0], 0,0,0);
            acc[1][1] = __builtin_amdgcn_mfma_f32_32x32x16_f16(ah1, bh1, acc[1][1], 0,0,0);
            acc[1][1] = __builtin_amdgcn_mfma_f32_32x32x16_f16(ah1, bl1, acc[1][1], 0,0,0);
            acc[1][1] = __builtin_amdgcn_mfma_f32_32x32x16_f16(al1, bh1, acc[1][1], 0,0,0);
        }
        __syncthreads();
    }
    #pragma unroll
    for (int rt = 0; rt < 2; rt++)
        #pragma unroll
        for (int ct = 0; ct < 2; ct++){
            int baser = row0 + wr*64 + rt*32 + 4*(lane >> 5);
            int c = col0 + wc*64 + ct*32 + (lane & 31);
            #pragma unroll
            for (int r = 0; r < 16; r++){
                int rr = baser + (r & 3) + 8*(r >> 2);
                C[(size_t)rr*M + c] = acc[rt][ct][r];
            }
        }
}

// ---------------- GAT attention coefficients ----------------
__global__ void attn_pre(const float* __restrict__ h, const float* __restrict__ wsrc,
                         const float* __restrict__ wdst, float* __restrict__ as_,
                         float* __restrict__ ad_){
    int lane = threadIdx.x & 63;
    int w = threadIdx.x >> 6;
    int d = blockIdx.x*4 + w;
    float4 hv = *(const float4*)(h + (size_t)d*256 + lane*4);
    float4 ws = *(const float4*)(wsrc + lane*4);
    float4 wd = *(const float4*)(wdst + lane*4);
    float ps = hv.x*ws.x + hv.y*ws.y + hv.z*ws.z + hv.w*ws.w;
    float pd = hv.x*wd.x + hv.y*wd.y + hv.z*wd.z + hv.w*wd.w;
    #pragma unroll
    for (int m = 8; m; m >>= 1){ ps += __shfl_xor(ps, m); pd += __shfl_xor(pd, m); }
    if ((lane & 15) == 0){
        as_[d*4 + (lane >> 4)] = ps;
        ad_[d*4 + (lane >> 4)] = pd;
    }
}

// ---- GAT aggregation: no-max softmax, 8-wide pipeline ----
template<int RELU>
__global__ void gat_agg(const float* __restrict__ h, const float* __restrict__ as_,
                        const float* __restrict__ ad_, const float* __restrict__ bias,
                        const int2* __restrict__ rpx, const int* __restrict__ esrc,
                        float* __restrict__ out){
    int lane = threadIdx.x & 63;
    int w = threadIdx.x >> 6;
    int nb = gridDim.x;
    int b = blockIdx.x;
    int sb = (b & 7)*(nb >> 3) + (b >> 3);
    int d = sb*4 + w;
    int2 re = rpx[d];
    int beg = re.x, end = re.y;

    int hh = lane >> 4;
    int c0 = lane*4;
    float adh = ad_[(d<<2) + hh];
    float aself = as_[(d<<2) + hh];

    float dn[4];
    dn[0] = __expf(leaky(aself + adh)); dn[1] = 0.f; dn[2] = 0.f; dn[3] = 0.f;
    float4 hd = *(const float4*)(h + (d<<8) + c0);
    float4 AX[4];
    AX[0].x = dn[0]*hd.x; AX[0].y = dn[0]*hd.y; AX[0].z = dn[0]*hd.z; AX[0].w = dn[0]*hd.w;
    AX[1] = {0,0,0,0}; AX[2] = {0,0,0,0}; AX[3] = {0,0,0,0};

    int i = beg;
    int endu = beg + ((end - beg) & ~7);
    for (; i < endu; i += 8){
        int s_[8];
        #pragma unroll
        for (int j = 0; j < 8; j++) s_[j] = esrc[i + j];
        float a_[8];
        #pragma unroll
        for (int j = 0; j < 8; j++) a_[j] = as_[(s_[j]<<2) + hh];
        float4 hv_[8];
        #pragma unroll
        for (int j = 0; j < 8; j++) hv_[j] = *(const float4*)(h + (s_[j]<<8) + c0);
        #pragma unroll
        for (int j = 0; j < 8; j++){
            float x = a_[j] + adh;
            float p = __expf(fmaxf(x, 0.2f*x));
            dn[j & 3] += p;
            AX[j & 3].x = fmaf(p, hv_[j].x, AX[j & 3].x);
            AX[j & 3].y = fmaf(p, hv_[j].y, AX[j & 3].y);
            AX[j & 3].z = fmaf(p, hv_[j].z, AX[j & 3].z);
            AX[j & 3].w = fmaf(p, hv_[j].w, AX[j & 3].w);
        }
    }
    for (; i < end; ++i){
        int s = esrc[i];
        float x = as_[(s<<2) + hh] + adh;
        float4 hv = *(const float4*)(h + (s<<8) + c0);
        float p = __expf(fmaxf(x, 0.2f*x));
        dn[0] += p;
        AX[0].x = fmaf(p, hv.x, AX[0].x); AX[0].y = fmaf(p, hv.y, AX[0].y);
        AX[0].z = fmaf(p, hv.z, AX[0].z); AX[0].w = fmaf(p, hv.w, AX[0].w);
    }
    float den = ((dn[0] + dn[1]) + (dn[2] + dn[3])) + 1e-16f;
    float r = 1.0f / den;
    float4 bv = *(const float4*)(bias + c0);
    float4 acc;
    acc.x = ((AX[0].x+AX[1].x)+(AX[2].x+AX[3].x))*r + bv.x;
    acc.y = ((AX[0].y+AX[1].y)+(AX[2].y+AX[3].y))*r + bv.y;
    acc.z = ((AX[0].z+AX[1].z)+(AX[2].z+AX[3].z))*r + bv.z;
    acc.w = ((AX[0].w+AX[1].w)+(AX[2].w+AX[3].w))*r + bv.w;
    if (RELU){
        acc.x = fmaxf(acc.x, 0.f); acc.y = fmaxf(acc.y, 0.f);
        acc.z = fmaxf(acc.z, 0.f); acc.w = fmaxf(acc.w, 0.f);
    }
    *(float4*)(out + (d<<8) + c0) = acc;
}

// ---- GCN aggregation + fused SAG-score partial dots ----
__global__ void gcn_agg_sag(const float* __restrict__ h, const float* __restrict__ dinv,
                            const float* __restrict__ bias,
                            const float* __restrict__ wrel, const float* __restrict__ wroot,
                            const float* __restrict__ brel,
                            const int2* __restrict__ rpx, const int* __restrict__ esrc,
                            float* __restrict__ out, float* __restrict__ Y, float* __restrict__ Z){
    int lane = threadIdx.x & 63;
    int w = threadIdx.x >> 6;
    int nb = gridDim.x;
    int b = blockIdx.x;
    int sb = (b & 7)*(nb >> 3) + (b >> 3);
    int d = sb*4 + w;
    int2 re = rpx[d];
    int beg = re.x, end = re.y;
    float dv = dinv[d];
    int c0 = lane*2;
    float2 hd = *(const float2*)(h + (d<<7) + c0);
    float self = dv*dv;
    float ax[4] = {self*hd.x, 0.f, 0.f, 0.f};
    float ay[4] = {self*hd.y, 0.f, 0.f, 0.f};
    int i = beg;
    int endu = beg + ((end - beg) & ~7);
    for (; i < endu; i += 8){
        int s_[8];
        #pragma unroll
        for (int j = 0; j < 8; j++) s_[j] = esrc[i + j];
        float di_[8];
        #pragma unroll
        for (int j = 0; j < 8; j++) di_[j] = dinv[s_[j]];
        float2 hv_[8];
        #pragma unroll
        for (int j = 0; j < 8; j++) hv_[j] = *(const float2*)(h + (s_[j]<<7) + c0);
        #pragma unroll
        for (int j = 0; j < 8; j++){
            float coef = di_[j]*dv;
            ax[j & 3] = fmaf(coef, hv_[j].x, ax[j & 3]);
            ay[j & 3] = fmaf(coef, hv_[j].y, ay[j & 3]);
        }
    }
    for (; i < end; ++i){
        int s = esrc[i];
        float coef = dinv[s]*dv;
        float2 hv = *(const float2*)(h + (s<<7) + c0);
        ax[0] = fmaf(coef, hv.x, ax[0]); ay[0] = fmaf(coef, hv.y, ay[0]);
    }
    float axs = ((ax[0]+ax[1])+(ax[2]+ax[3]));
    float ays = ((ay[0]+ay[1])+(ay[2]+ay[3]));
    axs = fmaxf(axs + bias[c0], 0.f);
    ays = fmaxf(ays + bias[c0+1], 0.f);
    float2 o; o.x = axs; o.y = ays;
    *(float2*)(out + (d<<7) + c0) = o;
    float py = axs*wrel[c0]  + ays*wrel[c0+1];
    float pz = axs*wroot[c0] + ays*wroot[c0+1];
    #pragma unroll
    for (int off = 32; off; off >>= 1){ py += __shfl_xor(py, off); pz += __shfl_xor(pz, off); }
    if (lane == 0){ Y[d] = py; Z[d] = pz + brel[0]; }
}

// ---------------- SAG score via scalar gather ----------------
__global__ void sag_lite(const float* __restrict__ Y, const float* __restrict__ Z,
                         const int2* __restrict__ rpx, const int* __restrict__ esrc,
                         float* __restrict__ score){
    int lane = threadIdx.x & 63;
    int w = threadIdx.x >> 6;
    int nb = gridDim.x;
    int b = blockIdx.x;
    int sb = (b & 7)*(nb >> 3) + (b >> 3);
    int d = sb*4 + w;
    int2 re = rpx[d];
    float s = 0.f;
    for (int i = re.x + lane; i < re.y; i += 64) s += Y[esrc[i]];
    #pragma unroll
    for (int off = 32; off; off >>= 1) s += __shfl_xor(s, off);
    if (lane == 0) score[d] = s + Z[d];
}

// ---------------- radix-select top-k ----------------
__global__ __launch_bounds__(1024) void topk_sel(const float* __restrict__ score,
        int npg, int k, int* __restrict__ perm, float* __restrict__ ssort,
        int* __restrict__ nid, int writeNid){
    __shared__ unsigned keys[2048];
    __shared__ int hist[256];
    __shared__ int cge[256];
    __shared__ int warpsum[16];
    __shared__ int s_bin, s_need;
    int g = blockIdx.x, tid = threadIdx.x;
    for (int i = tid; i < npg; i += 1024){
        unsigned u = __float_as_uint(score[g*npg + i]);
        u = (u & 0x80000000u) ? ~u : (u | 0x80000000u);
        keys[i] = u;
    }
    if (tid == 0) s_need = k;
    __syncthreads();
    unsigned prefix = 0u, pmask = 0u;
    #pragma unroll
    for (int shift = 24; shift >= 0; shift -= 8){
        if (tid < 256) hist[tid] = 0;
        __syncthreads();
        for (int i = tid; i < npg; i += 1024){
            unsigned u = keys[i];
            if ((u & pmask) == prefix) atomicAdd(&hist[(u >> shift) & 255u], 1);
        }
        __syncthreads();
        if (tid < 256) cge[tid] = hist[tid];
        __syncthreads();
        for (int off = 1; off < 256; off <<= 1){
            int v = 0;
            if (tid < 256 - off) v = cge[tid + off];
            __syncthreads();
            if (tid < 256) cge[tid] += v;
            __syncthreads();
        }
        int need = s_need;
        if (tid < 256){
            int above = (tid == 255) ? 0 : cge[tid + 1];
            if (cge[tid] >= need && above < need) s_bin = tid;
        }
        __syncthreads();
        if (tid == 0) s_need = need - ((s_bin == 255) ? 0 : cge[s_bin + 1]);
        __syncthreads();
        prefix |= ((unsigned)s_bin) << shift;
        pmask  |= (255u << shift);
        __syncthreads();
    }
    unsigned thr = prefix;
    int m = s_need;
    int i0 = 2*tid, i1 = 2*tid + 1;
    int f0 = 0, f1 = 0;
    if (i0 < npg){
        unsigned u = keys[i0];
        if (u > thr) f0 = 1;
        else if (u == thr){
            int r = 0;
            for (int j = 0; j < i0; j++) r += (keys[j] == thr);
            f0 = (r < m) ? 1 : 0;
        }
    }
    if (i1 < npg){
        unsigned u = keys[i1];
        if (u > thr) f1 = 1;
        else if (u == thr){
            int r = 0;
            for (int j = 0; j < i1; j++) r += (keys[j] == thr);
            f1 = (r < m) ? 1 : 0;
        }
    }
    int pair = f0 + f1;
    int lane = tid & 63, wv = tid >> 6;
    int x = pair;
    #pragma unroll
    for (int off = 1; off < 64; off <<= 1){ int y = __shfl_up(x, off); if (lane >= off) x += y; }
    if (lane == 63) warpsum[wv] = x;
    __syncthreads();
    if (tid == 0){ int run = 0; for (int w2 = 0; w2 < 16; w2++){ int t = warpsum[w2]; warpsum[w2] = run; run += t; } }
    __syncthreads();
    int excl = x - pair + warpsum[wv];
    if (f0){
        int pos = excl;
        int node = g*npg + i0;
        perm[g*k + pos] = node;
        ssort[g*k + pos] = score[node];
        if (writeNid) nid[node] = g*k + pos;
    }
    if (f1){
        int pos = excl + f0;
        int node = g*npg + i1;
        perm[g*k + pos] = node;
        ssort[g*k + pos] = score[node];
        if (writeNid) nid[node] = g*k + pos;
    }
}

__global__ void pool_gather(const float* __restrict__ x, const int* __restrict__ perm,
                            const float* __restrict__ ssort, float* __restrict__ xn){
    int j = blockIdx.x; int c = threadIdx.x;
    int o = perm[j];
    float t = tanhf(ssort[j]);
    xn[(size_t)j*128 + c] = x[(size_t)o*128 + c] * t;
}

__global__ void pool_mean2(const float* __restrict__ x, const int* __restrict__ perm,
                           const float* __restrict__ ssort, float* __restrict__ g){
    __shared__ float tt[KK2];
    __shared__ float part[128];
    int b = blockIdx.x, t = threadIdx.x;     // 256 threads
    tt[t]       = tanhf(ssort[b*KK2 + t]);
    tt[t + 256] = tanhf(ssort[b*KK2 + t + 256]);
    __syncthreads();
    int c = t & 127, half = t >> 7;
    float s = 0.f;
    #pragma unroll 4
    for (int i = half*256; i < half*256 + 256; i++){
        int o = perm[b*KK2 + i];
        s = fmaf(tt[i], x[(size_t)o*128 + c], s);
    }
    if (half) part[c] = s;
    __syncthreads();
    if (!half) g[b*128 + c] = (s + part[c]) * (1.0f/KK2);
}

__global__ void mlp_k(const float* __restrict__ g,
                      const float* __restrict__ fc1w, const float* __restrict__ fc1b,
                      const float* __restrict__ fc2w, const float* __restrict__ fc2b,
                      const float* __restrict__ ow,  const float* __restrict__ ob,
                      float* __restrict__ out){
    __shared__ float gv[128], t1[256], t2[128];
    int b = blockIdx.x, t = threadIdx.x;
    if (t < 128) gv[t] = g[b*128 + t];
    __syncthreads();
    {
        float s = fc1b[t];
        for (int c = 0; c < 128; c++) s += gv[c]*fc1w[t*128 + c];
        t1[t] = fmaxf(s, 0.f);
    }
    __syncthreads();
    if (t < 128){
        float s = fc2b[t];
        for (int c = 0; c < 256; c++) s += t1[c]*fc2w[t*256 + c];
        t2[t] = fmaxf(s, 0.f);
    }
    __syncthreads();
    if (t < 10){
        float s = ob[t];
        for (int c = 0; c < 128; c++) s += t2[c]*ow[t*128 + c];
        out[b*10 + t] = s;
    }
}

// ---------------- launch ----------------
extern "C" void kernel_launch(void* const* d_in, const int* in_sizes, int n_in,
                              void* d_out, int out_size, void* d_ws, size_t ws_size,
                              hipStream_t stream){
    (void)in_sizes; (void)n_in; (void)out_size; (void)ws_size;
    const float* x    = (const float*)d_in[0];
    const int*   eidx = (const int*)d_in[1];
    const int*   src  = eidx;
    const int*   dst  = eidx + EE;
    const float* g1w  = (const float*)d_in[3];
    const float* g1as = (const float*)d_in[4];
    const float* g1ad = (const float*)d_in[5];
    const float* g1b  = (const float*)d_in[6];
    const float* g2w  = (const float*)d_in[7];
    const float* g2as = (const float*)d_in[8];
    const float* g2ad = (const float*)d_in[9];
    const float* g2b  = (const float*)d_in[10];
    const float* c1w  = (const float*)d_in[11];
    const float* c1b  = (const float*)d_in[12];
    const float* s1wrel  = (const float*)d_in[13];
    const float* s1brel  = (const float*)d_in[14];
    const float* s1wroot = (const float*)d_in[15];
    const float* c2w  = (const float*)d_in[16];
    const float* c2b  = (const float*)d_in[17];
    const float* s2wrel  = (const float*)d_in[18];
    const float* s2brel  = (const float*)d_in[19];
    const float* s2wroot = (const float*)d_in[20];
    const float* f1w  = (const float*)d_in[21];
    const float* f1b  = (const float*)d_in[22];
    const float* f2w  = (const float*)d_in[23];
    const float* f2b  = (const float*)d_in[24];
    const float* ow   = (const float*)d_in[25];
    const float* ob   = (const float*)d_in[26];
    float* out = (float*)d_out;

    char* ws = (char*)d_ws;
    size_t off = 0;
    auto alloc = [&](size_t bytes)->char*{
        char* p = ws + off;
        off += (bytes + 255) & ~(size_t)255;
        return p;
    };
    float* F0     = (float*)alloc((size_t)N1*256*4);
    float* F1     = (float*)alloc((size_t)N1*256*4);
    float* F2     = (float*)alloc((size_t)N2*128*4);
    float* AS     = (float*)alloc((size_t)N1*4*4);
    float* AD     = (float*)alloc((size_t)N1*4*4);
    int2*  RPX    = (int2*) alloc((size_t)N1*8);
    int*   CUR    = (int*)  alloc((size_t)N1*4);
    int*   EL     = (int*)  alloc((size_t)EE*4);
    float* DINV   = (float*)alloc((size_t)N1*4);
    float* SCORE  = (float*)alloc((size_t)N1*4);
    float* Y      = (float*)alloc((size_t)N1*4);
    float* Z      = (float*)alloc((size_t)N1*4);
    int*   PERM1  = (int*)  alloc((size_t)N2*4);
    float* SSORT1 = (float*)alloc((size_t)N2*4);
    int*   NID    = (int*)  alloc((size_t)N1*4);
    int*   E1S    = (int*)  alloc((size_t)EE*4);
    int*   E1D    = (int*)  alloc((size_t)EE*4);
    int2*  RPX2   = (int2*) alloc((size_t)N2*8);
    int*   CUR2   = (int*)  alloc((size_t)N2*4);
    int*   EL2    = (int*)  alloc((size_t)EE*4);
    float* DINV2  = (float*)alloc((size_t)N2*4);
    int*   PERM2  = (int*)  alloc((size_t)N3*4);
    float* SSORT2 = (float*)alloc((size_t)N3*4);
    float* GBUF   = (float*)alloc((size_t)NB*128*4);
    int*   BS     = (int*)  alloc((size_t)128*4);
    _Float16* WH  = (_Float16*)alloc((size_t)131072*2);
    _Float16* WL  = (_Float16*)alloc((size_t)131072*2);
    const int o_g1 = 0, o_g2 = 16384, o_c1 = 81920, o_c2 = 114688;

    // ---- level-1 CSR (wide) + weight pre-split ----
    hipMemsetAsync(CUR, 0, (size_t)N1*4, stream);
    count_dst<<<EE/256, 256, 0, stream>>>(dst, CUR, EE);
    blocksum_k<<<N1/256, 256, 0, stream>>>(CUR, BS);
    scan_write_k<<<N1/256, 256, 0, stream>>>(CUR, BS, N1/256, RPX, CUR, DINV);
    scatter1<<<EE/256, 256, 0, stream>>>(src, dst, CUR, EL, EE);
    wsplit4<<<512, 256, 0, stream>>>(g1w, 16384, g2w, 65536, c1w, 32768, c2w, 16384, WH, WL);

    // ---- GAT layer 1 (64 -> 4x64, relu) ----
    gemm_h2<<<dim3(N1/128, 2), 256, 0, stream>>>(x, WH + o_g1, WL + o_g1, F0, N1, 64, 256);
    attn_pre<<<N1/4, 256, 0, stream>>>(F0, g1as, g1ad, AS, AD);
    gat_agg<1><<<N1/4, 256, 0, stream>>>(F0, AS, AD, g1b, RPX, EL, F1);

    // ---- GAT layer 2 (256 -> 4x64) ----
    gemm_h2<<<dim3(N1/128, 2), 256, 0, stream>>>(F1, WH + o_g2, WL + o_g2, F0, N1, 256, 256);
    attn_pre<<<N1/4, 256, 0, stream>>>(F0, g2as, g2ad, AS, AD);
    gat_agg<0><<<N1/4, 256, 0, stream>>>(F0, AS, AD, g2b, RPX, EL, F1);

    // ---- GCN1 (256 -> 128, relu) + fused SAG1 partial dots ----
    gemm_h2<<<dim3(N1/128, 1), 256, 0, stream>>>(F1, WH + o_c1, WL + o_c1, F0, N1, 256, 128);
    gcn_agg_sag<<<N1/4, 256, 0, stream>>>(F0, DINV, c1b, s1wrel, s1wroot, s1brel,
                                          RPX, EL, F1, Y, Z);

    // ---- SAGPool1 ----
    sag_lite<<<N1/4, 256, 0, stream>>>(Y, Z, RPX, EL, SCORE);
    hipMemsetAsync(NID, 0xFF, (size_t)N1*4, stream);   // -1
    topk_sel<<<NB, 1024, 0, stream>>>(SCORE, NPG1, KK1, PERM1, SSORT1, NID, 1);
    pool_gather<<<N2, 128, 0, stream>>>(F1, PERM1, SSORT1, F0);          // x2 -> F0

    // ---- level-2 CSR (wide; remap + count fused) ----
    hipMemsetAsync(CUR2, 0, (size_t)N2*4, stream);
    remap_count<<<EE/256, 256, 0, stream>>>(src, dst, NID, E1S, E1D, CUR2, EE);
    blocksum_k<<<N2/256, 256, 0, stream>>>(CUR2, BS);
    scan_write_k<<<N2/256, 256, 0, stream>>>(CUR2, BS, N2/256, RPX2, CUR2, DINV2);
    scatter2<<<EE/256, 256, 0, stream>>>(E1S, E1D, CUR2, EL2, EE);

    // ---- GCN2 (128 -> 128, relu) + fused SAG2 partial dots ----
    gemm_h2<<<dim3(N2/128, 1), 256, 0, stream>>>(F0, WH + o_c2, WL + o_c2, F1, N2, 128, 128);
    gcn_agg_sag<<<N2/4, 256, 0, stream>>>(F1, DINV2, c2b, s2wrel, s2wroot, s2brel,
                                          RPX2, EL2, F2, Y, Z);

    // ---- SAGPool2 ----
    sag_lite<<<N2/4, 256, 0, stream>>>(Y, Z, RPX2, EL2, SCORE);
    topk_sel<<<NB, 1024, 0, stream>>>(SCORE, NPG2, KK2, PERM2, SSORT2, nullptr, 0);

    // ---- fused gather + mean pool + MLP ----
    pool_mean2<<<NB, 256, 0, stream>>>(F2, PERM2, SSORT2, GBUF);
    mlp_k<<<NB, 256, 0, stream>>>(GBUF, f1w, f1b, f2w, f2b, ow, ob, out);
}

// Round 10
// 358.231 us; speedup vs baseline: 2.1351x; 1.0564x over previous
//
#include <hip/hip_runtime.h>

#define N1 32768
#define EE 524288
#define NB 16
#define DEG 16
#define NPG1 2048
#define KK1 1024
#define N2 16384
#define NPG2 1024
#define KK2 512
#define N3 8192

typedef _Float16 half8_t __attribute__((ext_vector_type(8)));
typedef float floatx16 __attribute__((ext_vector_type(16)));

static __device__ __forceinline__ float leaky(float x){ return fmaxf(x, 0.2f*x); }

// ---------------- CSR build (wide multi-kernel) ----------------
__global__ void count_dst(const int* __restrict__ dst, int* __restrict__ cnt, int E){
    int i = blockIdx.x*blockDim.x + threadIdx.x;
    if (i < E) atomicAdd(&cnt[dst[i]], 1);
}

__global__ void remap_count(const int* __restrict__ src, const int* __restrict__ dst,
                            const int* __restrict__ nid, int* __restrict__ ns,
                            int* __restrict__ nd, int* __restrict__ cnt, int E){
    int i = blockIdx.x*blockDim.x + threadIdx.x;
    if (i < E){
        int a = nid[src[i]], b = nid[dst[i]];
        ns[i] = a; nd[i] = b;
        if (a >= 0 && b >= 0) atomicAdd(&cnt[b], 1);
    }
}

__global__ void blocksum_k(const int* __restrict__ cnt, int* __restrict__ bs){
    __shared__ int red[4];
    int tid = threadIdx.x;
    int v = cnt[blockIdx.x*256 + tid];
    #pragma unroll
    for (int off = 32; off; off >>= 1) v += __shfl_xor(v, off);
    if ((tid & 63) == 0) red[tid >> 6] = v;
    __syncthreads();
    if (tid == 0) bs[blockIdx.x] = red[0] + red[1] + red[2] + red[3];
}

__global__ void scan_write_k(const int* __restrict__ cnt, const int* __restrict__ bs,
                             int nb, int2* __restrict__ rpx, int* __restrict__ cur,
                             float* __restrict__ dinv){
    __shared__ int sbs[128];
    __shared__ int wsum[4];
    int tid = threadIdx.x;
    int b = blockIdx.x;
    if (tid < nb) sbs[tid] = bs[tid];
    __syncthreads();
    for (int off = 1; off < nb; off <<= 1){
        int v = 0;
        if (tid < nb && tid >= off) v = sbs[tid - off];
        __syncthreads();
        if (tid < nb) sbs[tid] += v;
        __syncthreads();
    }
    int base = (b == 0) ? 0 : sbs[b-1];
    int i = b*256 + tid;
    int c = cnt[i];
    int lane = tid & 63, wv = tid >> 6;
    int x = c;
    #pragma unroll
    for (int off = 1; off < 64; off <<= 1){ int y = __shfl_up(x, off); if (lane >= off) x += y; }
    if (lane == 63) wsum[wv] = x;
    __syncthreads();
    if (tid == 0){ int run = 0; for (int w2 = 0; w2 < 4; w2++){ int t = wsum[w2]; wsum[w2] = run; run += t; } }
    __syncthreads();
    int excl = x - c + wsum[wv];
    int beg = base + excl;
    rpx[i]  = make_int2(beg, beg + c);
    cur[i]  = beg;
    dinv[i] = rsqrtf((float)c + 1.0f);
}

__global__ void scatter1(const int* __restrict__ src, const int* __restrict__ dst,
                         int* __restrict__ cur, int* __restrict__ esrc, int E){
    int i = blockIdx.x*blockDim.x + threadIdx.x;
    if (i < E){ int p = atomicAdd(&cur[dst[i]], 1); esrc[p] = src[i]; }
}

__global__ void scatter2(const int* __restrict__ ns, const int* __restrict__ nd,
                         int* __restrict__ cur, int* __restrict__ esrc, int E){
    int i = blockIdx.x*blockDim.x + threadIdx.x;
    if (i < E){
        int a = ns[i], b = nd[i];
        if (a >= 0 && b >= 0){ int p = atomicAdd(&cur[b], 1); esrc[p] = a; }
    }
}

// ---------------- weight pre-split (fp32 -> fp16 hi/lo) ----------------
__global__ void wsplit4(const float* __restrict__ w0, int n0,
                        const float* __restrict__ w1, int n1,
                        const float* __restrict__ w2, int n2,
                        const float* __restrict__ w3, int n3,
                        _Float16* __restrict__ wh, _Float16* __restrict__ wl){
    int i = blockIdx.x*256 + threadIdx.x;
    int n01 = n0 + n1, n012 = n01 + n2, nt = n012 + n3;
    if (i >= nt) return;
    float v = (i < n0) ? w0[i] : (i < n01) ? w1[i - n0] : (i < n012) ? w2[i - n01] : w3[i - n012];
    _Float16 h = (_Float16)v;
    wh[i] = h; wl[i] = (_Float16)(v - (float)h);
}

// ------------- split-fp16 MFMA GEMM: C = A @ W^T (fp32 A, pre-split W) ------
// optional row-gather + scale on A (perm != nullptr): A_eff[r] = A[perm[r]] * tt[r]
#define KS 64
static __device__ __forceinline__ int ldsoff(int row, int k8){
    return row*64 + ((k8 ^ (row & 7)) << 3);
}

__global__ __launch_bounds__(256, 2) void gemm_h2(const float* __restrict__ A,
        const _Float16* __restrict__ WHp, const _Float16* __restrict__ WLp,
        float* __restrict__ C, int n, int K, int M,
        const int* __restrict__ perm, const float* __restrict__ tt){
    __shared__ _Float16 sm[4*128*KS];
    _Float16* sAH = sm;
    _Float16* sAL = sm + 128*KS;
    _Float16* sWH = sm + 2*128*KS;
    _Float16* sWL = sm + 3*128*KS;
    int t = threadIdx.x;
    int lane = t & 63;
    int wid = t >> 6;
    int wr = wid >> 1, wc = wid & 1;
    int row0 = blockIdx.x*128, col0 = blockIdx.y*128;
    int srow = t >> 3;
    int sk8  = t & 7;

    floatx16 acc[2][2];
    #pragma unroll
    for (int i = 0; i < 2; i++)
        #pragma unroll
        for (int j = 0; j < 2; j++)
            #pragma unroll
            for (int q = 0; q < 16; q++) acc[i][j][q] = 0.f;

    for (int kk = 0; kk < K; kk += KS){
        #pragma unroll
        for (int p = 0; p < 4; p++){
            int r = srow + p*32;
            int rr = row0 + r;
            int arow = perm ? perm[rr] : rr;
            float tscale = perm ? tt[rr] : 1.0f;
            const float* ga = A + (size_t)arow*K + kk + sk8*8;
            float4 a0 = *(const float4*)ga;
            float4 a1 = *(const float4*)(ga + 4);
            half8_t ahi, alo;
            float av[8] = {a0.x,a0.y,a0.z,a0.w,a1.x,a1.y,a1.z,a1.w};
            #pragma unroll
            for (int q = 0; q < 8; q++){
                float v = av[q] * tscale;
                _Float16 h = (_Float16)v;
                ahi[q] = h; alo[q] = (_Float16)(v - (float)h);
            }
            size_t wo = (size_t)(col0 + r)*K + kk + sk8*8;
            half8_t whi = *(const half8_t*)(WHp + wo);
            half8_t wlo = *(const half8_t*)(WLp + wo);
            int o = ldsoff(r, sk8);
            *(half8_t*)&sAH[o] = ahi;
            *(half8_t*)&sAL[o] = alo;
            *(half8_t*)&sWH[o] = whi;
            *(half8_t*)&sWL[o] = wlo;
        }
        __syncthreads();
        #pragma unroll
        for (int kc = 0; kc < 4; kc++){
            int k8 = kc*2 + (lane >> 5);
            int ra = wr*64 + (lane & 31);
            int rb = wc*64 + (lane & 31);
            half8_t ah0 = *(const half8_t*)&sAH[ldsoff(ra,      k8)];
            half8_t ah1 = *(const half8_t*)&sAH[ldsoff(ra + 32, k8)];
            half8_t al0 = *(const half8_t*)&sAL[ldsoff(ra,      k8)];
            half8_t al1 = *(const half8_t*)&sAL[ldsoff(ra + 32, k8)];
            half8_t bh0 = *(const half8_t*)&sWH[ldsoff(rb,      k8)];
            half8_t bh1 = *(const half8_t*)&sWH[ldsoff(rb + 32, k8)];
            half8_t bl0 = *(const half8_t*)&sWL[ldsoff(rb,      k8)];
            half8_t bl1 = *(const half8_t*)&sWL[ldsoff(rb + 32, k8)];
            acc[0][0] = __builtin_amdgcn_mfma_f32_32x32x16_f16(ah0, bh0, acc[0][0], 0,0,0);
            acc[0][0] = __builtin_amdgcn_mfma_f32_32x32x16_f16(ah0, bl0, acc[0][0], 0,0,0);
            acc[0][0] = __builtin_amdgcn_mfma_f32_32x32x16_f16(al0, bh0, acc[0][0], 0,0,0);
            acc[0][1] = __builtin_amdgcn_mfma_f32_32x32x16_f16(ah0, bh1, acc[0][1], 0,0,0);
            acc[0][1] = __builtin_amdgcn_mfma_f32_32x32x16_f16(ah0, bl1, acc[0][1], 0,0,0);
            acc[0][1] = __builtin_amdgcn_mfma_f32_32x32x16_f16(al0, bh1, acc[0][1], 0,0,0);
            acc[1][0] = __builtin_amdgcn_mfma_f32_32x32x16_f16(ah1, bh0, acc[1][0], 0,0,0);
            acc[1][0] = __builtin_amdgcn_mfma_f32_32x32x16_f16(ah1, bl0, acc[1][0], 0,0,0);
            acc[1][0] = __builtin_amdgcn_mfma_f32_32x32x16_f16(al1, bh0, acc[1][0], 0,0,0);
            acc[1][1] = __builtin_amdgcn_mfma_f32_32x32x16_f16(ah1, bh1, acc[1][1], 0,0,0);
            acc[1][1] = __builtin_amdgcn_mfma_f32_32x32x16_f16(ah1, bl1, acc[1][1], 0,0,0);
            acc[1][1] = __builtin_amdgcn_mfma_f32_32x32x16_f16(al1, bh1, acc[1][1], 0,0,0);
        }
        __syncthreads();
    }
    #pragma unroll
    for (int rt = 0; rt < 2; rt++)
        #pragma unroll
        for (int ct = 0; ct < 2; ct++){
            int baser = row0 + wr*64 + rt*32 + 4*(lane >> 5);
            int c = col0 + wc*64 + ct*32 + (lane & 31);
            #pragma unroll
            for (int r = 0; r < 16; r++){
                int rr = baser + (r & 3) + 8*(r >> 2);
                C[(size_t)rr*M + c] = acc[rt][ct][r];
            }
        }
}

// ---------------- GAT attention coefficients ----------------
__global__ void attn_pre(const float* __restrict__ h, const float* __restrict__ wsrc,
                         const float* __restrict__ wdst, float* __restrict__ as_,
                         float* __restrict__ ad_){
    int lane = threadIdx.x & 63;
    int w = threadIdx.x >> 6;
    int d = blockIdx.x*4 + w;
    float4 hv = *(const float4*)(h + (size_t)d*256 + lane*4);
    float4 ws = *(const float4*)(wsrc + lane*4);
    float4 wd = *(const float4*)(wdst + lane*4);
    float ps = hv.x*ws.x + hv.y*ws.y + hv.z*ws.z + hv.w*ws.w;
    float pd = hv.x*wd.x + hv.y*wd.y + hv.z*wd.z + hv.w*wd.w;
    #pragma unroll
    for (int m = 8; m; m >>= 1){ ps += __shfl_xor(ps, m); pd += __shfl_xor(pd, m); }
    if ((lane & 15) == 0){
        as_[d*4 + (lane >> 4)] = ps;
        ad_[d*4 + (lane >> 4)] = pd;
    }
}

// ---- GAT aggregation: no-max softmax, 8-wide pipeline, scalarized node ids --
template<int RELU>
__global__ void gat_agg(const float* __restrict__ h, const float* __restrict__ as_,
                        const float* __restrict__ ad_, const float* __restrict__ bias,
                        const int2* __restrict__ rpx, const int* __restrict__ esrc,
                        float* __restrict__ out){
    int lane = threadIdx.x & 63;
    int nb = gridDim.x;
    int b = blockIdx.x;
    int sb = (b & 7)*(nb >> 3) + (b >> 3);
    int d = __builtin_amdgcn_readfirstlane(sb*4 + (int)(threadIdx.x >> 6));
    int2 re = rpx[d];
    int beg = re.x, end = re.y;

    int hh = lane >> 4;
    float adh = ad_[(d<<2) + hh];
    float aself = as_[(d<<2) + hh];

    float dn[4];
    dn[0] = __expf(leaky(aself + adh)); dn[1] = 0.f; dn[2] = 0.f; dn[3] = 0.f;
    float4 hd = ((const float4*)(h + ((size_t)d<<8)))[lane];
    float4 AX[4];
    AX[0].x = dn[0]*hd.x; AX[0].y = dn[0]*hd.y; AX[0].z = dn[0]*hd.z; AX[0].w = dn[0]*hd.w;
    AX[1] = {0,0,0,0}; AX[2] = {0,0,0,0}; AX[3] = {0,0,0,0};

    int i = beg;
    int endu = beg + ((end - beg) & ~7);
    for (; i < endu; i += 8){
        int s_[8];
        #pragma unroll
        for (int j = 0; j < 8; j++) s_[j] = __builtin_amdgcn_readfirstlane(esrc[i + j]);
        float a_[8];
        #pragma unroll
        for (int j = 0; j < 8; j++) a_[j] = as_[(s_[j]<<2) + hh];
        float4 hv_[8];
        #pragma unroll
        for (int j = 0; j < 8; j++) hv_[j] = ((const float4*)(h + ((size_t)s_[j]<<8)))[lane];
        #pragma unroll
        for (int j = 0; j < 8; j++){
            float x = a_[j] + adh;
            float p = __expf(fmaxf(x, 0.2f*x));
            dn[j & 3] += p;
            AX[j & 3].x = fmaf(p, hv_[j].x, AX[j & 3].x);
            AX[j & 3].y = fmaf(p, hv_[j].y, AX[j & 3].y);
            AX[j & 3].z = fmaf(p, hv_[j].z, AX[j & 3].z);
            AX[j & 3].w = fmaf(p, hv_[j].w, AX[j & 3].w);
        }
    }
    for (; i < end; ++i){
        int s = __builtin_amdgcn_readfirstlane(esrc[i]);
        float x = as_[(s<<2) + hh] + adh;
        float4 hv = ((const float4*)(h + ((size_t)s<<8)))[lane];
        float p = __expf(fmaxf(x, 0.2f*x));
        dn[0] += p;
        AX[0].x = fmaf(p, hv.x, AX[0].x); AX[0].y = fmaf(p, hv.y, AX[0].y);
        AX[0].z = fmaf(p, hv.z, AX[0].z); AX[0].w = fmaf(p, hv.w, AX[0].w);
    }
    float den = ((dn[0] + dn[1]) + (dn[2] + dn[3])) + 1e-16f;
    float r = 1.0f / den;
    int c0 = lane*4;
    float4 bv = *(const float4*)(bias + c0);
    float4 acc;
    acc.x = ((AX[0].x+AX[1].x)+(AX[2].x+AX[3].x))*r + bv.x;
    acc.y = ((AX[0].y+AX[1].y)+(AX[2].y+AX[3].y))*r + bv.y;
    acc.z = ((AX[0].z+AX[1].z)+(AX[2].z+AX[3].z))*r + bv.z;
    acc.w = ((AX[0].w+AX[1].w)+(AX[2].w+AX[3].w))*r + bv.w;
    if (RELU){
        acc.x = fmaxf(acc.x, 0.f); acc.y = fmaxf(acc.y, 0.f);
        acc.z = fmaxf(acc.z, 0.f); acc.w = fmaxf(acc.w, 0.f);
    }
    ((float4*)(out + ((size_t)d<<8)))[lane] = acc;
}

// ---- GCN aggregation + fused SAG-score partial dots, scalarized node ids ----
__global__ void gcn_agg_sag(const float* __restrict__ h, const float* __restrict__ dinv,
                            const float* __restrict__ bias,
                            const float* __restrict__ wrel, const float* __restrict__ wroot,
                            const float* __restrict__ brel,
                            const int2* __restrict__ rpx, const int* __restrict__ esrc,
                            float* __restrict__ out, float* __restrict__ Y, float* __restrict__ Z){
    int lane = threadIdx.x & 63;
    int nb = gridDim.x;
    int b = blockIdx.x;
    int sb = (b & 7)*(nb >> 3) + (b >> 3);
    int d = __builtin_amdgcn_readfirstlane(sb*4 + (int)(threadIdx.x >> 6));
    int2 re = rpx[d];
    int beg = re.x, end = re.y;
    float dv = dinv[d];
    int c0 = lane*2;
    float2 hd = ((const float2*)(h + ((size_t)d<<7)))[lane];
    float self = dv*dv;
    float ax[4] = {self*hd.x, 0.f, 0.f, 0.f};
    float ay[4] = {self*hd.y, 0.f, 0.f, 0.f};
    int i = beg;
    int endu = beg + ((end - beg) & ~7);
    for (; i < endu; i += 8){
        int s_[8];
        #pragma unroll
        for (int j = 0; j < 8; j++) s_[j] = __builtin_amdgcn_readfirstlane(esrc[i + j]);
        float di_[8];
        #pragma unroll
        for (int j = 0; j < 8; j++) di_[j] = dinv[s_[j]];
        float2 hv_[8];
        #pragma unroll
        for (int j = 0; j < 8; j++) hv_[j] = ((const float2*)(h + ((size_t)s_[j]<<7)))[lane];
        #pragma unroll
        for (int j = 0; j < 8; j++){
            float coef = di_[j]*dv;
            ax[j & 3] = fmaf(coef, hv_[j].x, ax[j & 3]);
            ay[j & 3] = fmaf(coef, hv_[j].y, ay[j & 3]);
        }
    }
    for (; i < end; ++i){
        int s = __builtin_amdgcn_readfirstlane(esrc[i]);
        float coef = dinv[s]*dv;
        float2 hv = ((const float2*)(h + ((size_t)s<<7)))[lane];
        ax[0] = fmaf(coef, hv.x, ax[0]); ay[0] = fmaf(coef, hv.y, ay[0]);
    }
    float axs = ((ax[0]+ax[1])+(ax[2]+ax[3]));
    float ays = ((ay[0]+ay[1])+(ay[2]+ay[3]));
    axs = fmaxf(axs + bias[c0], 0.f);
    ays = fmaxf(ays + bias[c0+1], 0.f);
    float2 o; o.x = axs; o.y = ays;
    ((float2*)(out + ((size_t)d<<7)))[lane] = o;
    float py = axs*wrel[c0]  + ays*wrel[c0+1];
    float pz = axs*wroot[c0] + ays*wroot[c0+1];
    #pragma unroll
    for (int off = 32; off; off >>= 1){ py += __shfl_xor(py, off); pz += __shfl_xor(pz, off); }
    if (lane == 0){ Y[d] = py; Z[d] = pz + brel[0]; }
}

// ------- fused SAG score + radix-select top-k (stores tanh(score)) ----------
__global__ __launch_bounds__(1024) void topk_sag(const float* __restrict__ Y,
        const float* __restrict__ Z, const int2* __restrict__ rpx,
        const int* __restrict__ esrc, int npg, int k, int* __restrict__ perm,
        float* __restrict__ ssort, int* __restrict__ nid, int writeNid){
    __shared__ float sc[2048];
    __shared__ unsigned keys[2048];
    __shared__ int hist[256];
    __shared__ int cge[256];
    __shared__ int warpsum[16];
    __shared__ int s_bin, s_need;
    int g = blockIdx.x, tid = threadIdx.x;
    for (int n = tid; n < npg; n += 1024){
        int node = g*npg + n;
        int2 re = rpx[node];
        float s = 0.f;
        int i = re.x;
        for (; i + 3 < re.y; i += 4)
            s += ((Y[esrc[i]] + Y[esrc[i+1]]) + (Y[esrc[i+2]] + Y[esrc[i+3]]));
        for (; i < re.y; ++i) s += Y[esrc[i]];
        float v = s + Z[node];
        sc[n] = v;
        unsigned u = __float_as_uint(v);
        keys[n] = (u & 0x80000000u) ? ~u : (u | 0x80000000u);
    }
    if (tid == 0) s_need = k;
    __syncthreads();
    unsigned prefix = 0u, pmask = 0u;
    #pragma unroll
    for (int shift = 24; shift >= 0; shift -= 8){
        if (tid < 256) hist[tid] = 0;
        __syncthreads();
        for (int i = tid; i < npg; i += 1024){
            unsigned u = keys[i];
            if ((u & pmask) == prefix) atomicAdd(&hist[(u >> shift) & 255u], 1);
        }
        __syncthreads();
        if (tid < 256) cge[tid] = hist[tid];
        __syncthreads();
        for (int off = 1; off < 256; off <<= 1){
            int v = 0;
            if (tid < 256 - off) v = cge[tid + off];
            __syncthreads();
            if (tid < 256) cge[tid] += v;
            __syncthreads();
        }
        int need = s_need;
        if (tid < 256){
            int above = (tid == 255) ? 0 : cge[tid + 1];
            if (cge[tid] >= need && above < need) s_bin = tid;
        }
        __syncthreads();
        if (tid == 0) s_need = need - ((s_bin == 255) ? 0 : cge[s_bin + 1]);
        __syncthreads();
        prefix |= ((unsigned)s_bin) << shift;
        pmask  |= (255u << shift);
        __syncthreads();
    }
    unsigned thr = prefix;
    int m = s_need;
    int i0 = 2*tid, i1 = 2*tid + 1;
    int f0 = 0, f1 = 0;
    if (i0 < npg){
        unsigned u = keys[i0];
        if (u > thr) f0 = 1;
        else if (u == thr){
            int r = 0;
            for (int j = 0; j < i0; j++) r += (keys[j] == thr);
            f0 = (r < m) ? 1 : 0;
        }
    }
    if (i1 < npg){
        unsigned u = keys[i1];
        if (u > thr) f1 = 1;
        else if (u == thr){
            int r = 0;
            for (int j = 0; j < i1; j++) r += (keys[j] == thr);
            f1 = (r < m) ? 1 : 0;
        }
    }
    int pair = f0 + f1;
    int lane = tid & 63, wv = tid >> 6;
    int x = pair;
    #pragma unroll
    for (int off = 1; off < 64; off <<= 1){ int y = __shfl_up(x, off); if (lane >= off) x += y; }
    if (lane == 63) warpsum[wv] = x;
    __syncthreads();
    if (tid == 0){ int run = 0; for (int w2 = 0; w2 < 16; w2++){ int t = warpsum[w2]; warpsum[w2] = run; run += t; } }
    __syncthreads();
    int excl = x - pair + warpsum[wv];
    if (f0){
        int pos = excl;
        int node = g*npg + i0;
        perm[g*k + pos] = node;
        ssort[g*k + pos] = tanhf(sc[i0]);
        if (writeNid) nid[node] = g*k + pos;
    }
    if (f1){
        int pos = excl + f0;
        int node = g*npg + i1;
        perm[g*k + pos] = node;
        ssort[g*k + pos] = tanhf(sc[i1]);
        if (writeNid) nid[node] = g*k + pos;
    }
}

// mean pool over pooled set (tt = ssort already tanh'd)
__global__ void pool_mean2(const float* __restrict__ x, const int* __restrict__ perm,
                           const float* __restrict__ ssort, float* __restrict__ g){
    __shared__ float tt[KK2];
    __shared__ float part[128];
    int b = blockIdx.x, t = threadIdx.x;     // 256 threads
    tt[t]       = ssort[b*KK2 + t];
    tt[t + 256] = ssort[b*KK2 + t + 256];
    __syncthreads();
    int c = t & 127, half = t >> 7;
    float s = 0.f;
    #pragma unroll 4
    for (int i = half*256; i < half*256 + 256; i++){
        int o = perm[b*KK2 + i];
        s = fmaf(tt[i], x[(size_t)o*128 + c], s);
    }
    if (half) part[c] = s;
    __syncthreads();
    if (!half) g[b*128 + c] = (s + part[c]) * (1.0f/KK2);
}

__global__ void mlp_k(const float* __restrict__ g,
                      const float* __restrict__ fc1w, const float* __restrict__ fc1b,
                      const float* __restrict__ fc2w, const float* __restrict__ fc2b,
                      const float* __restrict__ ow,  const float* __restrict__ ob,
                      float* __restrict__ out){
    __shared__ float gv[128], t1[256], t2[128];
    int b = blockIdx.x, t = threadIdx.x;
    if (t < 128) gv[t] = g[b*128 + t];
    __syncthreads();
    {
        float s = fc1b[t];
        for (int c = 0; c < 128; c++) s += gv[c]*fc1w[t*128 + c];
        t1[t] = fmaxf(s, 0.f);
    }
    __syncthreads();
    if (t < 128){
        float s = fc2b[t];
        for (int c = 0; c < 256; c++) s += t1[c]*fc2w[t*256 + c];
        t2[t] = fmaxf(s, 0.f);
    }
    __syncthreads();
    if (t < 10){
        float s = ob[t];
        for (int c = 0; c < 128; c++) s += t2[c]*ow[t*128 + c];
        out[b*10 + t] = s;
    }
}

// ---------------- launch ----------------
extern "C" void kernel_launch(void* const* d_in, const int* in_sizes, int n_in,
                              void* d_out, int out_size, void* d_ws, size_t ws_size,
                              hipStream_t stream){
    (void)in_sizes; (void)n_in; (void)out_size; (void)ws_size;
    const float* x    = (const float*)d_in[0];
    const int*   eidx = (const int*)d_in[1];
    const int*   src  = eidx;
    const int*   dst  = eidx + EE;
    const float* g1w  = (const float*)d_in[3];
    const float* g1as = (const float*)d_in[4];
    const float* g1ad = (const float*)d_in[5];
    const float* g1b  = (const float*)d_in[6];
    const float* g2w  = (const float*)d_in[7];
    const float* g2as = (const float*)d_in[8];
    const float* g2ad = (const float*)d_in[9];
    const float* g2b  = (const float*)d_in[10];
    const float* c1w  = (const float*)d_in[11];
    const float* c1b  = (const float*)d_in[12];
    const float* s1wrel  = (const float*)d_in[13];
    const float* s1brel  = (const float*)d_in[14];
    const float* s1wroot = (const float*)d_in[15];
    const float* c2w  = (const float*)d_in[16];
    const float* c2b  = (const float*)d_in[17];
    const float* s2wrel  = (const float*)d_in[18];
    const float* s2brel  = (const float*)d_in[19];
    const float* s2wroot = (const float*)d_in[20];
    const float* f1w  = (const float*)d_in[21];
    const float* f1b  = (const float*)d_in[22];
    const float* f2w  = (const float*)d_in[23];
    const float* f2b  = (const float*)d_in[24];
    const float* ow   = (const float*)d_in[25];
    const float* ob   = (const float*)d_in[26];
    float* out = (float*)d_out;

    char* ws = (char*)d_ws;
    size_t off = 0;
    auto alloc = [&](size_t bytes)->char*{
        char* p = ws + off;
        off += (bytes + 255) & ~(size_t)255;
        return p;
    };
    float* F0     = (float*)alloc((size_t)N1*256*4);
    float* F1     = (float*)alloc((size_t)N1*256*4);
    float* F2     = (float*)alloc((size_t)N2*128*4);
    float* AS     = (float*)alloc((size_t)N1*4*4);
    float* AD     = (float*)alloc((size_t)N1*4*4);
    int2*  RPX    = (int2*) alloc((size_t)N1*8);
    int*   CUR    = (int*)  alloc((size_t)N1*4);
    int*   EL     = (int*)  alloc((size_t)EE*4);
    float* DINV   = (float*)alloc((size_t)N1*4);
    float* Y      = (float*)alloc((size_t)N1*4);
    float* Z      = (float*)alloc((size_t)N1*4);
    int*   PERM1  = (int*)  alloc((size_t)N2*4);
    float* SSORT1 = (float*)alloc((size_t)N2*4);
    int*   NID    = (int*)  alloc((size_t)N1*4);
    int*   E1S    = (int*)  alloc((size_t)EE*4);
    int*   E1D    = (int*)  alloc((size_t)EE*4);
    int2*  RPX2   = (int2*) alloc((size_t)N2*8);
    int*   CUR2   = (int*)  alloc((size_t)N2*4);
    int*   EL2    = (int*)  alloc((size_t)EE*4);
    float* DINV2  = (float*)alloc((size_t)N2*4);
    int*   PERM2  = (int*)  alloc((size_t)N3*4);
    float* SSORT2 = (float*)alloc((size_t)N3*4);
    float* GBUF   = (float*)alloc((size_t)NB*128*4);
    int*   BS     = (int*)  alloc((size_t)128*4);
    _Float16* WH  = (_Float16*)alloc((size_t)131072*2);
    _Float16* WL  = (_Float16*)alloc((size_t)131072*2);
    const int o_g1 = 0, o_g2 = 16384, o_c1 = 81920, o_c2 = 114688;

    // ---- level-1 CSR (wide) + weight pre-split ----
    hipMemsetAsync(CUR, 0, (size_t)N1*4, stream);
    count_dst<<<EE/256, 256, 0, stream>>>(dst, CUR, EE);
    blocksum_k<<<N1/256, 256, 0, stream>>>(CUR, BS);
    scan_write_k<<<N1/256, 256, 0, stream>>>(CUR, BS, N1/256, RPX, CUR, DINV);
    scatter1<<<EE/256, 256, 0, stream>>>(src, dst, CUR, EL, EE);
    wsplit4<<<512, 256, 0, stream>>>(g1w, 16384, g2w, 65536, c1w, 32768, c2w, 16384, WH, WL);

    // ---- GAT layer 1 (64 -> 4x64, relu) ----
    gemm_h2<<<dim3(N1/128, 2), 256, 0, stream>>>(x, WH + o_g1, WL + o_g1, F0, N1, 64, 256, nullptr, nullptr);
    attn_pre<<<N1/4, 256, 0, stream>>>(F0, g1as, g1ad, AS, AD);
    gat_agg<1><<<N1/4, 256, 0, stream>>>(F0, AS, AD, g1b, RPX, EL, F1);

    // ---- GAT layer 2 (256 -> 4x64) ----
    gemm_h2<<<dim3(N1/128, 2), 256, 0, stream>>>(F1, WH + o_g2, WL + o_g2, F0, N1, 256, 256, nullptr, nullptr);
    attn_pre<<<N1/4, 256, 0, stream>>>(F0, g2as, g2ad, AS, AD);
    gat_agg<0><<<N1/4, 256, 0, stream>>>(F0, AS, AD, g2b, RPX, EL, F1);

    // ---- GCN1 (256 -> 128, relu) + fused SAG1 partial dots ----
    gemm_h2<<<dim3(N1/128, 1), 256, 0, stream>>>(F1, WH + o_c1, WL + o_c1, F0, N1, 256, 128, nullptr, nullptr);
    gcn_agg_sag<<<N1/4, 256, 0, stream>>>(F0, DINV, c1b, s1wrel, s1wroot, s1brel,
                                          RPX, EL, F1, Y, Z);

    // ---- SAGPool1 (fused score + top-k) ----
    hipMemsetAsync(NID, 0xFF, (size_t)N1*4, stream);   // -1
    topk_sag<<<NB, 1024, 0, stream>>>(Y, Z, RPX, EL, NPG1, KK1, PERM1, SSORT1, NID, 1);

    // ---- level-2 CSR (wide; remap + count fused) ----
    hipMemsetAsync(CUR2, 0, (size_t)N2*4, stream);
    remap_count<<<EE/256, 256, 0, stream>>>(src, dst, NID, E1S, E1D, CUR2, EE);
    blocksum_k<<<N2/256, 256, 0, stream>>>(CUR2, BS);
    scan_write_k<<<N2/256, 256, 0, stream>>>(CUR2, BS, N2/256, RPX2, CUR2, DINV2);
    scatter2<<<EE/256, 256, 0, stream>>>(E1S, E1D, CUR2, EL2, EE);

    // ---- GCN2 (128 -> 128, relu): GEMM reads F1 via perm * tanh (fused pool_gather)
    gemm_h2<<<dim3(N2/128, 1), 256, 0, stream>>>(F1, WH + o_c2, WL + o_c2, F0, N2, 128, 128, PERM1, SSORT1);
    gcn_agg_sag<<<N2/4, 256, 0, stream>>>(F0, DINV2, c2b, s2wrel, s2wroot, s2brel,
                                          RPX2, EL2, F2, Y, Z);

    // ---- SAGPool2 (fused score + top-k) ----
    topk_sag<<<NB, 1024, 0, stream>>>(Y, Z, RPX2, EL2, NPG2, KK2, PERM2, SSORT2, nullptr, 0);

    // ---- fused gather + mean pool + MLP ----
    pool_mean2<<<NB, 256, 0, stream>>>(F2, PERM2, SSORT2, GBUF);
    mlp_k<<<NB, 256, 0, stream>>>(GBUF, f1w, f1b, f2w, f2b, ow, ob, out);
}

// Round 11
// 335.486 us; speedup vs baseline: 2.2799x; 1.0678x over previous
//
#include <hip/hip_runtime.h>

#define N1 32768
#define EE 524288
#define NB 16
#define DEG 16
#define NPG1 2048
#define KK1 1024
#define N2 16384
#define NPG2 1024
#define KK2 512
#define N3 8192

typedef _Float16 half8_t __attribute__((ext_vector_type(8)));
typedef float floatx16 __attribute__((ext_vector_type(16)));

static __device__ __forceinline__ float leaky(float x){ return fmaxf(x, 0.2f*x); }

// ---------------- CSR build (wide multi-kernel) ----------------
__global__ void count_dst(const int* __restrict__ dst, int* __restrict__ cnt, int E){
    int i = blockIdx.x*blockDim.x + threadIdx.x;
    if (i < E) atomicAdd(&cnt[dst[i]], 1);
}

__global__ void remap_count(const int* __restrict__ src, const int* __restrict__ dst,
                            const int* __restrict__ nid, int* __restrict__ ns,
                            int* __restrict__ nd, int* __restrict__ cnt, int E){
    int i = blockIdx.x*blockDim.x + threadIdx.x;
    if (i < E){
        int a = nid[src[i]], b = nid[dst[i]];
        ns[i] = a; nd[i] = b;
        if (a >= 0 && b >= 0) atomicAdd(&cnt[b], 1);
    }
}

__global__ void blocksum_k(const int* __restrict__ cnt, int* __restrict__ bs){
    __shared__ int red[4];
    int tid = threadIdx.x;
    int v = cnt[blockIdx.x*256 + tid];
    #pragma unroll
    for (int off = 32; off; off >>= 1) v += __shfl_xor(v, off);
    if ((tid & 63) == 0) red[tid >> 6] = v;
    __syncthreads();
    if (tid == 0) bs[blockIdx.x] = red[0] + red[1] + red[2] + red[3];
}

__global__ void scan_write_k(const int* __restrict__ cnt, const int* __restrict__ bs,
                             int nb, int2* __restrict__ rpx, int* __restrict__ cur,
                             float* __restrict__ dinv){
    __shared__ int sbs[128];
    __shared__ int wsum[4];
    int tid = threadIdx.x;
    int b = blockIdx.x;
    if (tid < nb) sbs[tid] = bs[tid];
    __syncthreads();
    for (int off = 1; off < nb; off <<= 1){
        int v = 0;
        if (tid < nb && tid >= off) v = sbs[tid - off];
        __syncthreads();
        if (tid < nb) sbs[tid] += v;
        __syncthreads();
    }
    int base = (b == 0) ? 0 : sbs[b-1];
    int i = b*256 + tid;
    int c = cnt[i];
    int lane = tid & 63, wv = tid >> 6;
    int x = c;
    #pragma unroll
    for (int off = 1; off < 64; off <<= 1){ int y = __shfl_up(x, off); if (lane >= off) x += y; }
    if (lane == 63) wsum[wv] = x;
    __syncthreads();
    if (tid == 0){ int run = 0; for (int w2 = 0; w2 < 4; w2++){ int t = wsum[w2]; wsum[w2] = run; run += t; } }
    __syncthreads();
    int excl = x - c + wsum[wv];
    int beg = base + excl;
    rpx[i]  = make_int2(beg, beg + c);
    cur[i]  = beg;
    dinv[i] = rsqrtf((float)c + 1.0f);
}

__global__ void scatter1(const int* __restrict__ src, const int* __restrict__ dst,
                         int* __restrict__ cur, int* __restrict__ esrc, int E){
    int i = blockIdx.x*blockDim.x + threadIdx.x;
    if (i < E){ int p = atomicAdd(&cur[dst[i]], 1); esrc[p] = src[i]; }
}

__global__ void scatter2(const int* __restrict__ ns, const int* __restrict__ nd,
                         int* __restrict__ cur, int* __restrict__ esrc, int E){
    int i = blockIdx.x*blockDim.x + threadIdx.x;
    if (i < E){
        int a = ns[i], b = nd[i];
        if (a >= 0 && b >= 0){ int p = atomicAdd(&cur[b], 1); esrc[p] = a; }
    }
}

// ---------------- weight pre-split (fp32 -> fp16 hi/lo) ----------------
__global__ void wsplit4(const float* __restrict__ w0, int n0,
                        const float* __restrict__ w1, int n1,
                        const float* __restrict__ w2, int n2,
                        const float* __restrict__ w3, int n3,
                        _Float16* __restrict__ wh, _Float16* __restrict__ wl){
    int i = blockIdx.x*256 + threadIdx.x;
    int n01 = n0 + n1, n012 = n01 + n2, nt = n012 + n3;
    if (i >= nt) return;
    float v = (i < n0) ? w0[i] : (i < n01) ? w1[i - n0] : (i < n012) ? w2[i - n01] : w3[i - n012];
    _Float16 h = (_Float16)v;
    wh[i] = h; wl[i] = (_Float16)(v - (float)h);
}

// ------------- split-fp16 MFMA GEMM: C = A @ W^T (fp32 A, pre-split W) ------
// optional row-gather + scale on A (perm != nullptr): A_eff[r] = A[perm[r]] * tt[r]
#define KS 64
static __device__ __forceinline__ int ldsoff(int row, int k8){
    return row*64 + ((k8 ^ (row & 7)) << 3);
}

__global__ __launch_bounds__(256, 2) void gemm_h2(const float* __restrict__ A,
        const _Float16* __restrict__ WHp, const _Float16* __restrict__ WLp,
        float* __restrict__ C, int n, int K, int M,
        const int* __restrict__ perm, const float* __restrict__ tt){
    __shared__ _Float16 sm[4*128*KS];
    _Float16* sAH = sm;
    _Float16* sAL = sm + 128*KS;
    _Float16* sWH = sm + 2*128*KS;
    _Float16* sWL = sm + 3*128*KS;
    int t = threadIdx.x;
    int lane = t & 63;
    int wid = t >> 6;
    int wr = wid >> 1, wc = wid & 1;
    int row0 = blockIdx.x*128, col0 = blockIdx.y*128;
    int srow = t >> 3;
    int sk8  = t & 7;

    floatx16 acc[2][2];
    #pragma unroll
    for (int i = 0; i < 2; i++)
        #pragma unroll
        for (int j = 0; j < 2; j++)
            #pragma unroll
            for (int q = 0; q < 16; q++) acc[i][j][q] = 0.f;

    for (int kk = 0; kk < K; kk += KS){
        #pragma unroll
        for (int p = 0; p < 4; p++){
            int r = srow + p*32;
            int rr = row0 + r;
            int arow = perm ? perm[rr] : rr;
            float tscale = perm ? tt[rr] : 1.0f;
            const float* ga = A + (size_t)arow*K + kk + sk8*8;
            float4 a0 = *(const float4*)ga;
            float4 a1 = *(const float4*)(ga + 4);
            half8_t ahi, alo;
            float av[8] = {a0.x,a0.y,a0.z,a0.w,a1.x,a1.y,a1.z,a1.w};
            #pragma unroll
            for (int q = 0; q < 8; q++){
                float v = av[q] * tscale;
                _Float16 h = (_Float16)v;
                ahi[q] = h; alo[q] = (_Float16)(v - (float)h);
            }
            size_t wo = (size_t)(col0 + r)*K + kk + sk8*8;
            half8_t whi = *(const half8_t*)(WHp + wo);
            half8_t wlo = *(const half8_t*)(WLp + wo);
            int o = ldsoff(r, sk8);
            *(half8_t*)&sAH[o] = ahi;
            *(half8_t*)&sAL[o] = alo;
            *(half8_t*)&sWH[o] = whi;
            *(half8_t*)&sWL[o] = wlo;
        }
        __syncthreads();
        #pragma unroll
        for (int kc = 0; kc < 4; kc++){
            int k8 = kc*2 + (lane >> 5);
            int ra = wr*64 + (lane & 31);
            int rb = wc*64 + (lane & 31);
            half8_t ah0 = *(const half8_t*)&sAH[ldsoff(ra,      k8)];
            half8_t ah1 = *(const half8_t*)&sAH[ldsoff(ra + 32, k8)];
            half8_t al0 = *(const half8_t*)&sAL[ldsoff(ra,      k8)];
            half8_t al1 = *(const half8_t*)&sAL[ldsoff(ra + 32, k8)];
            half8_t bh0 = *(const half8_t*)&sWH[ldsoff(rb,      k8)];
            half8_t bh1 = *(const half8_t*)&sWH[ldsoff(rb + 32, k8)];
            half8_t bl0 = *(const half8_t*)&sWL[ldsoff(rb,      k8)];
            half8_t bl1 = *(const half8_t*)&sWL[ldsoff(rb + 32, k8)];
            acc[0][0] = __builtin_amdgcn_mfma_f32_32x32x16_f16(ah0, bh0, acc[0][0], 0,0,0);
            acc[0][0] = __builtin_amdgcn_mfma_f32_32x32x16_f16(ah0, bl0, acc[0][0], 0,0,0);
            acc[0][0] = __builtin_amdgcn_mfma_f32_32x32x16_f16(al0, bh0, acc[0][0], 0,0,0);
            acc[0][1] = __builtin_amdgcn_mfma_f32_32x32x16_f16(ah0, bh1, acc[0][1], 0,0,0);
            acc[0][1] = __builtin_amdgcn_mfma_f32_32x32x16_f16(ah0, bl1, acc[0][1], 0,0,0);
            acc[0][1] = __builtin_amdgcn_mfma_f32_32x32x16_f16(al0, bh1, acc[0][1], 0,0,0);
            acc[1][0] = __builtin_amdgcn_mfma_f32_32x32x16_f16(ah1, bh0, acc[1][0], 0,0,0);
            acc[1][0] = __builtin_amdgcn_mfma_f32_32x32x16_f16(ah1, bl0, acc[1][0], 0,0,0);
            acc[1][0] = __builtin_amdgcn_mfma_f32_32x32x16_f16(al1, bh0, acc[1][0], 0,0,0);
            acc[1][1] = __builtin_amdgcn_mfma_f32_32x32x16_f16(ah1, bh1, acc[1][1], 0,0,0);
            acc[1][1] = __builtin_amdgcn_mfma_f32_32x32x16_f16(ah1, bl1, acc[1][1], 0,0,0);
            acc[1][1] = __builtin_amdgcn_mfma_f32_32x32x16_f16(al1, bh1, acc[1][1], 0,0,0);
        }
        __syncthreads();
    }
    #pragma unroll
    for (int rt = 0; rt < 2; rt++)
        #pragma unroll
        for (int ct = 0; ct < 2; ct++){
            int baser = row0 + wr*64 + rt*32 + 4*(lane >> 5);
            int c = col0 + wc*64 + ct*32 + (lane & 31);
            #pragma unroll
            for (int r = 0; r < 16; r++){
                int rr = baser + (r & 3) + 8*(r >> 2);
                C[(size_t)rr*M + c] = acc[rt][ct][r];
            }
        }
}

// ---------------- GAT attention coefficients ----------------
__global__ void attn_pre(const float* __restrict__ h, const float* __restrict__ wsrc,
                         const float* __restrict__ wdst, float* __restrict__ as_,
                         float* __restrict__ ad_){
    int lane = threadIdx.x & 63;
    int w = threadIdx.x >> 6;
    int d = blockIdx.x*4 + w;
    float4 hv = *(const float4*)(h + (size_t)d*256 + lane*4);
    float4 ws = *(const float4*)(wsrc + lane*4);
    float4 wd = *(const float4*)(wdst + lane*4);
    float ps = hv.x*ws.x + hv.y*ws.y + hv.z*ws.z + hv.w*ws.w;
    float pd = hv.x*wd.x + hv.y*wd.y + hv.z*wd.z + hv.w*wd.w;
    #pragma unroll
    for (int m = 8; m; m >>= 1){ ps += __shfl_xor(ps, m); pd += __shfl_xor(pd, m); }
    if ((lane & 15) == 0){
        as_[d*4 + (lane >> 4)] = ps;
        ad_[d*4 + (lane >> 4)] = pd;
    }
}

// ---- GAT aggregation: no-max softmax, 8-wide pipeline, scalarized node ids --
template<int RELU>
__global__ void gat_agg(const float* __restrict__ h, const float* __restrict__ as_,
                        const float* __restrict__ ad_, const float* __restrict__ bias,
                        const int2* __restrict__ rpx, const int* __restrict__ esrc,
                        float* __restrict__ out){
    int lane = threadIdx.x & 63;
    int nb = gridDim.x;
    int b = blockIdx.x;
    int sb = (b & 7)*(nb >> 3) + (b >> 3);
    int d = __builtin_amdgcn_readfirstlane(sb*4 + (int)(threadIdx.x >> 6));
    int2 re = rpx[d];
    int beg = re.x, end = re.y;

    int hh = lane >> 4;
    float adh = ad_[(d<<2) + hh];
    float aself = as_[(d<<2) + hh];

    float dn[4];
    dn[0] = __expf(leaky(aself + adh)); dn[1] = 0.f; dn[2] = 0.f; dn[3] = 0.f;
    float4 hd = ((const float4*)(h + ((size_t)d<<8)))[lane];
    float4 AX[4];
    AX[0].x = dn[0]*hd.x; AX[0].y = dn[0]*hd.y; AX[0].z = dn[0]*hd.z; AX[0].w = dn[0]*hd.w;
    AX[1] = {0,0,0,0}; AX[2] = {0,0,0,0}; AX[3] = {0,0,0,0};

    int i = beg;
    int endu = beg + ((end - beg) & ~7);
    for (; i < endu; i += 8){
        int s_[8];
        #pragma unroll
        for (int j = 0; j < 8; j++) s_[j] = __builtin_amdgcn_readfirstlane(esrc[i + j]);
        float a_[8];
        #pragma unroll
        for (int j = 0; j < 8; j++) a_[j] = as_[(s_[j]<<2) + hh];
        float4 hv_[8];
        #pragma unroll
        for (int j = 0; j < 8; j++) hv_[j] = ((const float4*)(h + ((size_t)s_[j]<<8)))[lane];
        #pragma unroll
        for (int j = 0; j < 8; j++){
            float x = a_[j] + adh;
            float p = __expf(fmaxf(x, 0.2f*x));
            dn[j & 3] += p;
            AX[j & 3].x = fmaf(p, hv_[j].x, AX[j & 3].x);
            AX[j & 3].y = fmaf(p, hv_[j].y, AX[j & 3].y);
            AX[j & 3].z = fmaf(p, hv_[j].z, AX[j & 3].z);
            AX[j & 3].w = fmaf(p, hv_[j].w, AX[j & 3].w);
        }
    }
    for (; i < end; ++i){
        int s = __builtin_amdgcn_readfirstlane(esrc[i]);
        float x = as_[(s<<2) + hh] + adh;
        float4 hv = ((const float4*)(h + ((size_t)s<<8)))[lane];
        float p = __expf(fmaxf(x, 0.2f*x));
        dn[0] += p;
        AX[0].x = fmaf(p, hv.x, AX[0].x); AX[0].y = fmaf(p, hv.y, AX[0].y);
        AX[0].z = fmaf(p, hv.z, AX[0].z); AX[0].w = fmaf(p, hv.w, AX[0].w);
    }
    float den = ((dn[0] + dn[1]) + (dn[2] + dn[3])) + 1e-16f;
    float r = 1.0f / den;
    int c0 = lane*4;
    float4 bv = *(const float4*)(bias + c0);
    float4 acc;
    acc.x = ((AX[0].x+AX[1].x)+(AX[2].x+AX[3].x))*r + bv.x;
    acc.y = ((AX[0].y+AX[1].y)+(AX[2].y+AX[3].y))*r + bv.y;
    acc.z = ((AX[0].z+AX[1].z)+(AX[2].z+AX[3].z))*r + bv.z;
    acc.w = ((AX[0].w+AX[1].w)+(AX[2].w+AX[3].w))*r + bv.w;
    if (RELU){
        acc.x = fmaxf(acc.x, 0.f); acc.y = fmaxf(acc.y, 0.f);
        acc.z = fmaxf(acc.z, 0.f); acc.w = fmaxf(acc.w, 0.f);
    }
    ((float4*)(out + ((size_t)d<<8)))[lane] = acc;
}

// ---- GCN aggregation + fused SAG-score partial dots, scalarized node ids ----
__global__ void gcn_agg_sag(const float* __restrict__ h, const float* __restrict__ dinv,
                            const float* __restrict__ bias,
                            const float* __restrict__ wrel, const float* __restrict__ wroot,
                            const float* __restrict__ brel,
                            const int2* __restrict__ rpx, const int* __restrict__ esrc,
                            float* __restrict__ out, float* __restrict__ Y, float* __restrict__ Z){
    int lane = threadIdx.x & 63;
    int nb = gridDim.x;
    int b = blockIdx.x;
    int sb = (b & 7)*(nb >> 3) + (b >> 3);
    int d = __builtin_amdgcn_readfirstlane(sb*4 + (int)(threadIdx.x >> 6));
    int2 re = rpx[d];
    int beg = re.x, end = re.y;
    float dv = dinv[d];
    int c0 = lane*2;
    float2 hd = ((const float2*)(h + ((size_t)d<<7)))[lane];
    float self = dv*dv;
    float ax[4] = {self*hd.x, 0.f, 0.f, 0.f};
    float ay[4] = {self*hd.y, 0.f, 0.f, 0.f};
    int i = beg;
    int endu = beg + ((end - beg) & ~7);
    for (; i < endu; i += 8){
        int s_[8];
        #pragma unroll
        for (int j = 0; j < 8; j++) s_[j] = __builtin_amdgcn_readfirstlane(esrc[i + j]);
        float di_[8];
        #pragma unroll
        for (int j = 0; j < 8; j++) di_[j] = dinv[s_[j]];
        float2 hv_[8];
        #pragma unroll
        for (int j = 0; j < 8; j++) hv_[j] = ((const float2*)(h + ((size_t)s_[j]<<7)))[lane];
        #pragma unroll
        for (int j = 0; j < 8; j++){
            float coef = di_[j]*dv;
            ax[j & 3] = fmaf(coef, hv_[j].x, ax[j & 3]);
            ay[j & 3] = fmaf(coef, hv_[j].y, ay[j & 3]);
        }
    }
    for (; i < end; ++i){
        int s = __builtin_amdgcn_readfirstlane(esrc[i]);
        float coef = dinv[s]*dv;
        float2 hv = ((const float2*)(h + ((size_t)s<<7)))[lane];
        ax[0] = fmaf(coef, hv.x, ax[0]); ay[0] = fmaf(coef, hv.y, ay[0]);
    }
    float axs = ((ax[0]+ax[1])+(ax[2]+ax[3]));
    float ays = ((ay[0]+ay[1])+(ay[2]+ay[3]));
    axs = fmaxf(axs + bias[c0], 0.f);
    ays = fmaxf(ays + bias[c0+1], 0.f);
    float2 o; o.x = axs; o.y = ays;
    ((float2*)(out + ((size_t)d<<7)))[lane] = o;
    float py = axs*wrel[c0]  + ays*wrel[c0+1];
    float pz = axs*wroot[c0] + ays*wroot[c0+1];
    #pragma unroll
    for (int off = 32; off; off >>= 1){ py += __shfl_xor(py, off); pz += __shfl_xor(pz, off); }
    if (lane == 0){ Y[d] = py; Z[d] = pz + brel[0]; }
}

// ---------------- SAG score via scalar gather (wide) ----------------
__global__ void sag_lite(const float* __restrict__ Y, const float* __restrict__ Z,
                         const int2* __restrict__ rpx, const int* __restrict__ esrc,
                         float* __restrict__ score){
    int lane = threadIdx.x & 63;
    int w = threadIdx.x >> 6;
    int nb = gridDim.x;
    int b = blockIdx.x;
    int sb = (b & 7)*(nb >> 3) + (b >> 3);
    int d = sb*4 + w;
    int2 re = rpx[d];
    float s = 0.f;
    for (int i = re.x + lane; i < re.y; i += 64) s += Y[esrc[i]];
    #pragma unroll
    for (int off = 32; off; off >>= 1) s += __shfl_xor(s, off);
    if (lane == 0) score[d] = s + Z[d];
}

// ------- barrier-free wave-per-graph radix-select top-k ---------------------
// 64 lanes, all cross-lane via shfl/ballot; LDS only for keys+hist (in-wave
// ordering, no __syncthreads). Stores tanh(score); writes nid for ALL nodes.
__global__ __launch_bounds__(64) void topk_wave(const float* __restrict__ score,
        int npg, int k, int* __restrict__ perm, float* __restrict__ ssort,
        int* __restrict__ nid, int writeNid){
    __shared__ unsigned keys[2048];
    __shared__ int hist[256];
    int g = blockIdx.x;
    int lane = threadIdx.x;
    int nch = npg >> 6;
    for (int c = 0; c < nch; c++){
        unsigned u = __float_as_uint(score[g*npg + c*64 + lane]);
        keys[c*64 + lane] = (u & 0x80000000u) ? ~u : (u | 0x80000000u);
    }
    int need = k;
    unsigned prefix = 0u, pmask = 0u;
    #pragma unroll
    for (int shift = 24; shift >= 0; shift -= 8){
        #pragma unroll
        for (int q = 0; q < 4; q++) hist[lane*4 + q] = 0;
        for (int c = 0; c < nch; c++){
            unsigned u = keys[c*64 + lane];
            if ((u & pmask) == prefix) atomicAdd(&hist[(u >> shift) & 255u], 1);
        }
        int h0 = hist[lane*4], h1 = hist[lane*4+1], h2 = hist[lane*4+2], h3 = hist[lane*4+3];
        int s3 = h3, s2 = h2 + s3, s1 = h1 + s2, s0 = h0 + s1;   // suffix within quad
        int tot = s0;
        int suf = tot;                                           // inclusive suffix over lanes
        #pragma unroll
        for (int off = 1; off < 64; off <<= 1){
            int v = __shfl_down(suf, off);
            if (lane + off < 64) suf += v;
        }
        int above_quad = suf - tot;            // = cge of bin (lane+1)*4
        int c0 = s0 + above_quad, c1 = s1 + above_quad, c2 = s2 + above_quad, c3 = s3 + above_quad;
        int sel = -1;
        if (c0 >= need && c1 < need) sel = 0;
        if (c1 >= need && c2 < need) sel = 1;
        if (c2 >= need && c3 < need) sel = 2;
        if (c3 >= need && above_quad < need) sel = 3;
        unsigned long long msk = __ballot(sel >= 0);
        int srcl = __ffsll((long long)msk) - 1;
        int binq = __shfl(sel, srcl);
        int bin = srcl*4 + binq;
        int cge_next = (binq == 0) ? __shfl(c1, srcl) :
                       (binq == 1) ? __shfl(c2, srcl) :
                       (binq == 2) ? __shfl(c3, srcl) : __shfl(above_quad, srcl);
        need -= cge_next;
        prefix |= ((unsigned)bin) << shift;
        pmask  |= 255u << shift;
    }
    unsigned thr = prefix;
    int m = need;                                   // # of ==thr to take, lowest index first
    unsigned long long below = (lane == 63) ? 0x7FFFFFFFFFFFFFFFull : ((1ull << lane) - 1ull);
    int base = 0, eqbase = 0;
    for (int c = 0; c < nch; c++){
        unsigned u = keys[c*64 + lane];
        bool gt = u > thr;
        bool eq = (u == thr);
        unsigned long long meq = __ballot(eq);
        int eqrank = eqbase + __popcll(meq & below);
        bool take = gt || (eq && eqrank < m);
        unsigned long long mtk = __ballot(take);
        int pos = base + __popcll(mtk & below);
        int node = g*npg + c*64 + lane;
        if (take){
            perm[g*k + pos] = node;
            ssort[g*k + pos] = tanhf(score[node]);
            if (writeNid) nid[node] = g*k + pos;
        } else if (writeNid) nid[node] = -1;
        base += __popcll(mtk);
        eqbase += __popcll(meq);
    }
}

// mean pool over pooled set (tt = ssort already tanh'd)
__global__ void pool_mean2(const float* __restrict__ x, const int* __restrict__ perm,
                           const float* __restrict__ ssort, float* __restrict__ g){
    __shared__ float tt[KK2];
    __shared__ float part[128];
    int b = blockIdx.x, t = threadIdx.x;     // 256 threads
    tt[t]       = ssort[b*KK2 + t];
    tt[t + 256] = ssort[b*KK2 + t + 256];
    __syncthreads();
    int c = t & 127, half = t >> 7;
    float s = 0.f;
    #pragma unroll 4
    for (int i = half*256; i < half*256 + 256; i++){
        int o = perm[b*KK2 + i];
        s = fmaf(tt[i], x[(size_t)o*128 + c], s);
    }
    if (half) part[c] = s;
    __syncthreads();
    if (!half) g[b*128 + c] = (s + part[c]) * (1.0f/KK2);
}

__global__ void mlp_k(const float* __restrict__ g,
                      const float* __restrict__ fc1w, const float* __restrict__ fc1b,
                      const float* __restrict__ fc2w, const float* __restrict__ fc2b,
                      const float* __restrict__ ow,  const float* __restrict__ ob,
                      float* __restrict__ out){
    __shared__ float gv[128], t1[256], t2[128];
    int b = blockIdx.x, t = threadIdx.x;
    if (t < 128) gv[t] = g[b*128 + t];
    __syncthreads();
    {
        float s = fc1b[t];
        for (int c = 0; c < 128; c++) s += gv[c]*fc1w[t*128 + c];
        t1[t] = fmaxf(s, 0.f);
    }
    __syncthreads();
    if (t < 128){
        float s = fc2b[t];
        for (int c = 0; c < 256; c++) s += t1[c]*fc2w[t*256 + c];
        t2[t] = fmaxf(s, 0.f);
    }
    __syncthreads();
    if (t < 10){
        float s = ob[t];
        for (int c = 0; c < 128; c++) s += t2[c]*ow[t*128 + c];
        out[b*10 + t] = s;
    }
}

// ---------------- launch ----------------
extern "C" void kernel_launch(void* const* d_in, const int* in_sizes, int n_in,
                              void* d_out, int out_size, void* d_ws, size_t ws_size,
                              hipStream_t stream){
    (void)in_sizes; (void)n_in; (void)out_size; (void)ws_size;
    const float* x    = (const float*)d_in[0];
    const int*   eidx = (const int*)d_in[1];
    const int*   src  = eidx;
    const int*   dst  = eidx + EE;
    const float* g1w  = (const float*)d_in[3];
    const float* g1as = (const float*)d_in[4];
    const float* g1ad = (const float*)d_in[5];
    const float* g1b  = (const float*)d_in[6];
    const float* g2w  = (const float*)d_in[7];
    const float* g2as = (const float*)d_in[8];
    const float* g2ad = (const float*)d_in[9];
    const float* g2b  = (const float*)d_in[10];
    const float* c1w  = (const float*)d_in[11];
    const float* c1b  = (const float*)d_in[12];
    const float* s1wrel  = (const float*)d_in[13];
    const float* s1brel  = (const float*)d_in[14];
    const float* s1wroot = (const float*)d_in[15];
    const float* c2w  = (const float*)d_in[16];
    const float* c2b  = (const float*)d_in[17];
    const float* s2wrel  = (const float*)d_in[18];
    const float* s2brel  = (const float*)d_in[19];
    const float* s2wroot = (const float*)d_in[20];
    const float* f1w  = (const float*)d_in[21];
    const float* f1b  = (const float*)d_in[22];
    const float* f2w  = (const float*)d_in[23];
    const float* f2b  = (const float*)d_in[24];
    const float* ow   = (const float*)d_in[25];
    const float* ob   = (const float*)d_in[26];
    float* out = (float*)d_out;

    char* ws = (char*)d_ws;
    size_t off = 0;
    auto alloc = [&](size_t bytes)->char*{
        char* p = ws + off;
        off += (bytes + 255) & ~(size_t)255;
        return p;
    };
    float* F0     = (float*)alloc((size_t)N1*256*4);
    float* F1     = (float*)alloc((size_t)N1*256*4);
    float* F2     = (float*)alloc((size_t)N2*128*4);
    float* AS     = (float*)alloc((size_t)N1*4*4);
    float* AD     = (float*)alloc((size_t)N1*4*4);
    int2*  RPX    = (int2*) alloc((size_t)N1*8);
    int*   CUR    = (int*)  alloc((size_t)N1*4);
    int*   EL     = (int*)  alloc((size_t)EE*4);
    float* DINV   = (float*)alloc((size_t)N1*4);
    float* SCORE  = (float*)alloc((size_t)N1*4);
    float* Y      = (float*)alloc((size_t)N1*4);
    float* Z      = (float*)alloc((size_t)N1*4);
    int*   PERM1  = (int*)  alloc((size_t)N2*4);
    float* SSORT1 = (float*)alloc((size_t)N2*4);
    int*   NID    = (int*)  alloc((size_t)N1*4);
    int*   E1S    = (int*)  alloc((size_t)EE*4);
    int*   E1D    = (int*)  alloc((size_t)EE*4);
    int2*  RPX2   = (int2*) alloc((size_t)N2*8);
    int*   CUR2   = (int*)  alloc((size_t)N2*4);
    int*   EL2    = (int*)  alloc((size_t)EE*4);
    float* DINV2  = (float*)alloc((size_t)N2*4);
    int*   PERM2  = (int*)  alloc((size_t)N3*4);
    float* SSORT2 = (float*)alloc((size_t)N3*4);
    float* GBUF   = (float*)alloc((size_t)NB*128*4);
    int*   BS     = (int*)  alloc((size_t)128*4);
    _Float16* WH  = (_Float16*)alloc((size_t)131072*2);
    _Float16* WL  = (_Float16*)alloc((size_t)131072*2);
    const int o_g1 = 0, o_g2 = 16384, o_c1 = 81920, o_c2 = 114688;

    // ---- level-1 CSR (wide) + weight pre-split ----
    hipMemsetAsync(CUR, 0, (size_t)N1*4, stream);
    count_dst<<<EE/256, 256, 0, stream>>>(dst, CUR, EE);
    blocksum_k<<<N1/256, 256, 0, stream>>>(CUR, BS);
    scan_write_k<<<N1/256, 256, 0, stream>>>(CUR, BS, N1/256, RPX, CUR, DINV);
    scatter1<<<EE/256, 256, 0, stream>>>(src, dst, CUR, EL, EE);
    wsplit4<<<512, 256, 0, stream>>>(g1w, 16384, g2w, 65536, c1w, 32768, c2w, 16384, WH, WL);

    // ---- GAT layer 1 (64 -> 4x64, relu) ----
    gemm_h2<<<dim3(N1/128, 2), 256, 0, stream>>>(x, WH + o_g1, WL + o_g1, F0, N1, 64, 256, nullptr, nullptr);
    attn_pre<<<N1/4, 256, 0, stream>>>(F0, g1as, g1ad, AS, AD);
    gat_agg<1><<<N1/4, 256, 0, stream>>>(F0, AS, AD, g1b, RPX, EL, F1);

    // ---- GAT layer 2 (256 -> 4x64) ----
    gemm_h2<<<dim3(N1/128, 2), 256, 0, stream>>>(F1, WH + o_g2, WL + o_g2, F0, N1, 256, 256, nullptr, nullptr);
    attn_pre<<<N1/4, 256, 0, stream>>>(F0, g2as, g2ad, AS, AD);
    gat_agg<0><<<N1/4, 256, 0, stream>>>(F0, AS, AD, g2b, RPX, EL, F1);

    // ---- GCN1 (256 -> 128, relu) + fused SAG1 partial dots ----
    gemm_h2<<<dim3(N1/128, 1), 256, 0, stream>>>(F1, WH + o_c1, WL + o_c1, F0, N1, 256, 128, nullptr, nullptr);
    gcn_agg_sag<<<N1/4, 256, 0, stream>>>(F0, DINV, c1b, s1wrel, s1wroot, s1brel,
                                          RPX, EL, F1, Y, Z);

    // ---- SAGPool1: wide score gather + wave-level select ----
    sag_lite<<<N1/4, 256, 0, stream>>>(Y, Z, RPX, EL, SCORE);
    topk_wave<<<NB, 64, 0, stream>>>(SCORE, NPG1, KK1, PERM1, SSORT1, NID, 1);

    // ---- level-2 CSR (wide; remap + count fused) ----
    hipMemsetAsync(CUR2, 0, (size_t)N2*4, stream);
    remap_count<<<EE/256, 256, 0, stream>>>(src, dst, NID, E1S, E1D, CUR2, EE);
    blocksum_k<<<N2/256, 256, 0, stream>>>(CUR2, BS);
    scan_write_k<<<N2/256, 256, 0, stream>>>(CUR2, BS, N2/256, RPX2, CUR2, DINV2);
    scatter2<<<EE/256, 256, 0, stream>>>(E1S, E1D, CUR2, EL2, EE);

    // ---- GCN2 (128 -> 128, relu): GEMM reads F1 via perm * tanh (fused pool_gather)
    gemm_h2<<<dim3(N2/128, 1), 256, 0, stream>>>(F1, WH + o_c2, WL + o_c2, F0, N2, 128, 128, PERM1, SSORT1);
    gcn_agg_sag<<<N2/4, 256, 0, stream>>>(F0, DINV2, c2b, s2wrel, s2wroot, s2brel,
                                          RPX2, EL2, F2, Y, Z);

    // ---- SAGPool2: wide score gather + wave-level select ----
    sag_lite<<<N2/4, 256, 0, stream>>>(Y, Z, RPX2, EL2, SCORE);
    topk_wave<<<NB, 64, 0, stream>>>(SCORE, NPG2, KK2, PERM2, SSORT2, nullptr, 0);

    // ---- fused gather + mean pool + MLP ----
    pool_mean2<<<NB, 256, 0, stream>>>(F2, PERM2, SSORT2, GBUF);
    mlp_k<<<NB, 256, 0, stream>>>(GBUF, f1w, f1b, f2w, f2b, ow, ob, out);
}

// Round 12
// 314.762 us; speedup vs baseline: 2.4300x; 1.0658x over previous
//
#include <hip/hip_runtime.h>

#define N1 32768
#define EE 524288
#define NB 16
#define DEG 16
#define NPG1 2048
#define KK1 1024
#define N2 16384
#define NPG2 1024
#define KK2 512
#define N3 8192

typedef _Float16 half8_t __attribute__((ext_vector_type(8)));
typedef float floatx16 __attribute__((ext_vector_type(16)));

static __device__ __forceinline__ float leaky(float x){ return fmaxf(x, 0.2f*x); }

// ---------------- level-1 CSR build (wide) + fused weight split -------------
__global__ void count_split(const int* __restrict__ dst, int* __restrict__ cnt,
                            const float* __restrict__ w0, int n0,
                            const float* __restrict__ w1, int n1,
                            const float* __restrict__ w2, int n2,
                            const float* __restrict__ w3, int n3,
                            _Float16* __restrict__ wh, _Float16* __restrict__ wl){
    int b = blockIdx.x;
    int tid = threadIdx.x;
    if (b < EE/256){
        atomicAdd(&cnt[dst[b*256 + tid]], 1);
    } else {
        int i = (b - EE/256)*256 + tid;
        int n01 = n0 + n1, n012 = n01 + n2, nt = n012 + n3;
        if (i >= nt) return;
        float v = (i < n0) ? w0[i] : (i < n01) ? w1[i - n0] : (i < n012) ? w2[i - n01] : w3[i - n012];
        _Float16 h = (_Float16)v;
        wh[i] = h; wl[i] = (_Float16)(v - (float)h);
    }
}

__global__ void blocksum_k(const int* __restrict__ cnt, int* __restrict__ bs){
    __shared__ int red[4];
    int tid = threadIdx.x;
    int v = cnt[blockIdx.x*256 + tid];
    #pragma unroll
    for (int off = 32; off; off >>= 1) v += __shfl_xor(v, off);
    if ((tid & 63) == 0) red[tid >> 6] = v;
    __syncthreads();
    if (tid == 0) bs[blockIdx.x] = red[0] + red[1] + red[2] + red[3];
}

__global__ void scan_write_k(const int* __restrict__ cnt, const int* __restrict__ bs,
                             int nb, int2* __restrict__ rpx, int* __restrict__ cur,
                             float* __restrict__ dinv){
    __shared__ int sbs[128];
    __shared__ int wsum[4];
    int tid = threadIdx.x;
    int b = blockIdx.x;
    if (tid < nb) sbs[tid] = bs[tid];
    __syncthreads();
    for (int off = 1; off < nb; off <<= 1){
        int v = 0;
        if (tid < nb && tid >= off) v = sbs[tid - off];
        __syncthreads();
        if (tid < nb) sbs[tid] += v;
        __syncthreads();
    }
    int base = (b == 0) ? 0 : sbs[b-1];
    int i = b*256 + tid;
    int c = cnt[i];
    int lane = tid & 63, wv = tid >> 6;
    int x = c;
    #pragma unroll
    for (int off = 1; off < 64; off <<= 1){ int y = __shfl_up(x, off); if (lane >= off) x += y; }
    if (lane == 63) wsum[wv] = x;
    __syncthreads();
    if (tid == 0){ int run = 0; for (int w2 = 0; w2 < 4; w2++){ int t = wsum[w2]; wsum[w2] = run; run += t; } }
    __syncthreads();
    int excl = x - c + wsum[wv];
    int beg = base + excl;
    rpx[i]  = make_int2(beg, beg + c);
    cur[i]  = beg;
    dinv[i] = rsqrtf((float)c + 1.0f);
}

__global__ void scatter1(const int* __restrict__ src, const int* __restrict__ dst,
                         int* __restrict__ cur, int* __restrict__ esrc, int E){
    int i = blockIdx.x*blockDim.x + threadIdx.x;
    if (i < E){ int p = atomicAdd(&cur[dst[i]], 1); esrc[p] = src[i]; }
}

// ------- level-2 CSR: in-place bucket compaction with gaps (one kernel) -----
// new node d2's in-edges = selected subset of level-1 bucket of perm[d2].
__global__ void csr2_build(const int* __restrict__ perm, const int* __restrict__ nid,
                           const int2* __restrict__ rpx, const int* __restrict__ EL,
                           int2* __restrict__ rpx2, float* __restrict__ dinv2,
                           int* __restrict__ EL2){
    int lane = threadIdx.x & 63;
    int w = threadIdx.x >> 6;
    int d2 = blockIdx.x*4 + w;
    int old = __builtin_amdgcn_readfirstlane(perm[d2]);
    int2 re = rpx[old];
    int beg = re.x, end = re.y;
    unsigned long long below = (1ull << lane) - 1ull;   // lane 63: 0x7FFF... (ok)
    int cnt = 0;
    for (int i = beg; i < end; i += 64){
        int ii = i + lane;
        int sn = -1;
        if (ii < end) sn = nid[EL[ii]];
        bool take = sn >= 0;
        unsigned long long m = __ballot(take);
        int pos = cnt + __popcll(m & below);
        if (take) EL2[beg + pos] = sn;
        cnt += __popcll(m);
    }
    if (lane == 0){
        rpx2[d2] = make_int2(beg, beg + cnt);
        dinv2[d2] = rsqrtf((float)cnt + 1.0f);
    }
}

// ------------- split-fp16 MFMA GEMM: C = A @ W^T (fp32 A, pre-split W) ------
// optional row-gather + scale on A (perm != nullptr): A_eff[r] = A[perm[r]] * tt[r]
#define KS 64
static __device__ __forceinline__ int ldsoff(int row, int k8){
    return row*64 + ((k8 ^ (row & 7)) << 3);
}

__global__ __launch_bounds__(256, 2) void gemm_h2(const float* __restrict__ A,
        const _Float16* __restrict__ WHp, const _Float16* __restrict__ WLp,
        float* __restrict__ C, int n, int K, int M,
        const int* __restrict__ perm, const float* __restrict__ tt){
    __shared__ _Float16 sm[4*128*KS];
    _Float16* sAH = sm;
    _Float16* sAL = sm + 128*KS;
    _Float16* sWH = sm + 2*128*KS;
    _Float16* sWL = sm + 3*128*KS;
    int t = threadIdx.x;
    int lane = t & 63;
    int wid = t >> 6;
    int wr = wid >> 1, wc = wid & 1;
    int row0 = blockIdx.x*128, col0 = blockIdx.y*128;
    int srow = t >> 3;
    int sk8  = t & 7;

    floatx16 acc[2][2];
    #pragma unroll
    for (int i = 0; i < 2; i++)
        #pragma unroll
        for (int j = 0; j < 2; j++)
            #pragma unroll
            for (int q = 0; q < 16; q++) acc[i][j][q] = 0.f;

    for (int kk = 0; kk < K; kk += KS){
        #pragma unroll
        for (int p = 0; p < 4; p++){
            int r = srow + p*32;
            int rr = row0 + r;
            int arow = perm ? perm[rr] : rr;
            float tscale = perm ? tt[rr] : 1.0f;
            const float* ga = A + (size_t)arow*K + kk + sk8*8;
            float4 a0 = *(const float4*)ga;
            float4 a1 = *(const float4*)(ga + 4);
            half8_t ahi, alo;
            float av[8] = {a0.x,a0.y,a0.z,a0.w,a1.x,a1.y,a1.z,a1.w};
            #pragma unroll
            for (int q = 0; q < 8; q++){
                float v = av[q] * tscale;
                _Float16 h = (_Float16)v;
                ahi[q] = h; alo[q] = (_Float16)(v - (float)h);
            }
            size_t wo = (size_t)(col0 + r)*K + kk + sk8*8;
            half8_t whi = *(const half8_t*)(WHp + wo);
            half8_t wlo = *(const half8_t*)(WLp + wo);
            int o = ldsoff(r, sk8);
            *(half8_t*)&sAH[o] = ahi;
            *(half8_t*)&sAL[o] = alo;
            *(half8_t*)&sWH[o] = whi;
            *(half8_t*)&sWL[o] = wlo;
        }
        __syncthreads();
        #pragma unroll
        for (int kc = 0; kc < 4; kc++){
            int k8 = kc*2 + (lane >> 5);
            int ra = wr*64 + (lane & 31);
            int rb = wc*64 + (lane & 31);
            half8_t ah0 = *(const half8_t*)&sAH[ldsoff(ra,      k8)];
            half8_t ah1 = *(const half8_t*)&sAH[ldsoff(ra + 32, k8)];
            half8_t al0 = *(const half8_t*)&sAL[ldsoff(ra,      k8)];
            half8_t al1 = *(const half8_t*)&sAL[ldsoff(ra + 32, k8)];
            half8_t bh0 = *(const half8_t*)&sWH[ldsoff(rb,      k8)];
            half8_t bh1 = *(const half8_t*)&sWH[ldsoff(rb + 32, k8)];
            half8_t bl0 = *(const half8_t*)&sWL[ldsoff(rb,      k8)];
            half8_t bl1 = *(const half8_t*)&sWL[ldsoff(rb + 32, k8)];
            acc[0][0] = __builtin_amdgcn_mfma_f32_32x32x16_f16(ah0, bh0, acc[0][0], 0,0,0);
            acc[0][0] = __builtin_amdgcn_mfma_f32_32x32x16_f16(ah0, bl0, acc[0][0], 0,0,0);
            acc[0][0] = __builtin_amdgcn_mfma_f32_32x32x16_f16(al0, bh0, acc[0][0], 0,0,0);
            acc[0][1] = __builtin_amdgcn_mfma_f32_32x32x16_f16(ah0, bh1, acc[0][1], 0,0,0);
            acc[0][1] = __builtin_amdgcn_mfma_f32_32x32x16_f16(ah0, bl1, acc[0][1], 0,0,0);
            acc[0][1] = __builtin_amdgcn_mfma_f32_32x32x16_f16(al0, bh1, acc[0][1], 0,0,0);
            acc[1][0] = __builtin_amdgcn_mfma_f32_32x32x16_f16(ah1, bh0, acc[1][0], 0,0,0);
            acc[1][0] = __builtin_amdgcn_mfma_f32_32x32x16_f16(ah1, bl0, acc[1][0], 0,0,0);
            acc[1][0] = __builtin_amdgcn_mfma_f32_32x32x16_f16(al1, bh0, acc[1][0], 0,0,0);
            acc[1][1] = __builtin_amdgcn_mfma_f32_32x32x16_f16(ah1, bh1, acc[1][1], 0,0,0);
            acc[1][1] = __builtin_amdgcn_mfma_f32_32x32x16_f16(ah1, bl1, acc[1][1], 0,0,0);
            acc[1][1] = __builtin_amdgcn_mfma_f32_32x32x16_f16(al1, bh1, acc[1][1], 0,0,0);
        }
        __syncthreads();
    }
    #pragma unroll
    for (int rt = 0; rt < 2; rt++)
        #pragma unroll
        for (int ct = 0; ct < 2; ct++){
            int baser = row0 + wr*64 + rt*32 + 4*(lane >> 5);
            int c = col0 + wc*64 + ct*32 + (lane & 31);
            #pragma unroll
            for (int r = 0; r < 16; r++){
                int rr = baser + (r & 3) + 8*(r >> 2);
                C[(size_t)rr*M + c] = acc[rt][ct][r];
            }
        }
}

// ---------------- GAT attention coefficients ----------------
__global__ void attn_pre(const float* __restrict__ h, const float* __restrict__ wsrc,
                         const float* __restrict__ wdst, float* __restrict__ as_,
                         float* __restrict__ ad_){
    int lane = threadIdx.x & 63;
    int w = threadIdx.x >> 6;
    int d = blockIdx.x*4 + w;
    float4 hv = *(const float4*)(h + (size_t)d*256 + lane*4);
    float4 ws = *(const float4*)(wsrc + lane*4);
    float4 wd = *(const float4*)(wdst + lane*4);
    float ps = hv.x*ws.x + hv.y*ws.y + hv.z*ws.z + hv.w*ws.w;
    float pd = hv.x*wd.x + hv.y*wd.y + hv.z*wd.z + hv.w*wd.w;
    #pragma unroll
    for (int m = 8; m; m >>= 1){ ps += __shfl_xor(ps, m); pd += __shfl_xor(pd, m); }
    if ((lane & 15) == 0){
        as_[d*4 + (lane >> 4)] = ps;
        ad_[d*4 + (lane >> 4)] = pd;
    }
}

// ---- GAT aggregation: no-max softmax, 8-wide pipeline, scalarized node ids --
template<int RELU>
__global__ void gat_agg(const float* __restrict__ h, const float* __restrict__ as_,
                        const float* __restrict__ ad_, const float* __restrict__ bias,
                        const int2* __restrict__ rpx, const int* __restrict__ esrc,
                        float* __restrict__ out){
    int lane = threadIdx.x & 63;
    int nb = gridDim.x;
    int b = blockIdx.x;
    int sb = (b & 7)*(nb >> 3) + (b >> 3);
    int d = __builtin_amdgcn_readfirstlane(sb*4 + (int)(threadIdx.x >> 6));
    int2 re = rpx[d];
    int beg = re.x, end = re.y;

    int hh = lane >> 4;
    float adh = ad_[(d<<2) + hh];
    float aself = as_[(d<<2) + hh];

    float dn[4];
    dn[0] = __expf(leaky(aself + adh)); dn[1] = 0.f; dn[2] = 0.f; dn[3] = 0.f;
    float4 hd = ((const float4*)(h + ((size_t)d<<8)))[lane];
    float4 AX[4];
    AX[0].x = dn[0]*hd.x; AX[0].y = dn[0]*hd.y; AX[0].z = dn[0]*hd.z; AX[0].w = dn[0]*hd.w;
    AX[1] = {0,0,0,0}; AX[2] = {0,0,0,0}; AX[3] = {0,0,0,0};

    int i = beg;
    int endu = beg + ((end - beg) & ~7);
    for (; i < endu; i += 8){
        int s_[8];
        #pragma unroll
        for (int j = 0; j < 8; j++) s_[j] = __builtin_amdgcn_readfirstlane(esrc[i + j]);
        float a_[8];
        #pragma unroll
        for (int j = 0; j < 8; j++) a_[j] = as_[(s_[j]<<2) + hh];
        float4 hv_[8];
        #pragma unroll
        for (int j = 0; j < 8; j++) hv_[j] = ((const float4*)(h + ((size_t)s_[j]<<8)))[lane];
        #pragma unroll
        for (int j = 0; j < 8; j++){
            float x = a_[j] + adh;
            float p = __expf(fmaxf(x, 0.2f*x));
            dn[j & 3] += p;
            AX[j & 3].x = fmaf(p, hv_[j].x, AX[j & 3].x);
            AX[j & 3].y = fmaf(p, hv_[j].y, AX[j & 3].y);
            AX[j & 3].z = fmaf(p, hv_[j].z, AX[j & 3].z);
            AX[j & 3].w = fmaf(p, hv_[j].w, AX[j & 3].w);
        }
    }
    for (; i < end; ++i){
        int s = __builtin_amdgcn_readfirstlane(esrc[i]);
        float x = as_[(s<<2) + hh] + adh;
        float4 hv = ((const float4*)(h + ((size_t)s<<8)))[lane];
        float p = __expf(fmaxf(x, 0.2f*x));
        dn[0] += p;
        AX[0].x = fmaf(p, hv.x, AX[0].x); AX[0].y = fmaf(p, hv.y, AX[0].y);
        AX[0].z = fmaf(p, hv.z, AX[0].z); AX[0].w = fmaf(p, hv.w, AX[0].w);
    }
    float den = ((dn[0] + dn[1]) + (dn[2] + dn[3])) + 1e-16f;
    float r = 1.0f / den;
    int c0 = lane*4;
    float4 bv = *(const float4*)(bias + c0);
    float4 acc;
    acc.x = ((AX[0].x+AX[1].x)+(AX[2].x+AX[3].x))*r + bv.x;
    acc.y = ((AX[0].y+AX[1].y)+(AX[2].y+AX[3].y))*r + bv.y;
    acc.z = ((AX[0].z+AX[1].z)+(AX[2].z+AX[3].z))*r + bv.z;
    acc.w = ((AX[0].w+AX[1].w)+(AX[2].w+AX[3].w))*r + bv.w;
    if (RELU){
        acc.x = fmaxf(acc.x, 0.f); acc.y = fmaxf(acc.y, 0.f);
        acc.z = fmaxf(acc.z, 0.f); acc.w = fmaxf(acc.w, 0.f);
    }
    ((float4*)(out + ((size_t)d<<8)))[lane] = acc;
}

// ---- GCN aggregation + fused SAG-score partial dots, scalarized node ids ----
__global__ void gcn_agg_sag(const float* __restrict__ h, const float* __restrict__ dinv,
                            const float* __restrict__ bias,
                            const float* __restrict__ wrel, const float* __restrict__ wroot,
                            const float* __restrict__ brel,
                            const int2* __restrict__ rpx, const int* __restrict__ esrc,
                            float* __restrict__ out, float* __restrict__ Y, float* __restrict__ Z){
    int lane = threadIdx.x & 63;
    int nb = gridDim.x;
    int b = blockIdx.x;
    int sb = (b & 7)*(nb >> 3) + (b >> 3);
    int d = __builtin_amdgcn_readfirstlane(sb*4 + (int)(threadIdx.x >> 6));
    int2 re = rpx[d];
    int beg = re.x, end = re.y;
    float dv = dinv[d];
    int c0 = lane*2;
    float2 hd = ((const float2*)(h + ((size_t)d<<7)))[lane];
    float self = dv*dv;
    float ax[4] = {self*hd.x, 0.f, 0.f, 0.f};
    float ay[4] = {self*hd.y, 0.f, 0.f, 0.f};
    int i = beg;
    int endu = beg + ((end - beg) & ~7);
    for (; i < endu; i += 8){
        int s_[8];
        #pragma unroll
        for (int j = 0; j < 8; j++) s_[j] = __builtin_amdgcn_readfirstlane(esrc[i + j]);
        float di_[8];
        #pragma unroll
        for (int j = 0; j < 8; j++) di_[j] = dinv[s_[j]];
        float2 hv_[8];
        #pragma unroll
        for (int j = 0; j < 8; j++) hv_[j] = ((const float2*)(h + ((size_t)s_[j]<<7)))[lane];
        #pragma unroll
        for (int j = 0; j < 8; j++){
            float coef = di_[j]*dv;
            ax[j & 3] = fmaf(coef, hv_[j].x, ax[j & 3]);
            ay[j & 3] = fmaf(coef, hv_[j].y, ay[j & 3]);
        }
    }
    for (; i < end; ++i){
        int s = __builtin_amdgcn_readfirstlane(esrc[i]);
        float coef = dinv[s]*dv;
        float2 hv = ((const float2*)(h + ((size_t)s<<7)))[lane];
        ax[0] = fmaf(coef, hv.x, ax[0]); ay[0] = fmaf(coef, hv.y, ay[0]);
    }
    float axs = ((ax[0]+ax[1])+(ax[2]+ax[3]));
    float ays = ((ay[0]+ay[1])+(ay[2]+ay[3]));
    axs = fmaxf(axs + bias[c0], 0.f);
    ays = fmaxf(ays + bias[c0+1], 0.f);
    float2 o; o.x = axs; o.y = ays;
    ((float2*)(out + ((size_t)d<<7)))[lane] = o;
    float py = axs*wrel[c0]  + ays*wrel[c0+1];
    float pz = axs*wroot[c0] + ays*wroot[c0+1];
    #pragma unroll
    for (int off = 32; off; off >>= 1){ py += __shfl_xor(py, off); pz += __shfl_xor(pz, off); }
    if (lane == 0){ Y[d] = py; Z[d] = pz + brel[0]; }
}

// ---------------- SAG score via scalar gather (wide) ----------------
__global__ void sag_lite(const float* __restrict__ Y, const float* __restrict__ Z,
                         const int2* __restrict__ rpx, const int* __restrict__ esrc,
                         float* __restrict__ score){
    int lane = threadIdx.x & 63;
    int w = threadIdx.x >> 6;
    int nb = gridDim.x;
    int b = blockIdx.x;
    int sb = (b & 7)*(nb >> 3) + (b >> 3);
    int d = sb*4 + w;
    int2 re = rpx[d];
    float s = 0.f;
    for (int i = re.x + lane; i < re.y; i += 64) s += Y[esrc[i]];
    #pragma unroll
    for (int off = 32; off; off >>= 1) s += __shfl_xor(s, off);
    if (lane == 0) score[d] = s + Z[d];
}

// ------- barrier-free wave-per-graph radix-select top-k ---------------------
__global__ __launch_bounds__(64) void topk_wave(const float* __restrict__ score,
        int npg, int k, int* __restrict__ perm, float* __restrict__ ssort,
        int* __restrict__ nid, int writeNid){
    __shared__ unsigned keys[2048];
    __shared__ int hist[256];
    int g = blockIdx.x;
    int lane = threadIdx.x;
    int nch = npg >> 6;
    for (int c = 0; c < nch; c++){
        unsigned u = __float_as_uint(score[g*npg + c*64 + lane]);
        keys[c*64 + lane] = (u & 0x80000000u) ? ~u : (u | 0x80000000u);
    }
    int need = k;
    unsigned prefix = 0u, pmask = 0u;
    #pragma unroll
    for (int shift = 24; shift >= 0; shift -= 8){
        #pragma unroll
        for (int q = 0; q < 4; q++) hist[lane*4 + q] = 0;
        for (int c = 0; c < nch; c++){
            unsigned u = keys[c*64 + lane];
            if ((u & pmask) == prefix) atomicAdd(&hist[(u >> shift) & 255u], 1);
        }
        int h0 = hist[lane*4], h1 = hist[lane*4+1], h2 = hist[lane*4+2], h3 = hist[lane*4+3];
        int s3 = h3, s2 = h2 + s3, s1 = h1 + s2, s0 = h0 + s1;
        int tot = s0;
        int suf = tot;
        #pragma unroll
        for (int off = 1; off < 64; off <<= 1){
            int v = __shfl_down(suf, off);
            if (lane + off < 64) suf += v;
        }
        int above_quad = suf - tot;
        int c0 = s0 + above_quad, c1 = s1 + above_quad, c2 = s2 + above_quad, c3 = s3 + above_quad;
        int sel = -1;
        if (c0 >= need && c1 < need) sel = 0;
        if (c1 >= need && c2 < need) sel = 1;
        if (c2 >= need && c3 < need) sel = 2;
        if (c3 >= need && above_quad < need) sel = 3;
        unsigned long long msk = __ballot(sel >= 0);
        int srcl = __ffsll((long long)msk) - 1;
        int binq = __shfl(sel, srcl);
        int bin = srcl*4 + binq;
        int cge_next = (binq == 0) ? __shfl(c1, srcl) :
                       (binq == 1) ? __shfl(c2, srcl) :
                       (binq == 2) ? __shfl(c3, srcl) : __shfl(above_quad, srcl);
        need -= cge_next;
        prefix |= ((unsigned)bin) << shift;
        pmask  |= 255u << shift;
    }
    unsigned thr = prefix;
    int m = need;
    unsigned long long below = (lane == 63) ? 0x7FFFFFFFFFFFFFFFull : ((1ull << lane) - 1ull);
    int base = 0, eqbase = 0;
    for (int c = 0; c < nch; c++){
        unsigned u = keys[c*64 + lane];
        bool gt = u > thr;
        bool eq = (u == thr);
        unsigned long long meq = __ballot(eq);
        int eqrank = eqbase + __popcll(meq & below);
        bool take = gt || (eq && eqrank < m);
        unsigned long long mtk = __ballot(take);
        int pos = base + __popcll(mtk & below);
        int node = g*npg + c*64 + lane;
        if (take){
            perm[g*k + pos] = node;
            ssort[g*k + pos] = tanhf(score[node]);
            if (writeNid) nid[node] = g*k + pos;
        } else if (writeNid) nid[node] = -1;
        base += __popcll(mtk);
        eqbase += __popcll(meq);
    }
}

// ------ fused final: gather+mean pool then 3-layer MLP (one block/graph) ----
__global__ void pool_mlp(const float* __restrict__ x, const int* __restrict__ perm,
                         const float* __restrict__ ssort,
                         const float* __restrict__ fc1w, const float* __restrict__ fc1b,
                         const float* __restrict__ fc2w, const float* __restrict__ fc2b,
                         const float* __restrict__ ow,  const float* __restrict__ ob,
                         float* __restrict__ out){
    __shared__ float tt[KK2];
    __shared__ float part[128];
    __shared__ float gv[128], t1[256], t2[128];
    int b = blockIdx.x, t = threadIdx.x;     // 256 threads
    tt[t]       = ssort[b*KK2 + t];
    tt[t + 256] = ssort[b*KK2 + t + 256];
    __syncthreads();
    int c = t & 127, half = t >> 7;
    float s = 0.f;
    #pragma unroll 4
    for (int i = half*256; i < half*256 + 256; i++){
        int o = perm[b*KK2 + i];
        s = fmaf(tt[i], x[(size_t)o*128 + c], s);
    }
    if (half) part[c] = s;
    __syncthreads();
    if (!half) gv[c] = (s + part[c]) * (1.0f/KK2);
    __syncthreads();
    {
        float s1 = fc1b[t];
        for (int cc = 0; cc < 128; cc++) s1 += gv[cc]*fc1w[t*128 + cc];
        t1[t] = fmaxf(s1, 0.f);
    }
    __syncthreads();
    if (t < 128){
        float s2 = fc2b[t];
        for (int cc = 0; cc < 256; cc++) s2 += t1[cc]*fc2w[t*256 + cc];
        t2[t] = fmaxf(s2, 0.f);
    }
    __syncthreads();
    if (t < 10){
        float s3 = ob[t];
        for (int cc = 0; cc < 128; cc++) s3 += t2[cc]*ow[t*128 + cc];
        out[b*10 + t] = s3;
    }
}

// ---------------- launch ----------------
extern "C" void kernel_launch(void* const* d_in, const int* in_sizes, int n_in,
                              void* d_out, int out_size, void* d_ws, size_t ws_size,
                              hipStream_t stream){
    (void)in_sizes; (void)n_in; (void)out_size; (void)ws_size;
    const float* x    = (const float*)d_in[0];
    const int*   eidx = (const int*)d_in[1];
    const int*   src  = eidx;
    const int*   dst  = eidx + EE;
    const float* g1w  = (const float*)d_in[3];
    const float* g1as = (const float*)d_in[4];
    const float* g1ad = (const float*)d_in[5];
    const float* g1b  = (const float*)d_in[6];
    const float* g2w  = (const float*)d_in[7];
    const float* g2as = (const float*)d_in[8];
    const float* g2ad = (const float*)d_in[9];
    const float* g2b  = (const float*)d_in[10];
    const float* c1w  = (const float*)d_in[11];
    const float* c1b  = (const float*)d_in[12];
    const float* s1wrel  = (const float*)d_in[13];
    const float* s1brel  = (const float*)d_in[14];
    const float* s1wroot = (const float*)d_in[15];
    const float* c2w  = (const float*)d_in[16];
    const float* c2b  = (const float*)d_in[17];
    const float* s2wrel  = (const float*)d_in[18];
    const float* s2brel  = (const float*)d_in[19];
    const float* s2wroot = (const float*)d_in[20];
    const float* f1w  = (const float*)d_in[21];
    const float* f1b  = (const float*)d_in[22];
    const float* f2w  = (const float*)d_in[23];
    const float* f2b  = (const float*)d_in[24];
    const float* ow   = (const float*)d_in[25];
    const float* ob   = (const float*)d_in[26];
    float* out = (float*)d_out;

    char* ws = (char*)d_ws;
    size_t off = 0;
    auto alloc = [&](size_t bytes)->char*{
        char* p = ws + off;
        off += (bytes + 255) & ~(size_t)255;
        return p;
    };
    float* F0     = (float*)alloc((size_t)N1*256*4);
    float* F1     = (float*)alloc((size_t)N1*256*4);
    float* F2     = (float*)alloc((size_t)N2*128*4);
    float* AS     = (float*)alloc((size_t)N1*4*4);
    float* AD     = (float*)alloc((size_t)N1*4*4);
    int2*  RPX    = (int2*) alloc((size_t)N1*8);
    int*   CUR    = (int*)  alloc((size_t)N1*4);
    int*   EL     = (int*)  alloc((size_t)EE*4);
    float* DINV   = (float*)alloc((size_t)N1*4);
    float* SCORE  = (float*)alloc((size_t)N1*4);
    float* Y      = (float*)alloc((size_t)N1*4);
    float* Z      = (float*)alloc((size_t)N1*4);
    int*   PERM1  = (int*)  alloc((size_t)N2*4);
    float* SSORT1 = (float*)alloc((size_t)N2*4);
    int*   NID    = (int*)  alloc((size_t)N1*4);
    int2*  RPX2   = (int2*) alloc((size_t)N2*8);
    int*   EL2    = (int*)  alloc((size_t)EE*4);
    float* DINV2  = (float*)alloc((size_t)N2*4);
    int*   PERM2  = (int*)  alloc((size_t)N3*4);
    float* SSORT2 = (float*)alloc((size_t)N3*4);
    int*   BS     = (int*)  alloc((size_t)128*4);
    _Float16* WH  = (_Float16*)alloc((size_t)131072*2);
    _Float16* WL  = (_Float16*)alloc((size_t)131072*2);
    const int o_g1 = 0, o_g2 = 16384, o_c1 = 81920, o_c2 = 114688;

    // ---- level-1 CSR (wide) with fused weight pre-split ----
    hipMemsetAsync(CUR, 0, (size_t)N1*4, stream);
    count_split<<<EE/256 + 512, 256, 0, stream>>>(dst, CUR,
        g1w, 16384, g2w, 65536, c1w, 32768, c2w, 16384, WH, WL);
    blocksum_k<<<N1/256, 256, 0, stream>>>(CUR, BS);
    scan_write_k<<<N1/256, 256, 0, stream>>>(CUR, BS, N1/256, RPX, CUR, DINV);
    scatter1<<<EE/256, 256, 0, stream>>>(src, dst, CUR, EL, EE);

    // ---- GAT layer 1 (64 -> 4x64, relu) ----
    gemm_h2<<<dim3(N1/128, 2), 256, 0, stream>>>(x, WH + o_g1, WL + o_g1, F0, N1, 64, 256, nullptr, nullptr);
    attn_pre<<<N1/4, 256, 0, stream>>>(F0, g1as, g1ad, AS, AD);
    gat_agg<1><<<N1/4, 256, 0, stream>>>(F0, AS, AD, g1b, RPX, EL, F1);

    // ---- GAT layer 2 (256 -> 4x64) ----
    gemm_h2<<<dim3(N1/128, 2), 256, 0, stream>>>(F1, WH + o_g2, WL + o_g2, F0, N1, 256, 256, nullptr, nullptr);
    attn_pre<<<N1/4, 256, 0, stream>>>(F0, g2as, g2ad, AS, AD);
    gat_agg<0><<<N1/4, 256, 0, stream>>>(F0, AS, AD, g2b, RPX, EL, F1);

    // ---- GCN1 (256 -> 128, relu) + fused SAG1 partial dots ----
    gemm_h2<<<dim3(N1/128, 1), 256, 0, stream>>>(F1, WH + o_c1, WL + o_c1, F0, N1, 256, 128, nullptr, nullptr);
    gcn_agg_sag<<<N1/4, 256, 0, stream>>>(F0, DINV, c1b, s1wrel, s1wroot, s1brel,
                                          RPX, EL, F1, Y, Z);

    // ---- SAGPool1: wide score gather + wave-level select ----
    sag_lite<<<N1/4, 256, 0, stream>>>(Y, Z, RPX, EL, SCORE);
    topk_wave<<<NB, 64, 0, stream>>>(SCORE, NPG1, KK1, PERM1, SSORT1, NID, 1);

    // ---- level-2 CSR: single-kernel in-place bucket compaction ----
    csr2_build<<<N2/4, 256, 0, stream>>>(PERM1, NID, RPX, EL, RPX2, DINV2, EL2);

    // ---- GCN2 (128 -> 128, relu): GEMM reads F1 via perm * tanh ----
    gemm_h2<<<dim3(N2/128, 1), 256, 0, stream>>>(F1, WH + o_c2, WL + o_c2, F0, N2, 128, 128, PERM1, SSORT1);
    gcn_agg_sag<<<N2/4, 256, 0, stream>>>(F0, DINV2, c2b, s2wrel, s2wroot, s2brel,
                                          RPX2, EL2, F2, Y, Z);

    // ---- SAGPool2: wide score gather + wave-level select ----
    sag_lite<<<N2/4, 256, 0, stream>>>(Y, Z, RPX2, EL2, SCORE);
    topk_wave<<<NB, 64, 0, stream>>>(SCORE, NPG2, KK2, PERM2, SSORT2, nullptr, 0);

    // ---- fused gather + mean pool + MLP ----
    pool_mlp<<<NB, 256, 0, stream>>>(F2, PERM2, SSORT2,
                                     f1w, f1b, f2w, f2b, ow, ob, out);
}

// Round 13
// 289.643 us; speedup vs baseline: 2.6407x; 1.0867x over previous
//
#include <hip/hip_runtime.h>

#define N1 32768
#define EE 524288
#define NB 16
#define DEG 16
#define NPG1 2048
#define KK1 1024
#define N2 16384
#define NPG2 1024
#define KK2 512
#define N3 8192
#define CAP 64            // per-node bucket capacity (P(deg>64) ~ 1e-45)

typedef _Float16 half8_t __attribute__((ext_vector_type(8)));
typedef float floatx16 __attribute__((ext_vector_type(16)));

static __device__ __forceinline__ float leaky(float x){ return fmaxf(x, 0.2f*x); }

// ---- CSR1: single scatter into fixed-capacity buckets + fused weight split --
__global__ void scatter_split(const int* __restrict__ src, const int* __restrict__ dst,
                              int* __restrict__ cnt, int* __restrict__ esrc,
                              const float* __restrict__ w0, int n0,
                              const float* __restrict__ w1, int n1,
                              const float* __restrict__ w2, int n2,
                              const float* __restrict__ w3, int n3,
                              _Float16* __restrict__ wh, _Float16* __restrict__ wl){
    int b = blockIdx.x;
    int tid = threadIdx.x;
    if (b < EE/256){
        int i = b*256 + tid;
        int d = dst[i];
        int p = atomicAdd(&cnt[d], 1);
        esrc[(d << 6) + p] = src[i];
    } else {
        int i = (b - EE/256)*256 + tid;
        int n01 = n0 + n1, n012 = n01 + n2, nt = n012 + n3;
        if (i >= nt) return;
        float v = (i < n0) ? w0[i] : (i < n01) ? w1[i - n0] : (i < n012) ? w2[i - n01] : w3[i - n012];
        _Float16 h = (_Float16)v;
        wh[i] = h; wl[i] = (_Float16)(v - (float)h);
    }
}

// ---- CSR2: in-place bucket compaction with gaps (one kernel) ----
__global__ void csr2_build(const int* __restrict__ perm, const int* __restrict__ nid,
                           const int* __restrict__ cnt, const int* __restrict__ EL,
                           int2* __restrict__ rpx2, float* __restrict__ dinv2,
                           int* __restrict__ EL2){
    int lane = threadIdx.x & 63;
    int w = threadIdx.x >> 6;
    int d2 = blockIdx.x*4 + w;
    int old = __builtin_amdgcn_readfirstlane(perm[d2]);
    int beg = old << 6;
    int end = beg + cnt[old];
    unsigned long long below = (1ull << lane) - 1ull;
    int c2 = 0;
    for (int i = beg; i < end; i += 64){
        int ii = i + lane;
        int sn = -1;
        if (ii < end) sn = nid[EL[ii]];
        bool take = sn >= 0;
        unsigned long long m = __ballot(take);
        int pos = c2 + __popcll(m & below);
        if (take) EL2[beg + pos] = sn;
        c2 += __popcll(m);
    }
    if (lane == 0){
        rpx2[d2] = make_int2(beg, beg + c2);
        dinv2[d2] = rsqrtf((float)c2 + 1.0f);
    }
}

// ------------- split-fp16 MFMA GEMM + optional fused attn-dots --------------
// optional row-gather+scale on A (perm); optional attn epilogue (asrc!=null):
// AS[row*4+h]=sum_c C[row][c]*asrc[c], same for AD (heads partitioned by block).
#define KS 64
static __device__ __forceinline__ int ldsoff(int row, int k8){
    return row*64 + ((k8 ^ (row & 7)) << 3);
}

__global__ __launch_bounds__(256, 2) void gemm_h2(const float* __restrict__ A,
        const _Float16* __restrict__ WHp, const _Float16* __restrict__ WLp,
        float* __restrict__ C, int n, int K, int M,
        const int* __restrict__ perm, const float* __restrict__ tt,
        const float* __restrict__ asrc, const float* __restrict__ adst,
        float* __restrict__ AS, float* __restrict__ AD){
    __shared__ _Float16 sm[4*128*KS];
    _Float16* sAH = sm;
    _Float16* sAL = sm + 128*KS;
    _Float16* sWH = sm + 2*128*KS;
    _Float16* sWL = sm + 3*128*KS;
    int t = threadIdx.x;
    int lane = t & 63;
    int wid = t >> 6;
    int wr = wid >> 1, wc = wid & 1;
    int row0 = blockIdx.x*128, col0 = blockIdx.y*128;
    int srow = t >> 3;
    int sk8  = t & 7;

    floatx16 acc[2][2];
    #pragma unroll
    for (int i = 0; i < 2; i++)
        #pragma unroll
        for (int j = 0; j < 2; j++)
            #pragma unroll
            for (int q = 0; q < 16; q++) acc[i][j][q] = 0.f;

    for (int kk = 0; kk < K; kk += KS){
        #pragma unroll
        for (int p = 0; p < 4; p++){
            int r = srow + p*32;
            int rr = row0 + r;
            int arow = perm ? perm[rr] : rr;
            float tscale = perm ? tt[rr] : 1.0f;
            const float* ga = A + (size_t)arow*K + kk + sk8*8;
            float4 a0 = *(const float4*)ga;
            float4 a1 = *(const float4*)(ga + 4);
            half8_t ahi, alo;
            float av[8] = {a0.x,a0.y,a0.z,a0.w,a1.x,a1.y,a1.z,a1.w};
            #pragma unroll
            for (int q = 0; q < 8; q++){
                float v = av[q] * tscale;
                _Float16 h = (_Float16)v;
                ahi[q] = h; alo[q] = (_Float16)(v - (float)h);
            }
            size_t wo = (size_t)(col0 + r)*K + kk + sk8*8;
            half8_t whi = *(const half8_t*)(WHp + wo);
            half8_t wlo = *(const half8_t*)(WLp + wo);
            int o = ldsoff(r, sk8);
            *(half8_t*)&sAH[o] = ahi;
            *(half8_t*)&sAL[o] = alo;
            *(half8_t*)&sWH[o] = whi;
            *(half8_t*)&sWL[o] = wlo;
        }
        __syncthreads();
        #pragma unroll
        for (int kc = 0; kc < 4; kc++){
            int k8 = kc*2 + (lane >> 5);
            int ra = wr*64 + (lane & 31);
            int rb = wc*64 + (lane & 31);
            half8_t ah0 = *(const half8_t*)&sAH[ldsoff(ra,      k8)];
            half8_t ah1 = *(const half8_t*)&sAH[ldsoff(ra + 32, k8)];
            half8_t al0 = *(const half8_t*)&sAL[ldsoff(ra,      k8)];
            half8_t al1 = *(const half8_t*)&sAL[ldsoff(ra + 32, k8)];
            half8_t bh0 = *(const half8_t*)&sWH[ldsoff(rb,      k8)];
            half8_t bh1 = *(const half8_t*)&sWH[ldsoff(rb + 32, k8)];
            half8_t bl0 = *(const half8_t*)&sWL[ldsoff(rb,      k8)];
            half8_t bl1 = *(const half8_t*)&sWL[ldsoff(rb + 32, k8)];
            acc[0][0] = __builtin_amdgcn_mfma_f32_32x32x16_f16(ah0, bh0, acc[0][0], 0,0,0);
            acc[0][0] = __builtin_amdgcn_mfma_f32_32x32x16_f16(ah0, bl0, acc[0][0], 0,0,0);
            acc[0][0] = __builtin_amdgcn_mfma_f32_32x32x16_f16(al0, bh0, acc[0][0], 0,0,0);
            acc[0][1] = __builtin_amdgcn_mfma_f32_32x32x16_f16(ah0, bh1, acc[0][1], 0,0,0);
            acc[0][1] = __builtin_amdgcn_mfma_f32_32x32x16_f16(ah0, bl1, acc[0][1], 0,0,0);
            acc[0][1] = __builtin_amdgcn_mfma_f32_32x32x16_f16(al0, bh1, acc[0][1], 0,0,0);
            acc[1][0] = __builtin_amdgcn_mfma_f32_32x32x16_f16(ah1, bh0, acc[1][0], 0,0,0);
            acc[1][0] = __builtin_amdgcn_mfma_f32_32x32x16_f16(ah1, bl0, acc[1][0], 0,0,0);
            acc[1][0] = __builtin_amdgcn_mfma_f32_32x32x16_f16(al1, bh0, acc[1][0], 0,0,0);
            acc[1][1] = __builtin_amdgcn_mfma_f32_32x32x16_f16(ah1, bh1, acc[1][1], 0,0,0);
            acc[1][1] = __builtin_amdgcn_mfma_f32_32x32x16_f16(ah1, bl1, acc[1][1], 0,0,0);
            acc[1][1] = __builtin_amdgcn_mfma_f32_32x32x16_f16(al1, bh1, acc[1][1], 0,0,0);
        }
        __syncthreads();
    }
    #pragma unroll
    for (int rt = 0; rt < 2; rt++)
        #pragma unroll
        for (int ct = 0; ct < 2; ct++){
            int baser = row0 + wr*64 + rt*32 + 4*(lane >> 5);
            int c = col0 + wc*64 + ct*32 + (lane & 31);
            #pragma unroll
            for (int r = 0; r < 16; r++){
                int rr = baser + (r & 3) + 8*(r >> 2);
                C[(size_t)rr*M + c] = acc[rt][ct][r];
            }
        }
    // fused attention dot-products (GAT layers): wave covers one head
    if (asrc){
        int hh = (col0 >> 6) + wc;
        float a_s0 = asrc[col0 + wc*64 +  0 + (lane & 31)];
        float a_s1 = asrc[col0 + wc*64 + 32 + (lane & 31)];
        float a_d0 = adst[col0 + wc*64 +  0 + (lane & 31)];
        float a_d1 = adst[col0 + wc*64 + 32 + (lane & 31)];
        #pragma unroll
        for (int rt = 0; rt < 2; rt++){
            floatx16 vs, vd;
            #pragma unroll
            for (int r = 0; r < 16; r++){
                vs[r] = acc[rt][0][r]*a_s0 + acc[rt][1][r]*a_s1;
                vd[r] = acc[rt][0][r]*a_d0 + acc[rt][1][r]*a_d1;
            }
            #pragma unroll
            for (int off = 1; off < 32; off <<= 1){
                #pragma unroll
                for (int r = 0; r < 16; r++){
                    vs[r] += __shfl_xor(vs[r], off);
                    vd[r] += __shfl_xor(vd[r], off);
                }
            }
            if ((lane & 31) == 0){
                int baser = row0 + wr*64 + rt*32 + 4*(lane >> 5);
                #pragma unroll
                for (int r = 0; r < 16; r++){
                    int rr = baser + (r & 3) + 8*(r >> 2);
                    AS[rr*4 + hh] = vs[r];
                    AD[rr*4 + hh] = vd[r];
                }
            }
        }
    }
}

// ---- GAT aggregation: cnt-based buckets, no-max softmax, 8-wide pipeline ----
template<int RELU>
__global__ void gat_agg(const float* __restrict__ h, const float* __restrict__ as_,
                        const float* __restrict__ ad_, const float* __restrict__ bias,
                        const int* __restrict__ cnt, const int* __restrict__ esrc,
                        float* __restrict__ out){
    int lane = threadIdx.x & 63;
    int nb = gridDim.x;
    int b = blockIdx.x;
    int sb = (b & 7)*(nb >> 3) + (b >> 3);
    int d = __builtin_amdgcn_readfirstlane(sb*4 + (int)(threadIdx.x >> 6));
    int beg = d << 6;
    int end = beg + cnt[d];

    int hh = lane >> 4;
    float adh = ad_[(d<<2) + hh];
    float aself = as_[(d<<2) + hh];

    float dn[4];
    dn[0] = __expf(leaky(aself + adh)); dn[1] = 0.f; dn[2] = 0.f; dn[3] = 0.f;
    float4 hd = ((const float4*)(h + ((size_t)d<<8)))[lane];
    float4 AX[4];
    AX[0].x = dn[0]*hd.x; AX[0].y = dn[0]*hd.y; AX[0].z = dn[0]*hd.z; AX[0].w = dn[0]*hd.w;
    AX[1] = {0,0,0,0}; AX[2] = {0,0,0,0}; AX[3] = {0,0,0,0};

    int i = beg;
    int endu = beg + ((end - beg) & ~7);
    for (; i < endu; i += 8){
        int s_[8];
        #pragma unroll
        for (int j = 0; j < 8; j++) s_[j] = __builtin_amdgcn_readfirstlane(esrc[i + j]);
        float a_[8];
        #pragma unroll
        for (int j = 0; j < 8; j++) a_[j] = as_[(s_[j]<<2) + hh];
        float4 hv_[8];
        #pragma unroll
        for (int j = 0; j < 8; j++) hv_[j] = ((const float4*)(h + ((size_t)s_[j]<<8)))[lane];
        #pragma unroll
        for (int j = 0; j < 8; j++){
            float x = a_[j] + adh;
            float p = __expf(fmaxf(x, 0.2f*x));
            dn[j & 3] += p;
            AX[j & 3].x = fmaf(p, hv_[j].x, AX[j & 3].x);
            AX[j & 3].y = fmaf(p, hv_[j].y, AX[j & 3].y);
            AX[j & 3].z = fmaf(p, hv_[j].z, AX[j & 3].z);
            AX[j & 3].w = fmaf(p, hv_[j].w, AX[j & 3].w);
        }
    }
    for (; i < end; ++i){
        int s = __builtin_amdgcn_readfirstlane(esrc[i]);
        float x = as_[(s<<2) + hh] + adh;
        float4 hv = ((const float4*)(h + ((size_t)s<<8)))[lane];
        float p = __expf(fmaxf(x, 0.2f*x));
        dn[0] += p;
        AX[0].x = fmaf(p, hv.x, AX[0].x); AX[0].y = fmaf(p, hv.y, AX[0].y);
        AX[0].z = fmaf(p, hv.z, AX[0].z); AX[0].w = fmaf(p, hv.w, AX[0].w);
    }
    float den = ((dn[0] + dn[1]) + (dn[2] + dn[3])) + 1e-16f;
    float r = 1.0f / den;
    int c0 = lane*4;
    float4 bv = *(const float4*)(bias + c0);
    float4 acc;
    acc.x = ((AX[0].x+AX[1].x)+(AX[2].x+AX[3].x))*r + bv.x;
    acc.y = ((AX[0].y+AX[1].y)+(AX[2].y+AX[3].y))*r + bv.y;
    acc.z = ((AX[0].z+AX[1].z)+(AX[2].z+AX[3].z))*r + bv.z;
    acc.w = ((AX[0].w+AX[1].w)+(AX[2].w+AX[3].w))*r + bv.w;
    if (RELU){
        acc.x = fmaxf(acc.x, 0.f); acc.y = fmaxf(acc.y, 0.f);
        acc.z = fmaxf(acc.z, 0.f); acc.w = fmaxf(acc.w, 0.f);
    }
    ((float4*)(out + ((size_t)d<<8)))[lane] = acc;
}

// ---- GCN aggregation + fused SAG partial dots. MODE 0: cnt-buckets; 1: rpx --
template<int MODE>
__global__ void gcn_agg_sag(const float* __restrict__ h, const int* __restrict__ cnt,
                            const int2* __restrict__ rpx, const float* __restrict__ dinv,
                            const float* __restrict__ bias,
                            const float* __restrict__ wrel, const float* __restrict__ wroot,
                            const float* __restrict__ brel,
                            const int* __restrict__ esrc,
                            float* __restrict__ out, float* __restrict__ Y, float* __restrict__ Z){
    int lane = threadIdx.x & 63;
    int nb = gridDim.x;
    int b = blockIdx.x;
    int sb = (b & 7)*(nb >> 3) + (b >> 3);
    int d = __builtin_amdgcn_readfirstlane(sb*4 + (int)(threadIdx.x >> 6));
    int beg, end;
    float dv;
    if (MODE == 0){
        beg = d << 6; end = beg + cnt[d];
        dv = rsqrtf((float)(end - beg) + 1.0f);
    } else {
        int2 re = rpx[d]; beg = re.x; end = re.y;
        dv = dinv[d];
    }
    int c0 = lane*2;
    float2 hd = ((const float2*)(h + ((size_t)d<<7)))[lane];
    float self = dv*dv;
    float ax[4] = {self*hd.x, 0.f, 0.f, 0.f};
    float ay[4] = {self*hd.y, 0.f, 0.f, 0.f};
    int i = beg;
    int endu = beg + ((end - beg) & ~7);
    for (; i < endu; i += 8){
        int s_[8];
        #pragma unroll
        for (int j = 0; j < 8; j++) s_[j] = __builtin_amdgcn_readfirstlane(esrc[i + j]);
        float di_[8];
        #pragma unroll
        for (int j = 0; j < 8; j++){
            if (MODE == 0) di_[j] = rsqrtf((float)cnt[s_[j]] + 1.0f);
            else           di_[j] = dinv[s_[j]];
        }
        float2 hv_[8];
        #pragma unroll
        for (int j = 0; j < 8; j++) hv_[j] = ((const float2*)(h + ((size_t)s_[j]<<7)))[lane];
        #pragma unroll
        for (int j = 0; j < 8; j++){
            float coef = di_[j]*dv;
            ax[j & 3] = fmaf(coef, hv_[j].x, ax[j & 3]);
            ay[j & 3] = fmaf(coef, hv_[j].y, ay[j & 3]);
        }
    }
    for (; i < end; ++i){
        int s = __builtin_amdgcn_readfirstlane(esrc[i]);
        float di = (MODE == 0) ? rsqrtf((float)cnt[s] + 1.0f) : dinv[s];
        float coef = di*dv;
        float2 hv = ((const float2*)(h + ((size_t)s<<7)))[lane];
        ax[0] = fmaf(coef, hv.x, ax[0]); ay[0] = fmaf(coef, hv.y, ay[0]);
    }
    float axs = ((ax[0]+ax[1])+(ax[2]+ax[3]));
    float ays = ((ay[0]+ay[1])+(ay[2]+ay[3]));
    axs = fmaxf(axs + bias[c0], 0.f);
    ays = fmaxf(ays + bias[c0+1], 0.f);
    float2 o; o.x = axs; o.y = ays;
    ((float2*)(out + ((size_t)d<<7)))[lane] = o;
    float py = axs*wrel[c0]  + ays*wrel[c0+1];
    float pz = axs*wroot[c0] + ays*wroot[c0+1];
    #pragma unroll
    for (int off = 32; off; off >>= 1){ py += __shfl_xor(py, off); pz += __shfl_xor(pz, off); }
    if (lane == 0){ Y[d] = py; Z[d] = pz + brel[0]; }
}

// ---- SAG score via scalar gather (wide). MODE 0: cnt; 1: rpx ----
template<int MODE>
__global__ void sag_lite(const float* __restrict__ Y, const float* __restrict__ Z,
                         const int* __restrict__ cnt, const int2* __restrict__ rpx,
                         const int* __restrict__ esrc, float* __restrict__ score){
    int lane = threadIdx.x & 63;
    int w = threadIdx.x >> 6;
    int nb = gridDim.x;
    int b = blockIdx.x;
    int sb = (b & 7)*(nb >> 3) + (b >> 3);
    int d = sb*4 + w;
    int beg, end;
    if (MODE == 0){ beg = d << 6; end = beg + cnt[d]; }
    else { int2 re = rpx[d]; beg = re.x; end = re.y; }
    float s = 0.f;
    for (int i = beg + lane; i < end; i += 64) s += Y[esrc[i]];
    #pragma unroll
    for (int off = 32; off; off >>= 1) s += __shfl_xor(s, off);
    if (lane == 0) score[d] = s + Z[d];
}

// ------- barrier-free wave-per-graph radix-select top-k ---------------------
__global__ __launch_bounds__(64) void topk_wave(const float* __restrict__ score,
        int npg, int k, int* __restrict__ perm, float* __restrict__ ssort,
        int* __restrict__ nid, int writeNid){
    __shared__ unsigned keys[2048];
    __shared__ int hist[256];
    int g = blockIdx.x;
    int lane = threadIdx.x;
    int nch = npg >> 6;
    for (int c = 0; c < nch; c++){
        unsigned u = __float_as_uint(score[g*npg + c*64 + lane]);
        keys[c*64 + lane] = (u & 0x80000000u) ? ~u : (u | 0x80000000u);
    }
    int need = k;
    unsigned prefix = 0u, pmask = 0u;
    #pragma unroll
    for (int shift = 24; shift >= 0; shift -= 8){
        #pragma unroll
        for (int q = 0; q < 4; q++) hist[lane*4 + q] = 0;
        for (int c = 0; c < nch; c++){
            unsigned u = keys[c*64 + lane];
            if ((u & pmask) == prefix) atomicAdd(&hist[(u >> shift) & 255u], 1);
        }
        int h0 = hist[lane*4], h1 = hist[lane*4+1], h2 = hist[lane*4+2], h3 = hist[lane*4+3];
        int s3 = h3, s2 = h2 + s3, s1 = h1 + s2, s0 = h0 + s1;
        int tot = s0;
        int suf = tot;
        #pragma unroll
        for (int off = 1; off < 64; off <<= 1){
            int v = __shfl_down(suf, off);
            if (lane + off < 64) suf += v;
        }
        int above_quad = suf - tot;
        int c0 = s0 + above_quad, c1 = s1 + above_quad, c2 = s2 + above_quad, c3 = s3 + above_quad;
        int sel = -1;
        if (c0 >= need && c1 < need) sel = 0;
        if (c1 >= need && c2 < need) sel = 1;
        if (c2 >= need && c3 < need) sel = 2;
        if (c3 >= need && above_quad < need) sel = 3;
        unsigned long long msk = __ballot(sel >= 0);
        int srcl = __ffsll((long long)msk) - 1;
        int binq = __shfl(sel, srcl);
        int bin = srcl*4 + binq;
        int cge_next = (binq == 0) ? __shfl(c1, srcl) :
                       (binq == 1) ? __shfl(c2, srcl) :
                       (binq == 2) ? __shfl(c3, srcl) : __shfl(above_quad, srcl);
        need -= cge_next;
        prefix |= ((unsigned)bin) << shift;
        pmask  |= 255u << shift;
    }
    unsigned thr = prefix;
    int m = need;
    unsigned long long below = (1ull << lane) - 1ull;
    int base = 0, eqbase = 0;
    for (int c = 0; c < nch; c++){
        unsigned u = keys[c*64 + lane];
        bool gt = u > thr;
        bool eq = (u == thr);
        unsigned long long meq = __ballot(eq);
        int eqrank = eqbase + __popcll(meq & below);
        bool take = gt || (eq && eqrank < m);
        unsigned long long mtk = __ballot(take);
        int pos = base + __popcll(mtk & below);
        int node = g*npg + c*64 + lane;
        if (take){
            perm[g*k + pos] = node;
            ssort[g*k + pos] = tanhf(score[node]);
            if (writeNid) nid[node] = g*k + pos;
        } else if (writeNid) nid[node] = -1;
        base += __popcll(mtk);
        eqbase += __popcll(meq);
    }
}

// ------ fused final: gather+mean pool then 3-layer MLP (one block/graph) ----
__global__ void pool_mlp(const float* __restrict__ x, const int* __restrict__ perm,
                         const float* __restrict__ ssort,
                         const float* __restrict__ fc1w, const float* __restrict__ fc1b,
                         const float* __restrict__ fc2w, const float* __restrict__ fc2b,
                         const float* __restrict__ ow,  const float* __restrict__ ob,
                         float* __restrict__ out){
    __shared__ float tt[KK2];
    __shared__ float part[128];
    __shared__ float gv[128], t1[256], t2[128];
    int b = blockIdx.x, t = threadIdx.x;     // 256 threads
    tt[t]       = ssort[b*KK2 + t];
    tt[t + 256] = ssort[b*KK2 + t + 256];
    __syncthreads();
    int c = t & 127, half = t >> 7;
    float s = 0.f;
    #pragma unroll 4
    for (int i = half*256; i < half*256 + 256; i++){
        int o = perm[b*KK2 + i];
        s = fmaf(tt[i], x[(size_t)o*128 + c], s);
    }
    if (half) part[c] = s;
    __syncthreads();
    if (!half) gv[c] = (s + part[c]) * (1.0f/KK2);
    __syncthreads();
    {
        float s1 = fc1b[t];
        for (int cc = 0; cc < 128; cc++) s1 += gv[cc]*fc1w[t*128 + cc];
        t1[t] = fmaxf(s1, 0.f);
    }
    __syncthreads();
    if (t < 128){
        float s2 = fc2b[t];
        for (int cc = 0; cc < 256; cc++) s2 += t1[cc]*fc2w[t*256 + cc];
        t2[t] = fmaxf(s2, 0.f);
    }
    __syncthreads();
    if (t < 10){
        float s3 = ob[t];
        for (int cc = 0; cc < 128; cc++) s3 += t2[cc]*ow[t*128 + cc];
        out[b*10 + t] = s3;
    }
}

// ---------------- launch ----------------
extern "C" void kernel_launch(void* const* d_in, const int* in_sizes, int n_in,
                              void* d_out, int out_size, void* d_ws, size_t ws_size,
                              hipStream_t stream){
    (void)in_sizes; (void)n_in; (void)out_size; (void)ws_size;
    const float* x    = (const float*)d_in[0];
    const int*   eidx = (const int*)d_in[1];
    const int*   src  = eidx;
    const int*   dst  = eidx + EE;
    const float* g1w  = (const float*)d_in[3];
    const float* g1as = (const float*)d_in[4];
    const float* g1ad = (const float*)d_in[5];
    const float* g1b  = (const float*)d_in[6];
    const float* g2w  = (const float*)d_in[7];
    const float* g2as = (const float*)d_in[8];
    const float* g2ad = (const float*)d_in[9];
    const float* g2b  = (const float*)d_in[10];
    const float* c1w  = (const float*)d_in[11];
    const float* c1b  = (const float*)d_in[12];
    const float* s1wrel  = (const float*)d_in[13];
    const float* s1brel  = (const float*)d_in[14];
    const float* s1wroot = (const float*)d_in[15];
    const float* c2w  = (const float*)d_in[16];
    const float* c2b  = (const float*)d_in[17];
    const float* s2wrel  = (const float*)d_in[18];
    const float* s2brel  = (const float*)d_in[19];
    const float* s2wroot = (const float*)d_in[20];
    const float* f1w  = (const float*)d_in[21];
    const float* f1b  = (const float*)d_in[22];
    const float* f2w  = (const float*)d_in[23];
    const float* f2b  = (const float*)d_in[24];
    const float* ow   = (const float*)d_in[25];
    const float* ob   = (const float*)d_in[26];
    float* out = (float*)d_out;

    char* ws = (char*)d_ws;
    size_t off = 0;
    auto alloc = [&](size_t bytes)->char*{
        char* p = ws + off;
        off += (bytes + 255) & ~(size_t)255;
        return p;
    };
    float* F0     = (float*)alloc((size_t)N1*256*4);
    float* F1     = (float*)alloc((size_t)N1*256*4);
    float* F2     = (float*)alloc((size_t)N2*128*4);
    float* AS     = (float*)alloc((size_t)N1*4*4);
    float* AD     = (float*)alloc((size_t)N1*4*4);
    int*   CNT    = (int*)  alloc((size_t)N1*4);
    int*   EL     = (int*)  alloc((size_t)N1*CAP*4);
    float* SCORE  = (float*)alloc((size_t)N1*4);
    float* Y      = (float*)alloc((size_t)N1*4);
    float* Z      = (float*)alloc((size_t)N1*4);
    int*   PERM1  = (int*)  alloc((size_t)N2*4);
    float* SSORT1 = (float*)alloc((size_t)N2*4);
    int*   NID    = (int*)  alloc((size_t)N1*4);
    int2*  RPX2   = (int2*) alloc((size_t)N2*8);
    int*   EL2    = (int*)  alloc((size_t)N1*CAP*4);
    float* DINV2  = (float*)alloc((size_t)N2*4);
    int*   PERM2  = (int*)  alloc((size_t)N3*4);
    float* SSORT2 = (float*)alloc((size_t)N3*4);
    _Float16* WH  = (_Float16*)alloc((size_t)131072*2);
    _Float16* WL  = (_Float16*)alloc((size_t)131072*2);
    const int o_g1 = 0, o_g2 = 16384, o_c1 = 81920, o_c2 = 114688;

    // ---- CSR1 (scan-free, fixed-capacity buckets) + weight pre-split ----
    hipMemsetAsync(CNT, 0, (size_t)N1*4, stream);
    scatter_split<<<EE/256 + 512, 256, 0, stream>>>(src, dst, CNT, EL,
        g1w, 16384, g2w, 65536, c1w, 32768, c2w, 16384, WH, WL);

    // ---- GAT layer 1 (64 -> 4x64, relu); attn dots fused in GEMM ----
    gemm_h2<<<dim3(N1/128, 2), 256, 0, stream>>>(x, WH + o_g1, WL + o_g1, F0, N1, 64, 256,
                                                 nullptr, nullptr, g1as, g1ad, AS, AD);
    gat_agg<1><<<N1/4, 256, 0, stream>>>(F0, AS, AD, g1b, CNT, EL, F1);

    // ---- GAT layer 2 (256 -> 4x64) ----
    gemm_h2<<<dim3(N1/128, 2), 256, 0, stream>>>(F1, WH + o_g2, WL + o_g2, F0, N1, 256, 256,
                                                 nullptr, nullptr, g2as, g2ad, AS, AD);
    gat_agg<0><<<N1/4, 256, 0, stream>>>(F0, AS, AD, g2b, CNT, EL, F1);

    // ---- GCN1 (256 -> 128, relu) + fused SAG1 partial dots ----
    gemm_h2<<<dim3(N1/128, 1), 256, 0, stream>>>(F1, WH + o_c1, WL + o_c1, F0, N1, 256, 128,
                                                 nullptr, nullptr, nullptr, nullptr, nullptr, nullptr);
    gcn_agg_sag<0><<<N1/4, 256, 0, stream>>>(F0, CNT, nullptr, nullptr, c1b,
                                             s1wrel, s1wroot, s1brel, EL, F1, Y, Z);

    // ---- SAGPool1: wide score gather + wave-level select ----
    sag_lite<0><<<N1/4, 256, 0, stream>>>(Y, Z, CNT, nullptr, EL, SCORE);
    topk_wave<<<NB, 64, 0, stream>>>(SCORE, NPG1, KK1, PERM1, SSORT1, NID, 1);

    // ---- CSR2: single-kernel in-place bucket compaction ----
    csr2_build<<<N2/4, 256, 0, stream>>>(PERM1, NID, CNT, EL, RPX2, DINV2, EL2);

    // ---- GCN2 (128 -> 128, relu): GEMM reads F1 via perm * tanh ----
    gemm_h2<<<dim3(N2/128, 1), 256, 0, stream>>>(F1, WH + o_c2, WL + o_c2, F0, N2, 128, 128,
                                                 PERM1, SSORT1, nullptr, nullptr, nullptr, nullptr);
    gcn_agg_sag<1><<<N2/4, 256, 0, stream>>>(F0, nullptr, RPX2, DINV2, c2b,
                                             s2wrel, s2wroot, s2brel, EL2, F2, Y, Z);

    // ---- SAGPool2: wide score gather + wave-level select ----
    sag_lite<1><<<N2/4, 256, 0, stream>>>(Y, Z, nullptr, RPX2, EL2, SCORE);
    topk_wave<<<NB, 64, 0, stream>>>(SCORE, NPG2, KK2, PERM2, SSORT2, nullptr, 0);

    // ---- fused gather + mean pool + MLP ----
    pool_mlp<<<NB, 256, 0, stream>>>(F2, PERM2, SSORT2,
                                     f1w, f1b, f2w, f2b, ow, ob, out);
}